// Round 1
// baseline (596.956 us; speedup 1.0000x reference)
//
#include <hip/hip_runtime.h>
#include <float.h>

#define BB 4
#define HH 8
#define BHN 32
#define NTOK 4096
#define DD 64
#define MM 64
#define PAD 68

// ---------------- 4x4-tile 64x64x64 matmul helper (256 threads, ti=tid>>4 rows, tj=tid&15 cols)
template<int LDA, int LDB>
__device__ __forceinline__ void mm_acc(float acc[4][4],
    const float (*A)[LDA], const float (*B)[LDB], int ti, int tj) {
  #pragma unroll
  for (int k4 = 0; k4 < 16; ++k4) {
    float a[4][4], b[4][4];
    #pragma unroll
    for (int x = 0; x < 4; ++x) {
      float4 t = *(const float4*)&A[ti*4+x][k4*4];
      a[x][0]=t.x; a[x][1]=t.y; a[x][2]=t.z; a[x][3]=t.w;
    }
    #pragma unroll
    for (int kk = 0; kk < 4; ++kk) {
      float4 t = *(const float4*)&B[k4*4+kk][tj*4];
      b[kk][0]=t.x; b[kk][1]=t.y; b[kk][2]=t.z; b[kk][3]=t.w;
    }
    #pragma unroll
    for (int kk = 0; kk < 4; ++kk)
      #pragma unroll
      for (int x = 0; x < 4; ++x)
        #pragma unroll
        for (int y = 0; y < 4; ++y)
          acc[x][y] = fmaf(a[x][kk], b[kk][y], acc[x][y]);
  }
}

// ---------------- zero the accumulation region (num, den, scal) each launch
__global__ __launch_bounds__(256) void k_zero(float* __restrict__ ws) {
  int i = blockIdx.x * 256 + threadIdx.x;
  if (i < 133124) ws[i] = 0.f;
}

// ---------------- row sums for selection (both K and Q), mask/token0 -> -FLT_MAX
__global__ __launch_bounds__(256) void k_somme(const float* __restrict__ Kg,
    const float* __restrict__ Qg, const int* __restrict__ mask,
    float* __restrict__ somK, float* __restrict__ somQ) {
  int tid = threadIdx.x;
  int lane = tid & 63;
  long grow = (long)blockIdx.x * 16 + (tid >> 6) * 4 + (lane >> 4);
  int which = grow >= (long)(BHN * NTOK);
  long row = which ? grow - (long)BHN * NTOK : grow;   // bh*N + n
  int n = (int)(row & (NTOK - 1));
  int bh = (int)(row >> 12);
  int b = bh >> 3;
  const float* src = which ? Qg : Kg;
  float4 v = *((const float4*)(src + row * DD) + (lane & 15));
  float s = v.x + v.y + v.z + v.w;
  s += __shfl_xor(s, 1); s += __shfl_xor(s, 2);
  s += __shfl_xor(s, 4); s += __shfl_xor(s, 8);
  if ((lane & 15) == 0) {
    float out = (n == 0 || mask[b * NTOK + n] != 0) ? -FLT_MAX : s;
    (which ? somQ : somK)[row] = out;
  }
}

// ---------------- per-(bh,which): iterative top-63 argmax + append 0 + sort + gather rows
__global__ __launch_bounds__(256) void k_select(const float* __restrict__ Kg,
    const float* __restrict__ Qg, const float* __restrict__ somK,
    const float* __restrict__ somQ, float* __restrict__ nc, float* __restrict__ nr) {
  int bh = blockIdx.x;
  int which = blockIdx.y;           // 0: K -> nc, 1: Q (scaled) -> nr
  __shared__ float s[NTOK];
  __shared__ float rv[256];
  __shared__ int ri[256];
  __shared__ int sel[MM];
  int tid = threadIdx.x;
  const float* som = (which ? somQ : somK) + (long)bh * NTOK;
  for (int i = tid; i < NTOK; i += 256) s[i] = som[i];
  __syncthreads();
  for (int r = 0; r < MM - 1; ++r) {
    float bv = -FLT_MAX; int bi = NTOK;
    for (int i = tid; i < NTOK; i += 256) {
      float v = s[i];
      if (v > bv || (v == bv && i < bi)) { bv = v; bi = i; }
    }
    rv[tid] = bv; ri[tid] = bi;
    __syncthreads();
    for (int st = 128; st > 0; st >>= 1) {
      if (tid < st) {
        float ov = rv[tid + st]; int oi = ri[tid + st];
        if (ov > rv[tid] || (ov == rv[tid] && oi < ri[tid])) { rv[tid] = ov; ri[tid] = oi; }
      }
      __syncthreads();
    }
    if (tid == 0) { sel[r] = ri[0]; s[ri[0]] = -FLT_MAX; }
    __syncthreads();
  }
  if (tid == 0) {
    sel[MM - 1] = 0;
    for (int i = 1; i < MM; ++i) {       // insertion sort ascending
      int key = sel[i]; int j = i - 1;
      while (j >= 0 && sel[j] > key) { sel[j + 1] = sel[j]; --j; }
      sel[j + 1] = key;
    }
  }
  __syncthreads();
  const float* src = which ? Qg : Kg;
  float* dst = (which ? nr : nc) + (long)bh * MM * DD;
  float scale = which ? 0.125f : 1.0f;
  for (int e = tid; e < MM * DD; e += 256) {
    int i = e >> 6, d = e & 63;
    dst[e] = src[((long)bh * NTOK + sel[i]) * DD + d] * scale;
  }
}

// ---------------- u = row-softmax(nr @ nc^T); write u; atomicMax global colsum max
__global__ __launch_bounds__(256) void k_u(const float* __restrict__ nc,
    const float* __restrict__ nr, float* __restrict__ u, unsigned int* __restrict__ scal) {
  int bh = blockIdx.x, tid = threadIdx.x, ti = tid >> 4, tj = tid & 15;
  __shared__ float A[MM][PAD];
  __shared__ float BT[DD][MM];
  __shared__ float cs[4][MM];
  for (int e = tid; e < 1024; e += 256) {
    int m = e >> 4, d4 = e & 15;
    *(float4*)&A[m][d4*4] = *(const float4*)&nr[(long)bh*MM*DD + m*DD + d4*4];
    float4 c = *(const float4*)&nc[(long)bh*MM*DD + m*DD + d4*4];
    BT[d4*4+0][m] = c.x; BT[d4*4+1][m] = c.y; BT[d4*4+2][m] = c.z; BT[d4*4+3][m] = c.w;
  }
  __syncthreads();
  float acc[4][4] = {};
  mm_acc<PAD, MM>(acc, A, BT, ti, tj);
  float e_[4][4];
  #pragma unroll
  for (int x = 0; x < 4; ++x)
    #pragma unroll
    for (int y = 0; y < 4; ++y) e_[x][y] = expf(acc[x][y]);
  float rsx[4];
  #pragma unroll
  for (int x = 0; x < 4; ++x) {
    rsx[x] = e_[x][0] + e_[x][1] + e_[x][2] + e_[x][3];
    rsx[x] += __shfl_xor(rsx[x], 1); rsx[x] += __shfl_xor(rsx[x], 2);
    rsx[x] += __shfl_xor(rsx[x], 4); rsx[x] += __shfl_xor(rsx[x], 8);
  }
  float cp[4] = {0.f, 0.f, 0.f, 0.f};
  #pragma unroll
  for (int x = 0; x < 4; ++x) {
    float inv = 1.f / rsx[x];
    float v0 = e_[x][0]*inv, v1 = e_[x][1]*inv, v2 = e_[x][2]*inv, v3 = e_[x][3]*inv;
    cp[0] += v0; cp[1] += v1; cp[2] += v2; cp[3] += v3;
    float4 o; o.x = v0; o.y = v1; o.z = v2; o.w = v3;
    *(float4*)&u[(long)bh*MM*MM + (ti*4+x)*MM + tj*4] = o;
  }
  #pragma unroll
  for (int y = 0; y < 4; ++y) {
    cp[y] += __shfl_xor(cp[y], 16);
    cp[y] += __shfl_xor(cp[y], 32);
  }
  if (((tid >> 4) & 3) == 0) {
    #pragma unroll
    for (int y = 0; y < 4; ++y) cs[tid >> 6][tj*4 + y] = cp[y];
  }
  __syncthreads();
  if (tid < 64) {
    float tot = cs[0][tid] + cs[1][tid] + cs[2][tid] + cs[3][tid];
    for (int off = 32; off; off >>= 1) tot = fmaxf(tot, __shfl_xor(tot, off));
    if (tid == 0) atomicMax(scal, __float_as_uint(tot));
  }
}

// ---------------- Newton-Schulz inverse, 6 iters, 64x64 per (bh)
__global__ __launch_bounds__(256) void k_newton(const float* __restrict__ u,
    const unsigned int* __restrict__ scal, float* __restrict__ vinv) {
  int bh = blockIdx.x, tid = threadIdx.x, ti = tid >> 4, tj = tid & 15;
  __shared__ float Km[MM][MM];
  __shared__ float Vm[MM][MM];
  __shared__ float T1[MM][MM];
  __shared__ float T2[MM][MM];
  const float* pu = u + (long)bh * MM * MM;
  for (int e = tid; e < MM * MM; e += 256) Km[e >> 6][e & 63] = pu[e];
  __syncthreads();
  float invs = 1.0f / __uint_as_float(scal[0]);
  for (int e = tid; e < MM * MM; e += 256) {
    int i = e >> 6, j = e & 63;
    Vm[i][j] = Km[j][i] * invs;
  }
  __syncthreads();
  for (int it = 0; it < 6; ++it) {
    float acc[4][4];
    // T1 = Km@Vm ; T2 = 7I - T1
    #pragma unroll
    for (int x=0;x<4;++x) for (int y=0;y<4;++y) acc[x][y] = 0.f;
    mm_acc<MM, MM>(acc, Km, Vm, ti, tj);
    #pragma unroll
    for (int x = 0; x < 4; ++x)
      #pragma unroll
      for (int y = 0; y < 4; ++y) {
        int i = ti*4+x, j = tj*4+y;
        T1[i][j] = acc[x][y];
        T2[i][j] = (i == j ? 7.f : 0.f) - acc[x][y];
      }
    __syncthreads();
    // T2 = 15I - T1@T2   (in place: compute->barrier->store)
    #pragma unroll
    for (int x=0;x<4;++x) for (int y=0;y<4;++y) acc[x][y] = 0.f;
    mm_acc<MM, MM>(acc, T1, T2, ti, tj);
    __syncthreads();
    #pragma unroll
    for (int x = 0; x < 4; ++x)
      #pragma unroll
      for (int y = 0; y < 4; ++y) {
        int i = ti*4+x, j = tj*4+y;
        T2[i][j] = (i == j ? 15.f : 0.f) - acc[x][y];
      }
    __syncthreads();
    // T2 = 13I - T1@T2
    #pragma unroll
    for (int x=0;x<4;++x) for (int y=0;y<4;++y) acc[x][y] = 0.f;
    mm_acc<MM, MM>(acc, T1, T2, ti, tj);
    __syncthreads();
    #pragma unroll
    for (int x = 0; x < 4; ++x)
      #pragma unroll
      for (int y = 0; y < 4; ++y) {
        int i = ti*4+x, j = tj*4+y;
        T2[i][j] = (i == j ? 13.f : 0.f) - acc[x][y];
      }
    __syncthreads();
    // Vm = 0.25 * Vm@T2
    #pragma unroll
    for (int x=0;x<4;++x) for (int y=0;y<4;++y) acc[x][y] = 0.f;
    mm_acc<MM, MM>(acc, Vm, T2, ti, tj);
    __syncthreads();
    #pragma unroll
    for (int x = 0; x < 4; ++x)
      #pragma unroll
      for (int y = 0; y < 4; ++y) Vm[ti*4+x][tj*4+y] = 0.25f * acc[x][y];
    __syncthreads();
  }
  for (int e = tid; e < MM * MM; e += 256) vinv[(long)bh*MM*MM + e] = Vm[e >> 6][e & 63];
}

// ---------------- num/den partials of kernel_3 @ V  (exp masked to mask==1, no max-sub)
__global__ __launch_bounds__(256) void k_w3(const float* __restrict__ Kg,
    const float* __restrict__ Vg, const int* __restrict__ maskg,
    const float* __restrict__ nr, float* __restrict__ num, float* __restrict__ den) {
  int bh = blockIdx.x, grp = blockIdx.y;
  int b = bh >> 3;
  int tid = threadIdx.x, ti = tid >> 4, tj = tid & 15;
  __shared__ float A[MM][PAD];
  __shared__ float KT[DD][MM];
  __shared__ float Vc[MM][MM];
  __shared__ int sm[MM];
  const float* pnr = nr + (long)bh * MM * DD;
  for (int e = tid; e < 1024; e += 256) {
    int m = e >> 4, d4 = e & 15;
    *(float4*)&A[m][d4*4] = *(const float4*)&pnr[m*DD + d4*4];
  }
  float accN[4][4] = {};
  float dacc[4] = {0.f, 0.f, 0.f, 0.f};
  #pragma unroll 1
  for (int sc = 0; sc < 4; ++sc) {
    int n0 = (grp * 4 + sc) * 64;
    if (sc) __syncthreads();
    for (int e = tid; e < 1024; e += 256) {
      int nn = e >> 4, d4 = e & 15;
      float4 kt = *(const float4*)&Kg[((long)bh*NTOK + n0 + nn)*DD + d4*4];
      KT[d4*4+0][nn] = kt.x; KT[d4*4+1][nn] = kt.y; KT[d4*4+2][nn] = kt.z; KT[d4*4+3][nn] = kt.w;
      *(float4*)&Vc[nn][d4*4] = *(const float4*)&Vg[((long)bh*NTOK + n0 + nn)*DD + d4*4];
    }
    if (tid < 64) sm[tid] = maskg[b * NTOK + n0 + tid];
    __syncthreads();
    float acc[4][4] = {};
    mm_acc<PAD, MM>(acc, A, KT, ti, tj);
    float e_[4][4];
    #pragma unroll
    for (int y = 0; y < 4; ++y) {
      int keep = sm[tj*4 + y];
      #pragma unroll
      for (int x = 0; x < 4; ++x) e_[x][y] = keep ? expf(acc[x][y]) : 0.f;
    }
    float rsx[4];
    #pragma unroll
    for (int x = 0; x < 4; ++x) {
      rsx[x] = e_[x][0] + e_[x][1] + e_[x][2] + e_[x][3];
      rsx[x] += __shfl_xor(rsx[x], 1); rsx[x] += __shfl_xor(rsx[x], 2);
      rsx[x] += __shfl_xor(rsx[x], 4); rsx[x] += __shfl_xor(rsx[x], 8);
      dacc[x] += rsx[x];
    }
    int base = ((tid >> 4) & 3) * 16;
    #pragma unroll
    for (int q = 0; q < 16; ++q) {
      #pragma unroll
      for (int kk = 0; kk < 4; ++kk) {
        float4 bv = *(const float4*)&Vc[q*4+kk][tj*4];
        float e0 = __shfl(e_[0][kk], base + q, 64);
        float e1 = __shfl(e_[1][kk], base + q, 64);
        float e2 = __shfl(e_[2][kk], base + q, 64);
        float e3 = __shfl(e_[3][kk], base + q, 64);
        accN[0][0] = fmaf(e0, bv.x, accN[0][0]); accN[0][1] = fmaf(e0, bv.y, accN[0][1]);
        accN[0][2] = fmaf(e0, bv.z, accN[0][2]); accN[0][3] = fmaf(e0, bv.w, accN[0][3]);
        accN[1][0] = fmaf(e1, bv.x, accN[1][0]); accN[1][1] = fmaf(e1, bv.y, accN[1][1]);
        accN[1][2] = fmaf(e1, bv.z, accN[1][2]); accN[1][3] = fmaf(e1, bv.w, accN[1][3]);
        accN[2][0] = fmaf(e2, bv.x, accN[2][0]); accN[2][1] = fmaf(e2, bv.y, accN[2][1]);
        accN[2][2] = fmaf(e2, bv.z, accN[2][2]); accN[2][3] = fmaf(e2, bv.w, accN[2][3]);
        accN[3][0] = fmaf(e3, bv.x, accN[3][0]); accN[3][1] = fmaf(e3, bv.y, accN[3][1]);
        accN[3][2] = fmaf(e3, bv.z, accN[3][2]); accN[3][3] = fmaf(e3, bv.w, accN[3][3]);
      }
    }
  }
  float* pnum = num + (long)bh * MM * DD;
  #pragma unroll
  for (int x = 0; x < 4; ++x)
    #pragma unroll
    for (int y = 0; y < 4; ++y)
      atomicAdd(&pnum[(ti*4+x)*DD + tj*4+y], accN[x][y]);
  if (tj == 0) {
    #pragma unroll
    for (int x = 0; x < 4; ++x) atomicAdd(&den[bh*MM + ti*4+x], dacc[x]);
  }
}

// ---------------- Z = Vinv @ (num/den)
__global__ __launch_bounds__(256) void k_z(const float* __restrict__ vinv,
    const float* __restrict__ num, const float* __restrict__ den, float* __restrict__ Zg) {
  int bh = blockIdx.x, tid = threadIdx.x, ti = tid >> 4, tj = tid & 15;
  __shared__ float A[MM][PAD];
  __shared__ float W[MM][MM];
  __shared__ float dn[MM];
  if (tid < 64) dn[tid] = den[bh*MM + tid];
  for (int e = tid; e < 1024; e += 256) {
    int m = e >> 4, d4 = e & 15;
    *(float4*)&A[m][d4*4] = *(const float4*)&vinv[(long)bh*MM*MM + m*MM + d4*4];
  }
  __syncthreads();
  for (int e = tid; e < 1024; e += 256) {
    int m = e >> 4, d4 = e & 15;
    float4 t = *(const float4*)&num[(long)bh*MM*DD + m*DD + d4*4];
    float inv = 1.f / dn[m];
    t.x *= inv; t.y *= inv; t.z *= inv; t.w *= inv;
    *(float4*)&W[m][d4*4] = t;
  }
  __syncthreads();
  float acc[4][4] = {};
  mm_acc<PAD, MM>(acc, A, W, ti, tj);
  #pragma unroll
  for (int x = 0; x < 4; ++x) {
    float4 o; o.x = acc[x][0]; o.y = acc[x][1]; o.z = acc[x][2]; o.w = acc[x][3];
    *(float4*)&Zg[(long)bh*MM*DD + (ti*4+x)*DD + tj*4] = o;
  }
}

// ---------------- X = row-softmax(Qs @ nc^T) @ Z
__global__ __launch_bounds__(256) void k_final(const float* __restrict__ Qg,
    const float* __restrict__ nc, const float* __restrict__ Zg, float* __restrict__ Xg) {
  int bh = blockIdx.x, chunk = blockIdx.y;
  int tid = threadIdx.x, ti = tid >> 4, tj = tid & 15;
  int n0 = chunk * 64;
  __shared__ float Qc[64][PAD];
  __shared__ float BT[DD][MM];
  __shared__ float Zs[MM][MM];
  for (int e = tid; e < 1024; e += 256) {
    int r = e >> 4, d4 = e & 15;
    float4 q = *(const float4*)&Qg[((long)bh*NTOK + n0 + r)*DD + d4*4];
    q.x *= 0.125f; q.y *= 0.125f; q.z *= 0.125f; q.w *= 0.125f;
    *(float4*)&Qc[r][d4*4] = q;
    float4 c = *(const float4*)&nc[(long)bh*MM*DD + r*DD + d4*4];
    BT[d4*4+0][r] = c.x; BT[d4*4+1][r] = c.y; BT[d4*4+2][r] = c.z; BT[d4*4+3][r] = c.w;
    *(float4*)&Zs[r][d4*4] = *(const float4*)&Zg[(long)bh*MM*DD + r*DD + d4*4];
  }
  __syncthreads();
  float acc[4][4] = {};
  mm_acc<PAD, MM>(acc, Qc, BT, ti, tj);
  float e_[4][4];
  #pragma unroll
  for (int x = 0; x < 4; ++x)
    #pragma unroll
    for (int y = 0; y < 4; ++y) e_[x][y] = expf(acc[x][y]);
  float rsx[4];
  #pragma unroll
  for (int x = 0; x < 4; ++x) {
    rsx[x] = e_[x][0] + e_[x][1] + e_[x][2] + e_[x][3];
    rsx[x] += __shfl_xor(rsx[x], 1); rsx[x] += __shfl_xor(rsx[x], 2);
    rsx[x] += __shfl_xor(rsx[x], 4); rsx[x] += __shfl_xor(rsx[x], 8);
  }
  float acc2[4][4] = {};
  int base = ((tid >> 4) & 3) * 16;
  #pragma unroll
  for (int q = 0; q < 16; ++q) {
    #pragma unroll
    for (int kk = 0; kk < 4; ++kk) {
      float4 bv = *(const float4*)&Zs[q*4+kk][tj*4];
      float e0 = __shfl(e_[0][kk], base + q, 64);
      float e1 = __shfl(e_[1][kk], base + q, 64);
      float e2 = __shfl(e_[2][kk], base + q, 64);
      float e3 = __shfl(e_[3][kk], base + q, 64);
      acc2[0][0] = fmaf(e0, bv.x, acc2[0][0]); acc2[0][1] = fmaf(e0, bv.y, acc2[0][1]);
      acc2[0][2] = fmaf(e0, bv.z, acc2[0][2]); acc2[0][3] = fmaf(e0, bv.w, acc2[0][3]);
      acc2[1][0] = fmaf(e1, bv.x, acc2[1][0]); acc2[1][1] = fmaf(e1, bv.y, acc2[1][1]);
      acc2[1][2] = fmaf(e1, bv.z, acc2[1][2]); acc2[1][3] = fmaf(e1, bv.w, acc2[1][3]);
      acc2[2][0] = fmaf(e2, bv.x, acc2[2][0]); acc2[2][1] = fmaf(e2, bv.y, acc2[2][1]);
      acc2[2][2] = fmaf(e2, bv.z, acc2[2][2]); acc2[2][3] = fmaf(e2, bv.w, acc2[2][3]);
      acc2[3][0] = fmaf(e3, bv.x, acc2[3][0]); acc2[3][1] = fmaf(e3, bv.y, acc2[3][1]);
      acc2[3][2] = fmaf(e3, bv.z, acc2[3][2]); acc2[3][3] = fmaf(e3, bv.w, acc2[3][3]);
    }
  }
  #pragma unroll
  for (int x = 0; x < 4; ++x) {
    float inv = 1.f / rsx[x];
    float4 o;
    o.x = acc2[x][0] * inv; o.y = acc2[x][1] * inv;
    o.z = acc2[x][2] * inv; o.w = acc2[x][3] * inv;
    *(float4*)&Xg[((long)bh*NTOK + n0 + ti*4+x)*DD + tj*4] = o;
  }
}

extern "C" void kernel_launch(void* const* d_in, const int* in_sizes, int n_in,
                              void* d_out, int out_size, void* d_ws, size_t ws_size,
                              hipStream_t stream) {
  (void)in_sizes; (void)n_in; (void)out_size; (void)ws_size;
  const float* Qp = (const float*)d_in[0];
  const float* Kp = (const float*)d_in[1];
  const float* Vp = (const float*)d_in[2];
  const int* maskp = (const int*)d_in[3];
  float* out = (float*)d_out;

  float* wsf = (float*)d_ws;
  float* NUM = wsf;                                // 131072
  float* DEN = wsf + 131072;                       // 2048
  unsigned int* SCAL = (unsigned int*)(wsf + 133120);
  float* NC = wsf + 133124;
  float* NR = NC + 131072;
  float* U  = NR + 131072;
  float* VI = U  + 131072;
  float* Zb = VI + 131072;
  float* SK = Zb + 131072;
  float* SQ = SK + 131072;

  k_zero<<<521, 256, 0, stream>>>(wsf);
  k_somme<<<16384, 256, 0, stream>>>(Kp, Qp, maskp, SK, SQ);
  k_select<<<dim3(32, 2), 256, 0, stream>>>(Kp, Qp, SK, SQ, NC, NR);
  k_u<<<32, 256, 0, stream>>>(NC, NR, U, SCAL);
  k_newton<<<32, 256, 0, stream>>>(U, SCAL, VI);
  k_w3<<<dim3(32, 16), 256, 0, stream>>>(Kp, Vp, maskp, NR, NUM, DEN);
  k_z<<<32, 256, 0, stream>>>(VI, NUM, DEN, Zb);
  k_final<<<dim3(32, 64), 256, 0, stream>>>(Qp, NC, Zb, out);
}

// Round 2
// 325.177 us; speedup vs baseline: 1.8358x; 1.8358x over previous
//
#include <hip/hip_runtime.h>
#include <float.h>

#define BB 4
#define HH 8
#define BHN 32
#define NTOK 4096
#define DD 64
#define MM 64
#define PAD 68
#define GPART 16

// ---------------- 4x4-tile 64x64x64 matmul helper (256 threads, ti=tid>>4 rows, tj=tid&15 cols)
template<int LDA, int LDB>
__device__ __forceinline__ void mm_acc(float acc[4][4],
    const float (*A)[LDA], const float (*B)[LDB], int ti, int tj) {
  #pragma unroll
  for (int k4 = 0; k4 < 16; ++k4) {
    float a[4][4], b[4][4];
    #pragma unroll
    for (int x = 0; x < 4; ++x) {
      float4 t = *(const float4*)&A[ti*4+x][k4*4];
      a[x][0]=t.x; a[x][1]=t.y; a[x][2]=t.z; a[x][3]=t.w;
    }
    #pragma unroll
    for (int kk = 0; kk < 4; ++kk) {
      float4 t = *(const float4*)&B[k4*4+kk][tj*4];
      b[kk][0]=t.x; b[kk][1]=t.y; b[kk][2]=t.z; b[kk][3]=t.w;
    }
    #pragma unroll
    for (int kk = 0; kk < 4; ++kk)
      #pragma unroll
      for (int x = 0; x < 4; ++x)
        #pragma unroll
        for (int y = 0; y < 4; ++y)
          acc[x][y] = fmaf(a[x][kk], b[kk][y], acc[x][y]);
  }
}

// ---------------- row sums for selection (both K and Q), mask/token0 -> -FLT_MAX
__global__ __launch_bounds__(256) void k_somme(const float* __restrict__ Kg,
    const float* __restrict__ Qg, const int* __restrict__ mask,
    float* __restrict__ somK, float* __restrict__ somQ) {
  int tid = threadIdx.x;
  int lane = tid & 63;
  long grow = (long)blockIdx.x * 16 + (tid >> 6) * 4 + (lane >> 4);
  int which = grow >= (long)(BHN * NTOK);
  long row = which ? grow - (long)BHN * NTOK : grow;   // bh*N + n
  int n = (int)(row & (NTOK - 1));
  int bh = (int)(row >> 12);
  int b = bh >> 3;
  const float* src = which ? Qg : Kg;
  float4 v = *((const float4*)(src + row * DD) + (lane & 15));
  float s = v.x + v.y + v.z + v.w;
  s += __shfl_xor(s, 1); s += __shfl_xor(s, 2);
  s += __shfl_xor(s, 4); s += __shfl_xor(s, 8);
  if ((lane & 15) == 0) {
    float out = (n == 0 || mask[b * NTOK + n] != 0) ? -FLT_MAX : s;
    (which ? somQ : somK)[row] = out;
  }
}

// ---------------- per-(bh,which): radix top-63 select + token 0 + index-sorted gather
__global__ __launch_bounds__(256) void k_select(const float* __restrict__ Kg,
    const float* __restrict__ Qg, const float* __restrict__ somK,
    const float* __restrict__ somQ, float* __restrict__ nc, float* __restrict__ nr) {
  int bh = blockIdx.x;
  int which = blockIdx.y;           // 0: K -> nc, 1: Q (scaled) -> nr
  __shared__ unsigned int keys[NTOK];      // 16KB
  __shared__ int flg[NTOK];                // 16KB
  __shared__ unsigned int bins[256];
  __shared__ unsigned int cum[257];
  __shared__ int sh_bin, sh_need;
  __shared__ int sel[MM];
  int tid = threadIdx.x;
  const float* som = (which ? somQ : somK) + (long)bh * NTOK;
  for (int i = tid; i < NTOK; i += 256) {
    float f = som[i];
    unsigned int u = __float_as_uint(f);
    u = (u & 0x80000000u) ? ~u : (u | 0x80000000u);   // monotone map, ascending
    if (i == 0) u = 0u;                               // token 0 excluded from competition
    keys[i] = u;
  }
  __syncthreads();

  // --- 4-pass radix select: find exact key of the 63rd largest ---
  unsigned int pref = 0; int need = MM - 1;           // 63
  for (int pass = 0; pass < 4; ++pass) {
    int shift = 24 - pass * 8;
    unsigned int pm = (pass == 0) ? 0u : (0xFFFFFFFFu << (32 - 8 * pass));
    bins[tid] = 0;
    __syncthreads();
    for (int i = tid; i < NTOK; i += 256) {
      unsigned int k = keys[i];
      if ((k & pm) == pref) atomicAdd(&bins[(k >> shift) & 255], 1u);
    }
    __syncthreads();
    // inclusive suffix scan: cum[i] = sum_{j>=i} bins[j]
    cum[tid] = bins[tid];
    __syncthreads();
    for (int st = 1; st < 256; st <<= 1) {
      unsigned int add = (tid + st < 256) ? cum[tid + st] : 0u;
      __syncthreads();
      cum[tid] += add;
      __syncthreads();
    }
    unsigned int above = (tid < 255) ? cum[tid + 1] : 0u;
    if (cum[tid] >= (unsigned)need && above < (unsigned)need) {
      sh_bin = tid; sh_need = need - (int)above;
    }
    __syncthreads();
    pref |= ((unsigned)sh_bin) << shift;
    need = sh_need;
    __syncthreads();
  }
  unsigned int thr = pref;

  // --- tie ranking (ties at thr take smallest indices), contiguous segments ---
  int base = tid * 16;
  int ctie = 0;
  #pragma unroll
  for (int j = 0; j < 16; ++j) ctie += (keys[base + j] == thr);
  cum[tid] = (unsigned)ctie;
  __syncthreads();
  for (int st = 1; st < 256; st <<= 1) {
    unsigned int add = (tid >= st) ? cum[tid - st] : 0u;
    __syncthreads();
    cum[tid] += add;
    __syncthreads();
  }
  int tieoff = (int)cum[tid] - ctie;   // exclusive prefix of ties by index order
  int cnt = 0;
  #pragma unroll
  for (int j = 0; j < 16; ++j) {
    unsigned int k = keys[base + j];
    int f = (k > thr) ? 1 : 0;
    if (k == thr) { f = (tieoff < need) ? 1 : 0; ++tieoff; }
    if (base + j == 0) f = 1;          // always keep token 0
    flg[base + j] = f;
    cnt += f;
  }
  __syncthreads();
  // --- compaction prefix: positions in ascending-index order == sorted ---
  cum[tid] = (unsigned)cnt;
  __syncthreads();
  for (int st = 1; st < 256; st <<= 1) {
    unsigned int add = (tid >= st) ? cum[tid - st] : 0u;
    __syncthreads();
    cum[tid] += add;
    __syncthreads();
  }
  int off = (int)cum[tid] - cnt;
  #pragma unroll
  for (int j = 0; j < 16; ++j)
    if (flg[base + j]) sel[off++] = base + j;
  __syncthreads();

  // --- gather selected rows ---
  const float* src = which ? Qg : Kg;
  float* dst = (which ? nr : nc) + (long)bh * MM * DD;
  float scale = which ? 0.125f : 1.0f;
  for (int e = tid; e < MM * 16; e += 256) {
    int i = e >> 4, d4 = e & 15;
    float4 v = *(const float4*)&src[((long)bh * NTOK + sel[i]) * DD + d4 * 4];
    v.x *= scale; v.y *= scale; v.z *= scale; v.w *= scale;
    *(float4*)&dst[i * DD + d4 * 4] = v;
  }
}

// ---------------- u = row-softmax(nr @ nc^T); write u; per-bh colsum max
__global__ __launch_bounds__(256) void k_u(const float* __restrict__ nc,
    const float* __restrict__ nr, float* __restrict__ u, float* __restrict__ smax) {
  int bh = blockIdx.x, tid = threadIdx.x, ti = tid >> 4, tj = tid & 15;
  __shared__ float A[MM][PAD];
  __shared__ float BT[DD][MM];
  __shared__ float cs[4][MM];
  for (int e = tid; e < 1024; e += 256) {
    int m = e >> 4, d4 = e & 15;
    *(float4*)&A[m][d4*4] = *(const float4*)&nr[(long)bh*MM*DD + m*DD + d4*4];
    float4 c = *(const float4*)&nc[(long)bh*MM*DD + m*DD + d4*4];
    BT[d4*4+0][m] = c.x; BT[d4*4+1][m] = c.y; BT[d4*4+2][m] = c.z; BT[d4*4+3][m] = c.w;
  }
  __syncthreads();
  float acc[4][4] = {};
  mm_acc<PAD, MM>(acc, A, BT, ti, tj);
  float e_[4][4];
  #pragma unroll
  for (int x = 0; x < 4; ++x)
    #pragma unroll
    for (int y = 0; y < 4; ++y) e_[x][y] = expf(acc[x][y]);
  float rsx[4];
  #pragma unroll
  for (int x = 0; x < 4; ++x) {
    rsx[x] = e_[x][0] + e_[x][1] + e_[x][2] + e_[x][3];
    rsx[x] += __shfl_xor(rsx[x], 1); rsx[x] += __shfl_xor(rsx[x], 2);
    rsx[x] += __shfl_xor(rsx[x], 4); rsx[x] += __shfl_xor(rsx[x], 8);
  }
  float cp[4] = {0.f, 0.f, 0.f, 0.f};
  #pragma unroll
  for (int x = 0; x < 4; ++x) {
    float inv = 1.f / rsx[x];
    float v0 = e_[x][0]*inv, v1 = e_[x][1]*inv, v2 = e_[x][2]*inv, v3 = e_[x][3]*inv;
    cp[0] += v0; cp[1] += v1; cp[2] += v2; cp[3] += v3;
    float4 o; o.x = v0; o.y = v1; o.z = v2; o.w = v3;
    *(float4*)&u[(long)bh*MM*MM + (ti*4+x)*MM + tj*4] = o;
  }
  #pragma unroll
  for (int y = 0; y < 4; ++y) {
    cp[y] += __shfl_xor(cp[y], 16);
    cp[y] += __shfl_xor(cp[y], 32);
  }
  if (((tid >> 4) & 3) == 0) {
    #pragma unroll
    for (int y = 0; y < 4; ++y) cs[tid >> 6][tj*4 + y] = cp[y];
  }
  __syncthreads();
  if (tid < 64) {
    float tot = cs[0][tid] + cs[1][tid] + cs[2][tid] + cs[3][tid];
    for (int off = 32; off; off >>= 1) tot = fmaxf(tot, __shfl_xor(tot, off));
    if (tid == 0) smax[bh] = tot;
  }
}

// ---------------- Newton-Schulz inverse, 6 iters, 64x64 per (bh)
__global__ __launch_bounds__(256) void k_newton(const float* __restrict__ u,
    const float* __restrict__ smax, float* __restrict__ vinv) {
  int bh = blockIdx.x, tid = threadIdx.x, ti = tid >> 4, tj = tid & 15;
  __shared__ float Km[MM][MM];
  __shared__ float Vm[MM][MM];
  __shared__ float T1[MM][MM];
  __shared__ float T2[MM][MM];
  __shared__ float gmx;
  const float* pu = u + (long)bh * MM * MM;
  for (int e = tid; e < MM * MM; e += 256) Km[e >> 6][e & 63] = pu[e];
  if (tid < 64) {
    float v = (tid < 32) ? smax[tid] : 0.f;    // colsum maxes are positive
    for (int off = 32; off; off >>= 1) v = fmaxf(v, __shfl_xor(v, off));
    if (tid == 0) gmx = v;
  }
  __syncthreads();
  float invs = 1.0f / gmx;
  for (int e = tid; e < MM * MM; e += 256) {
    int i = e >> 6, j = e & 63;
    Vm[i][j] = Km[j][i] * invs;
  }
  __syncthreads();
  for (int it = 0; it < 6; ++it) {
    float acc[4][4];
    #pragma unroll
    for (int x=0;x<4;++x) for (int y=0;y<4;++y) acc[x][y] = 0.f;
    mm_acc<MM, MM>(acc, Km, Vm, ti, tj);
    #pragma unroll
    for (int x = 0; x < 4; ++x)
      #pragma unroll
      for (int y = 0; y < 4; ++y) {
        int i = ti*4+x, j = tj*4+y;
        T1[i][j] = acc[x][y];
        T2[i][j] = (i == j ? 7.f : 0.f) - acc[x][y];
      }
    __syncthreads();
    #pragma unroll
    for (int x=0;x<4;++x) for (int y=0;y<4;++y) acc[x][y] = 0.f;
    mm_acc<MM, MM>(acc, T1, T2, ti, tj);
    __syncthreads();
    #pragma unroll
    for (int x = 0; x < 4; ++x)
      #pragma unroll
      for (int y = 0; y < 4; ++y) {
        int i = ti*4+x, j = tj*4+y;
        T2[i][j] = (i == j ? 15.f : 0.f) - acc[x][y];
      }
    __syncthreads();
    #pragma unroll
    for (int x=0;x<4;++x) for (int y=0;y<4;++y) acc[x][y] = 0.f;
    mm_acc<MM, MM>(acc, T1, T2, ti, tj);
    __syncthreads();
    #pragma unroll
    for (int x = 0; x < 4; ++x)
      #pragma unroll
      for (int y = 0; y < 4; ++y) {
        int i = ti*4+x, j = tj*4+y;
        T2[i][j] = (i == j ? 13.f : 0.f) - acc[x][y];
      }
    __syncthreads();
    #pragma unroll
    for (int x=0;x<4;++x) for (int y=0;y<4;++y) acc[x][y] = 0.f;
    mm_acc<MM, MM>(acc, Vm, T2, ti, tj);
    __syncthreads();
    #pragma unroll
    for (int x = 0; x < 4; ++x)
      #pragma unroll
      for (int y = 0; y < 4; ++y) Vm[ti*4+x][tj*4+y] = 0.25f * acc[x][y];
    __syncthreads();
  }
  for (int e = tid; e < MM * MM; e += 256) vinv[(long)bh*MM*MM + e] = Vm[e >> 6][e & 63];
}

// ---------------- partials of kernel_3 @ V  (exp masked to mask==1), atomic-free
__global__ __launch_bounds__(256) void k_w3(const float* __restrict__ Kg,
    const float* __restrict__ Vg, const int* __restrict__ maskg,
    const float* __restrict__ nr, float* __restrict__ nump, float* __restrict__ denp) {
  int bh = blockIdx.x, grp = blockIdx.y;
  int b = bh >> 3;
  int tid = threadIdx.x, ti = tid >> 4, tj = tid & 15;
  __shared__ float A[MM][PAD];
  __shared__ float KT[DD][MM];
  __shared__ float Vc[MM][MM];
  __shared__ int sm[MM];
  const float* pnr = nr + (long)bh * MM * DD;
  for (int e = tid; e < 1024; e += 256) {
    int m = e >> 4, d4 = e & 15;
    *(float4*)&A[m][d4*4] = *(const float4*)&pnr[m*DD + d4*4];
  }
  float accN[4][4] = {};
  float dacc[4] = {0.f, 0.f, 0.f, 0.f};
  #pragma unroll 1
  for (int sc = 0; sc < 4; ++sc) {
    int n0 = (grp * 4 + sc) * 64;
    if (sc) __syncthreads();
    for (int e = tid; e < 1024; e += 256) {
      int nn = e >> 4, d4 = e & 15;
      float4 kt = *(const float4*)&Kg[((long)bh*NTOK + n0 + nn)*DD + d4*4];
      KT[d4*4+0][nn] = kt.x; KT[d4*4+1][nn] = kt.y; KT[d4*4+2][nn] = kt.z; KT[d4*4+3][nn] = kt.w;
      *(float4*)&Vc[nn][d4*4] = *(const float4*)&Vg[((long)bh*NTOK + n0 + nn)*DD + d4*4];
    }
    if (tid < 64) sm[tid] = maskg[b * NTOK + n0 + tid];
    __syncthreads();
    float acc[4][4] = {};
    mm_acc<PAD, MM>(acc, A, KT, ti, tj);
    float e_[4][4];
    #pragma unroll
    for (int y = 0; y < 4; ++y) {
      int keep = sm[tj*4 + y];
      #pragma unroll
      for (int x = 0; x < 4; ++x) e_[x][y] = keep ? expf(acc[x][y]) : 0.f;
    }
    float rsx[4];
    #pragma unroll
    for (int x = 0; x < 4; ++x) {
      rsx[x] = e_[x][0] + e_[x][1] + e_[x][2] + e_[x][3];
      rsx[x] += __shfl_xor(rsx[x], 1); rsx[x] += __shfl_xor(rsx[x], 2);
      rsx[x] += __shfl_xor(rsx[x], 4); rsx[x] += __shfl_xor(rsx[x], 8);
      dacc[x] += rsx[x];
    }
    int base = ((tid >> 4) & 3) * 16;
    #pragma unroll
    for (int q = 0; q < 16; ++q) {
      #pragma unroll
      for (int kk = 0; kk < 4; ++kk) {
        float4 bv = *(const float4*)&Vc[q*4+kk][tj*4];
        float e0 = __shfl(e_[0][kk], base + q, 64);
        float e1 = __shfl(e_[1][kk], base + q, 64);
        float e2 = __shfl(e_[2][kk], base + q, 64);
        float e3 = __shfl(e_[3][kk], base + q, 64);
        accN[0][0] = fmaf(e0, bv.x, accN[0][0]); accN[0][1] = fmaf(e0, bv.y, accN[0][1]);
        accN[0][2] = fmaf(e0, bv.z, accN[0][2]); accN[0][3] = fmaf(e0, bv.w, accN[0][3]);
        accN[1][0] = fmaf(e1, bv.x, accN[1][0]); accN[1][1] = fmaf(e1, bv.y, accN[1][1]);
        accN[1][2] = fmaf(e1, bv.z, accN[1][2]); accN[1][3] = fmaf(e1, bv.w, accN[1][3]);
        accN[2][0] = fmaf(e2, bv.x, accN[2][0]); accN[2][1] = fmaf(e2, bv.y, accN[2][1]);
        accN[2][2] = fmaf(e2, bv.z, accN[2][2]); accN[2][3] = fmaf(e2, bv.w, accN[2][3]);
        accN[3][0] = fmaf(e3, bv.x, accN[3][0]); accN[3][1] = fmaf(e3, bv.y, accN[3][1]);
        accN[3][2] = fmaf(e3, bv.z, accN[3][2]); accN[3][3] = fmaf(e3, bv.w, accN[3][3]);
      }
    }
  }
  float* pnum = nump + ((long)bh * GPART + grp) * (MM * DD);
  #pragma unroll
  for (int x = 0; x < 4; ++x) {
    float4 o; o.x = accN[x][0]; o.y = accN[x][1]; o.z = accN[x][2]; o.w = accN[x][3];
    *(float4*)&pnum[(ti*4+x)*DD + tj*4] = o;
  }
  if (tj == 0) {
    #pragma unroll
    for (int x = 0; x < 4; ++x)
      denp[((long)bh * GPART + grp) * MM + ti*4+x] = dacc[x];
  }
}

// ---------------- Z = Vinv @ (sum_g num_g / sum_g den_g)
__global__ __launch_bounds__(256) void k_z(const float* __restrict__ vinv,
    const float* __restrict__ nump, const float* __restrict__ denp, float* __restrict__ Zg) {
  int bh = blockIdx.x, tid = threadIdx.x, ti = tid >> 4, tj = tid & 15;
  __shared__ float A[MM][PAD];
  __shared__ float W[MM][MM];
  __shared__ float dn[MM];
  if (tid < 64) {
    float s = 0.f;
    #pragma unroll
    for (int g = 0; g < GPART; ++g) s += denp[((long)bh * GPART + g) * MM + tid];
    dn[tid] = s;
  }
  for (int e = tid; e < 1024; e += 256) {
    int m = e >> 4, d4 = e & 15;
    *(float4*)&A[m][d4*4] = *(const float4*)&vinv[(long)bh*MM*MM + m*MM + d4*4];
  }
  __syncthreads();
  for (int e = tid; e < 1024; e += 256) {
    int m = e >> 4, d4 = e & 15;
    float4 s = {0.f, 0.f, 0.f, 0.f};
    #pragma unroll
    for (int g = 0; g < GPART; ++g) {
      float4 t = *(const float4*)&nump[((long)bh * GPART + g) * (MM*DD) + m*DD + d4*4];
      s.x += t.x; s.y += t.y; s.z += t.z; s.w += t.w;
    }
    float inv = 1.f / dn[m];
    s.x *= inv; s.y *= inv; s.z *= inv; s.w *= inv;
    *(float4*)&W[m][d4*4] = s;
  }
  __syncthreads();
  float acc[4][4] = {};
  mm_acc<PAD, MM>(acc, A, W, ti, tj);
  #pragma unroll
  for (int x = 0; x < 4; ++x) {
    float4 o; o.x = acc[x][0]; o.y = acc[x][1]; o.z = acc[x][2]; o.w = acc[x][3];
    *(float4*)&Zg[(long)bh*MM*DD + (ti*4+x)*DD + tj*4] = o;
  }
}

// ---------------- X = row-softmax(Qs @ nc^T) @ Z
__global__ __launch_bounds__(256) void k_final(const float* __restrict__ Qg,
    const float* __restrict__ nc, const float* __restrict__ Zg, float* __restrict__ Xg) {
  int bh = blockIdx.x, chunk = blockIdx.y;
  int tid = threadIdx.x, ti = tid >> 4, tj = tid & 15;
  int n0 = chunk * 64;
  __shared__ float Qc[64][PAD];
  __shared__ float BT[DD][MM];
  __shared__ float Zs[MM][MM];
  for (int e = tid; e < 1024; e += 256) {
    int r = e >> 4, d4 = e & 15;
    float4 q = *(const float4*)&Qg[((long)bh*NTOK + n0 + r)*DD + d4*4];
    q.x *= 0.125f; q.y *= 0.125f; q.z *= 0.125f; q.w *= 0.125f;
    *(float4*)&Qc[r][d4*4] = q;
    float4 c = *(const float4*)&nc[(long)bh*MM*DD + r*DD + d4*4];
    BT[d4*4+0][r] = c.x; BT[d4*4+1][r] = c.y; BT[d4*4+2][r] = c.z; BT[d4*4+3][r] = c.w;
    *(float4*)&Zs[r][d4*4] = *(const float4*)&Zg[(long)bh*MM*DD + r*DD + d4*4];
  }
  __syncthreads();
  float acc[4][4] = {};
  mm_acc<PAD, MM>(acc, Qc, BT, ti, tj);
  float e_[4][4];
  #pragma unroll
  for (int x = 0; x < 4; ++x)
    #pragma unroll
    for (int y = 0; y < 4; ++y) e_[x][y] = expf(acc[x][y]);
  float rsx[4];
  #pragma unroll
  for (int x = 0; x < 4; ++x) {
    rsx[x] = e_[x][0] + e_[x][1] + e_[x][2] + e_[x][3];
    rsx[x] += __shfl_xor(rsx[x], 1); rsx[x] += __shfl_xor(rsx[x], 2);
    rsx[x] += __shfl_xor(rsx[x], 4); rsx[x] += __shfl_xor(rsx[x], 8);
  }
  float acc2[4][4] = {};
  int base = ((tid >> 4) & 3) * 16;
  #pragma unroll
  for (int q = 0; q < 16; ++q) {
    #pragma unroll
    for (int kk = 0; kk < 4; ++kk) {
      float4 bv = *(const float4*)&Zs[q*4+kk][tj*4];
      float e0 = __shfl(e_[0][kk], base + q, 64);
      float e1 = __shfl(e_[1][kk], base + q, 64);
      float e2 = __shfl(e_[2][kk], base + q, 64);
      float e3 = __shfl(e_[3][kk], base + q, 64);
      acc2[0][0] = fmaf(e0, bv.x, acc2[0][0]); acc2[0][1] = fmaf(e0, bv.y, acc2[0][1]);
      acc2[0][2] = fmaf(e0, bv.z, acc2[0][2]); acc2[0][3] = fmaf(e0, bv.w, acc2[0][3]);
      acc2[1][0] = fmaf(e1, bv.x, acc2[1][0]); acc2[1][1] = fmaf(e1, bv.y, acc2[1][1]);
      acc2[1][2] = fmaf(e1, bv.z, acc2[1][2]); acc2[1][3] = fmaf(e1, bv.w, acc2[1][3]);
      acc2[2][0] = fmaf(e2, bv.x, acc2[2][0]); acc2[2][1] = fmaf(e2, bv.y, acc2[2][1]);
      acc2[2][2] = fmaf(e2, bv.z, acc2[2][2]); acc2[2][3] = fmaf(e2, bv.w, acc2[2][3]);
      acc2[3][0] = fmaf(e3, bv.x, acc2[3][0]); acc2[3][1] = fmaf(e3, bv.y, acc2[3][1]);
      acc2[3][2] = fmaf(e3, bv.z, acc2[3][2]); acc2[3][3] = fmaf(e3, bv.w, acc2[3][3]);
    }
  }
  #pragma unroll
  for (int x = 0; x < 4; ++x) {
    float inv = 1.f / rsx[x];
    float4 o;
    o.x = acc2[x][0] * inv; o.y = acc2[x][1] * inv;
    o.z = acc2[x][2] * inv; o.w = acc2[x][3] * inv;
    *(float4*)&Xg[((long)bh*NTOK + n0 + ti*4+x)*DD + tj*4] = o;
  }
}

extern "C" void kernel_launch(void* const* d_in, const int* in_sizes, int n_in,
                              void* d_out, int out_size, void* d_ws, size_t ws_size,
                              hipStream_t stream) {
  (void)in_sizes; (void)n_in; (void)out_size; (void)ws_size;
  const float* Qp = (const float*)d_in[0];
  const float* Kp = (const float*)d_in[1];
  const float* Vp = (const float*)d_in[2];
  const int* maskp = (const int*)d_in[3];
  float* out = (float*)d_out;

  float* wsf = (float*)d_ws;
  float* NUMP = wsf;                               // 32*16*4096 = 2,097,152
  float* DENP = NUMP + (long)BHN * GPART * MM * DD; // 32*16*64 = 32,768
  float* SMAX = DENP + BHN * GPART * MM;           // 32
  float* NC = SMAX + 32;                           // 131072 each below
  float* NR = NC + BHN * MM * DD;
  float* U  = NR + BHN * MM * DD;
  float* VI = U  + BHN * MM * MM;
  float* Zb = VI + BHN * MM * MM;
  float* SK = Zb + BHN * MM * DD;
  float* SQ = SK + BHN * NTOK;

  k_somme<<<16384, 256, 0, stream>>>(Kp, Qp, maskp, SK, SQ);
  k_select<<<dim3(32, 2), 256, 0, stream>>>(Kp, Qp, SK, SQ, NC, NR);
  k_u<<<32, 256, 0, stream>>>(NC, NR, U, SMAX);
  k_newton<<<32, 256, 0, stream>>>(U, SMAX, VI);
  k_w3<<<dim3(32, GPART), 256, 0, stream>>>(Kp, Vp, maskp, NR, NUMP, DENP);
  k_z<<<32, 256, 0, stream>>>(VI, NUMP, DENP, Zb);
  k_final<<<dim3(32, 64), 256, 0, stream>>>(Qp, NC, Zb, out);
}

// Round 3
// 143.175 us; speedup vs baseline: 4.1694x; 2.2712x over previous
//
#include <hip/hip_runtime.h>
#include <float.h>

#define BB 4
#define HH 8
#define BHN 32
#define NTOK 4096
#define DD 64
#define MM 64
#define PAD 68
#define GPART 16

typedef _Float16 f16;
typedef __attribute__((ext_vector_type(4))) _Float16 f16x4;
typedef __attribute__((ext_vector_type(8))) _Float16 f16x8;
typedef __attribute__((ext_vector_type(4))) float f32x4;

// ---------------- 4x4-tile 64x64x64 matmul helper (256 threads, ti=tid>>4 rows, tj=tid&15 cols)
template<int LDA, int LDB>
__device__ __forceinline__ void mm_acc(float acc[4][4],
    const float (*A)[LDA], const float (*B)[LDB], int ti, int tj) {
  #pragma unroll
  for (int k4 = 0; k4 < 16; ++k4) {
    float a[4][4], b[4][4];
    #pragma unroll
    for (int x = 0; x < 4; ++x) {
      float4 t = *(const float4*)&A[ti*4+x][k4*4];
      a[x][0]=t.x; a[x][1]=t.y; a[x][2]=t.z; a[x][3]=t.w;
    }
    #pragma unroll
    for (int kk = 0; kk < 4; ++kk) {
      float4 t = *(const float4*)&B[k4*4+kk][tj*4];
      b[kk][0]=t.x; b[kk][1]=t.y; b[kk][2]=t.z; b[kk][3]=t.w;
    }
    #pragma unroll
    for (int kk = 0; kk < 4; ++kk)
      #pragma unroll
      for (int x = 0; x < 4; ++x)
        #pragma unroll
        for (int y = 0; y < 4; ++y)
          acc[x][y] = fmaf(a[x][kk], b[kk][y], acc[x][y]);
  }
}

// ---------------- row sums for selection (both K and Q), mask/token0 -> -FLT_MAX
__global__ __launch_bounds__(256) void k_somme(const float* __restrict__ Kg,
    const float* __restrict__ Qg, const int* __restrict__ mask,
    float* __restrict__ somK, float* __restrict__ somQ) {
  int tid = threadIdx.x;
  int lane = tid & 63;
  long grow = (long)blockIdx.x * 16 + (tid >> 6) * 4 + (lane >> 4);
  int which = grow >= (long)(BHN * NTOK);
  long row = which ? grow - (long)BHN * NTOK : grow;   // bh*N + n
  int n = (int)(row & (NTOK - 1));
  int bh = (int)(row >> 12);
  int b = bh >> 3;
  const float* src = which ? Qg : Kg;
  float4 v = *((const float4*)(src + row * DD) + (lane & 15));
  float s = v.x + v.y + v.z + v.w;
  s += __shfl_xor(s, 1); s += __shfl_xor(s, 2);
  s += __shfl_xor(s, 4); s += __shfl_xor(s, 8);
  if ((lane & 15) == 0) {
    float out = (n == 0 || mask[b * NTOK + n] != 0) ? -FLT_MAX : s;
    (which ? somQ : somK)[row] = out;
  }
}

// ---------------- per-(bh,which): radix top-63 select + token 0 + index-sorted gather
__global__ __launch_bounds__(256) void k_select(const float* __restrict__ Kg,
    const float* __restrict__ Qg, const float* __restrict__ somK,
    const float* __restrict__ somQ, float* __restrict__ nc, float* __restrict__ nr) {
  int bh = blockIdx.x;
  int which = blockIdx.y;           // 0: K -> nc, 1: Q (scaled) -> nr
  __shared__ unsigned int keys[NTOK];      // 16KB
  __shared__ int flg[NTOK];                // 16KB
  __shared__ unsigned int bins[256];
  __shared__ unsigned int cum[257];
  __shared__ int sh_bin, sh_need;
  __shared__ int sel[MM];
  int tid = threadIdx.x;
  const float* som = (which ? somQ : somK) + (long)bh * NTOK;
  for (int i = tid; i < NTOK; i += 256) {
    float f = som[i];
    unsigned int u = __float_as_uint(f);
    u = (u & 0x80000000u) ? ~u : (u | 0x80000000u);   // monotone map, ascending
    if (i == 0) u = 0u;                               // token 0 excluded from competition
    keys[i] = u;
  }
  __syncthreads();

  // --- 4-pass radix select: find exact key of the 63rd largest ---
  unsigned int pref = 0; int need = MM - 1;           // 63
  for (int pass = 0; pass < 4; ++pass) {
    int shift = 24 - pass * 8;
    unsigned int pm = (pass == 0) ? 0u : (0xFFFFFFFFu << (32 - 8 * pass));
    bins[tid] = 0;
    __syncthreads();
    for (int i = tid; i < NTOK; i += 256) {
      unsigned int k = keys[i];
      if ((k & pm) == pref) atomicAdd(&bins[(k >> shift) & 255], 1u);
    }
    __syncthreads();
    // inclusive suffix scan: cum[i] = sum_{j>=i} bins[j]
    cum[tid] = bins[tid];
    __syncthreads();
    for (int st = 1; st < 256; st <<= 1) {
      unsigned int add = (tid + st < 256) ? cum[tid + st] : 0u;
      __syncthreads();
      cum[tid] += add;
      __syncthreads();
    }
    unsigned int above = (tid < 255) ? cum[tid + 1] : 0u;
    if (cum[tid] >= (unsigned)need && above < (unsigned)need) {
      sh_bin = tid; sh_need = need - (int)above;
    }
    __syncthreads();
    pref |= ((unsigned)sh_bin) << shift;
    need = sh_need;
    __syncthreads();
  }
  unsigned int thr = pref;

  // --- tie ranking (ties at thr take smallest indices), contiguous segments ---
  int base = tid * 16;
  int ctie = 0;
  #pragma unroll
  for (int j = 0; j < 16; ++j) ctie += (keys[base + j] == thr);
  cum[tid] = (unsigned)ctie;
  __syncthreads();
  for (int st = 1; st < 256; st <<= 1) {
    unsigned int add = (tid >= st) ? cum[tid - st] : 0u;
    __syncthreads();
    cum[tid] += add;
    __syncthreads();
  }
  int tieoff = (int)cum[tid] - ctie;   // exclusive prefix of ties by index order
  int cnt = 0;
  #pragma unroll
  for (int j = 0; j < 16; ++j) {
    unsigned int k = keys[base + j];
    int f = (k > thr) ? 1 : 0;
    if (k == thr) { f = (tieoff < need) ? 1 : 0; ++tieoff; }
    if (base + j == 0) f = 1;          // always keep token 0
    flg[base + j] = f;
    cnt += f;
  }
  __syncthreads();
  // --- compaction prefix: positions in ascending-index order == sorted ---
  cum[tid] = (unsigned)cnt;
  __syncthreads();
  for (int st = 1; st < 256; st <<= 1) {
    unsigned int add = (tid >= st) ? cum[tid - st] : 0u;
    __syncthreads();
    cum[tid] += add;
    __syncthreads();
  }
  int off = (int)cum[tid] - cnt;
  #pragma unroll
  for (int j = 0; j < 16; ++j)
    if (flg[base + j]) sel[off++] = base + j;
  __syncthreads();

  // --- gather selected rows ---
  const float* src = which ? Qg : Kg;
  float* dst = (which ? nr : nc) + (long)bh * MM * DD;
  float scale = which ? 0.125f : 1.0f;
  for (int e = tid; e < MM * 16; e += 256) {
    int i = e >> 4, d4 = e & 15;
    float4 v = *(const float4*)&src[((long)bh * NTOK + sel[i]) * DD + d4 * 4];
    v.x *= scale; v.y *= scale; v.z *= scale; v.w *= scale;
    *(float4*)&dst[i * DD + d4 * 4] = v;
  }
}

// ---------------- u = row-softmax(nr @ nc^T); write u; per-bh colsum max
__global__ __launch_bounds__(256) void k_u(const float* __restrict__ nc,
    const float* __restrict__ nr, float* __restrict__ u, float* __restrict__ smax) {
  int bh = blockIdx.x, tid = threadIdx.x, ti = tid >> 4, tj = tid & 15;
  __shared__ float A[MM][PAD];
  __shared__ float BT[DD][MM];
  __shared__ float cs[4][MM];
  for (int e = tid; e < 1024; e += 256) {
    int m = e >> 4, d4 = e & 15;
    *(float4*)&A[m][d4*4] = *(const float4*)&nr[(long)bh*MM*DD + m*DD + d4*4];
    float4 c = *(const float4*)&nc[(long)bh*MM*DD + m*DD + d4*4];
    BT[d4*4+0][m] = c.x; BT[d4*4+1][m] = c.y; BT[d4*4+2][m] = c.z; BT[d4*4+3][m] = c.w;
  }
  __syncthreads();
  float acc[4][4] = {};
  mm_acc<PAD, MM>(acc, A, BT, ti, tj);
  float e_[4][4];
  #pragma unroll
  for (int x = 0; x < 4; ++x)
    #pragma unroll
    for (int y = 0; y < 4; ++y) e_[x][y] = expf(acc[x][y]);
  float rsx[4];
  #pragma unroll
  for (int x = 0; x < 4; ++x) {
    rsx[x] = e_[x][0] + e_[x][1] + e_[x][2] + e_[x][3];
    rsx[x] += __shfl_xor(rsx[x], 1); rsx[x] += __shfl_xor(rsx[x], 2);
    rsx[x] += __shfl_xor(rsx[x], 4); rsx[x] += __shfl_xor(rsx[x], 8);
  }
  float cp[4] = {0.f, 0.f, 0.f, 0.f};
  #pragma unroll
  for (int x = 0; x < 4; ++x) {
    float inv = 1.f / rsx[x];
    float v0 = e_[x][0]*inv, v1 = e_[x][1]*inv, v2 = e_[x][2]*inv, v3 = e_[x][3]*inv;
    cp[0] += v0; cp[1] += v1; cp[2] += v2; cp[3] += v3;
    float4 o; o.x = v0; o.y = v1; o.z = v2; o.w = v3;
    *(float4*)&u[(long)bh*MM*MM + (ti*4+x)*MM + tj*4] = o;
  }
  #pragma unroll
  for (int y = 0; y < 4; ++y) {
    cp[y] += __shfl_xor(cp[y], 16);
    cp[y] += __shfl_xor(cp[y], 32);
  }
  if (((tid >> 4) & 3) == 0) {
    #pragma unroll
    for (int y = 0; y < 4; ++y) cs[tid >> 6][tj*4 + y] = cp[y];
  }
  __syncthreads();
  if (tid < 64) {
    float tot = cs[0][tid] + cs[1][tid] + cs[2][tid] + cs[3][tid];
    for (int off = 32; off; off >>= 1) tot = fmaxf(tot, __shfl_xor(tot, off));
    if (tid == 0) smax[bh] = tot;
  }
}

// ---------------- Newton-Schulz inverse, 6 iters, 64x64 per (bh)
__global__ __launch_bounds__(256) void k_newton(const float* __restrict__ u,
    const float* __restrict__ smax, float* __restrict__ vinv) {
  int bh = blockIdx.x, tid = threadIdx.x, ti = tid >> 4, tj = tid & 15;
  __shared__ float Km[MM][MM];
  __shared__ float Vm[MM][MM];
  __shared__ float T1[MM][MM];
  __shared__ float T2[MM][MM];
  __shared__ float gmx;
  const float* pu = u + (long)bh * MM * MM;
  for (int e = tid; e < MM * MM; e += 256) Km[e >> 6][e & 63] = pu[e];
  if (tid < 64) {
    float v = (tid < 32) ? smax[tid] : 0.f;    // colsum maxes are positive
    for (int off = 32; off; off >>= 1) v = fmaxf(v, __shfl_xor(v, off));
    if (tid == 0) gmx = v;
  }
  __syncthreads();
  float invs = 1.0f / gmx;
  for (int e = tid; e < MM * MM; e += 256) {
    int i = e >> 6, j = e & 63;
    Vm[i][j] = Km[j][i] * invs;
  }
  __syncthreads();
  for (int it = 0; it < 6; ++it) {
    float acc[4][4];
    #pragma unroll
    for (int x=0;x<4;++x) for (int y=0;y<4;++y) acc[x][y] = 0.f;
    mm_acc<MM, MM>(acc, Km, Vm, ti, tj);
    #pragma unroll
    for (int x = 0; x < 4; ++x)
      #pragma unroll
      for (int y = 0; y < 4; ++y) {
        int i = ti*4+x, j = tj*4+y;
        T1[i][j] = acc[x][y];
        T2[i][j] = (i == j ? 7.f : 0.f) - acc[x][y];
      }
    __syncthreads();
    #pragma unroll
    for (int x=0;x<4;++x) for (int y=0;y<4;++y) acc[x][y] = 0.f;
    mm_acc<MM, MM>(acc, T1, T2, ti, tj);
    __syncthreads();
    #pragma unroll
    for (int x = 0; x < 4; ++x)
      #pragma unroll
      for (int y = 0; y < 4; ++y) {
        int i = ti*4+x, j = tj*4+y;
        T2[i][j] = (i == j ? 15.f : 0.f) - acc[x][y];
      }
    __syncthreads();
    #pragma unroll
    for (int x=0;x<4;++x) for (int y=0;y<4;++y) acc[x][y] = 0.f;
    mm_acc<MM, MM>(acc, T1, T2, ti, tj);
    __syncthreads();
    #pragma unroll
    for (int x = 0; x < 4; ++x)
      #pragma unroll
      for (int y = 0; y < 4; ++y) {
        int i = ti*4+x, j = tj*4+y;
        T2[i][j] = (i == j ? 13.f : 0.f) - acc[x][y];
      }
    __syncthreads();
    #pragma unroll
    for (int x=0;x<4;++x) for (int y=0;y<4;++y) acc[x][y] = 0.f;
    mm_acc<MM, MM>(acc, Vm, T2, ti, tj);
    __syncthreads();
    #pragma unroll
    for (int x = 0; x < 4; ++x)
      #pragma unroll
      for (int y = 0; y < 4; ++y) Vm[ti*4+x][tj*4+y] = 0.25f * acc[x][y];
    __syncthreads();
  }
  for (int e = tid; e < MM * MM; e += 256) vinv[(long)bh*MM*MM + e] = Vm[e >> 6][e & 63];
}

// ---------------- MFMA partials of kernel_3 @ V  (exp masked to mask==1), atomic-free
// Swapped QK^T: S^T = K @ nr^T so P^T C-regs ARE the A-frag of the PV mfma.
__global__ __launch_bounds__(256) void k_w3(const float* __restrict__ Kg,
    const float* __restrict__ Vg, const int* __restrict__ maskg,
    const float* __restrict__ nr, float* __restrict__ nump, float* __restrict__ denp) {
  int bh = blockIdx.x, grp = blockIdx.y, b = bh >> 3;
  int tid = threadIdx.x;
  int wave = tid >> 6, lane = tid & 63;
  int lm = lane & 15, hi = lane >> 4;
  __shared__ f16 Ks[64][72];   // stride 144B = 9*16B: aligned b128, 2-way banks (free)
  __shared__ f16 Vs[64][72];
  __shared__ float kmul[64];

  // nr B-fragments for this wave's m-tile (rows m0..m0+15), k = d split in halves
  int m0 = wave * 16;
  f16x8 nrf[2];
  {
    const float* p = nr + (long)bh*MM*DD + (long)(m0 + lm)*DD + hi*8;
    float4 q0 = *(const float4*)p;
    float4 q1 = *(const float4*)(p + 4);
    float4 q2 = *(const float4*)(p + 32);
    float4 q3 = *(const float4*)(p + 36);
    nrf[0][0]=(f16)q0.x; nrf[0][1]=(f16)q0.y; nrf[0][2]=(f16)q0.z; nrf[0][3]=(f16)q0.w;
    nrf[0][4]=(f16)q1.x; nrf[0][5]=(f16)q1.y; nrf[0][6]=(f16)q1.z; nrf[0][7]=(f16)q1.w;
    nrf[1][0]=(f16)q2.x; nrf[1][1]=(f16)q2.y; nrf[1][2]=(f16)q2.z; nrf[1][3]=(f16)q2.w;
    nrf[1][4]=(f16)q3.x; nrf[1][5]=(f16)q3.y; nrf[1][6]=(f16)q3.z; nrf[1][7]=(f16)q3.w;
  }

  f32x4 nacc[4];
  #pragma unroll
  for (int dt = 0; dt < 4; ++dt) nacc[dt] = (f32x4){0.f, 0.f, 0.f, 0.f};
  float dsum = 0.f;

  for (int sc = 0; sc < 4; ++sc) {
    int n0c = (grp * 4 + sc) * 64;
    if (sc) __syncthreads();
    // stage K,V chunk fp32->fp16
    for (int s = tid; s < 1024; s += 256) {
      int row = s >> 4, c4 = s & 15;
      float4 kv = *(const float4*)&Kg[((long)bh*NTOK + n0c + row)*DD + c4*4];
      float4 vv = *(const float4*)&Vg[((long)bh*NTOK + n0c + row)*DD + c4*4];
      f16x4 kk = {(f16)kv.x, (f16)kv.y, (f16)kv.z, (f16)kv.w};
      f16x4 vv4 = {(f16)vv.x, (f16)vv.y, (f16)vv.z, (f16)vv.w};
      *(f16x4*)&Ks[row][c4*4] = kk;
      *(f16x4*)&Vs[row][c4*4] = vv4;
    }
    if (tid < 64) kmul[tid] = maskg[b * NTOK + n0c + tid] ? 1.f : 0.f;
    __syncthreads();

    // S^T tiles: rows n (chunk tokens), cols m (wave's m-tile)
    f32x4 st[4];
    #pragma unroll
    for (int g = 0; g < 4; ++g) {
      f16x8 a0 = *(const f16x8*)&Ks[g*16 + lm][hi*8];
      f16x8 a1 = *(const f16x8*)&Ks[g*16 + lm][32 + hi*8];
      f32x4 c = {0.f, 0.f, 0.f, 0.f};
      c = __builtin_amdgcn_mfma_f32_16x16x32_f16(a0, nrf[0], c, 0, 0, 0);
      c = __builtin_amdgcn_mfma_f32_16x16x32_f16(a1, nrf[1], c, 0, 0, 0);
      st[g] = c;
    }
    // P = keep * exp(S); pack into A-frags for PV (k = token, kappa(hi,j)=hi*4+(j&3)+16*(j>>2))
    f16x8 pa[2];
    #pragma unroll
    for (int g = 0; g < 4; ++g) {
      #pragma unroll
      for (int r = 0; r < 4; ++r) {
        float p = __expf(st[g][r]) * kmul[g*16 + hi*4 + r];
        dsum += p;
        pa[g >> 1][(g & 1)*4 + r] = (f16)p;
      }
    }
    // num += P @ V
    #pragma unroll
    for (int dt = 0; dt < 4; ++dt) {
      f16x8 vb0, vb1;
      #pragma unroll
      for (int j = 0; j < 8; ++j) {
        int nrow = hi*4 + (j & 3) + 16*(j >> 2);
        vb0[j] = Vs[nrow][dt*16 + lm];
        vb1[j] = Vs[32 + nrow][dt*16 + lm];
      }
      nacc[dt] = __builtin_amdgcn_mfma_f32_16x16x32_f16(pa[0], vb0, nacc[dt], 0, 0, 0);
      nacc[dt] = __builtin_amdgcn_mfma_f32_16x16x32_f16(pa[1], vb1, nacc[dt], 0, 0, 0);
    }
  }
  // write partials
  float* pnum = nump + ((long)bh * GPART + grp) * (MM * DD);
  #pragma unroll
  for (int dt = 0; dt < 4; ++dt)
    #pragma unroll
    for (int r = 0; r < 4; ++r)
      pnum[(m0 + hi*4 + r)*DD + dt*16 + lm] = nacc[dt][r];
  float d2 = dsum + __shfl_xor(dsum, 16);
  d2 += __shfl_xor(d2, 32);
  if (lane < 16)
    denp[((long)bh * GPART + grp) * MM + m0 + lane] = d2;
}

// ---------------- Z = Vinv @ (sum_g num_g / sum_g den_g)
__global__ __launch_bounds__(256) void k_z(const float* __restrict__ vinv,
    const float* __restrict__ nump, const float* __restrict__ denp, float* __restrict__ Zg) {
  int bh = blockIdx.x, tid = threadIdx.x, ti = tid >> 4, tj = tid & 15;
  __shared__ float A[MM][PAD];
  __shared__ float W[MM][MM];
  __shared__ float dn[MM];
  if (tid < 64) {
    float s = 0.f;
    #pragma unroll
    for (int g = 0; g < GPART; ++g) s += denp[((long)bh * GPART + g) * MM + tid];
    dn[tid] = s;
  }
  for (int e = tid; e < 1024; e += 256) {
    int m = e >> 4, d4 = e & 15;
    *(float4*)&A[m][d4*4] = *(const float4*)&vinv[(long)bh*MM*MM + m*MM + d4*4];
  }
  __syncthreads();
  for (int e = tid; e < 1024; e += 256) {
    int m = e >> 4, d4 = e & 15;
    float4 s = {0.f, 0.f, 0.f, 0.f};
    #pragma unroll
    for (int g = 0; g < GPART; ++g) {
      float4 t = *(const float4*)&nump[((long)bh * GPART + g) * (MM*DD) + m*DD + d4*4];
      s.x += t.x; s.y += t.y; s.z += t.z; s.w += t.w;
    }
    float inv = 1.f / dn[m];
    s.x *= inv; s.y *= inv; s.z *= inv; s.w *= inv;
    *(float4*)&W[m][d4*4] = s;
  }
  __syncthreads();
  float acc[4][4] = {};
  mm_acc<PAD, MM>(acc, A, W, ti, tj);
  #pragma unroll
  for (int x = 0; x < 4; ++x) {
    float4 o; o.x = acc[x][0]; o.y = acc[x][1]; o.z = acc[x][2]; o.w = acc[x][3];
    *(float4*)&Zg[(long)bh*MM*DD + (ti*4+x)*DD + tj*4] = o;
  }
}

// ---------------- MFMA X = row-softmax(Qs @ nc^T) @ Z  (swapped S^T trick again)
__global__ __launch_bounds__(256) void k_final(const float* __restrict__ Qg,
    const float* __restrict__ nc, const float* __restrict__ Zg, float* __restrict__ Xg) {
  int bh = blockIdx.x, chunk = blockIdx.y;
  int tid = threadIdx.x;
  int wave = tid >> 6, lane = tid & 63;
  int lm = lane & 15, hi = lane >> 4;
  int n0 = chunk * 64;
  __shared__ f16 Qs[64][72];
  __shared__ f16 Ncs[64][72];
  __shared__ f16 Zs[64][72];
  // stage Q (scaled), nc, Z -> fp16 LDS
  for (int s = tid; s < 1024; s += 256) {
    int row = s >> 4, c4 = s & 15;
    float4 q = *(const float4*)&Qg[((long)bh*NTOK + n0 + row)*DD + c4*4];
    f16x4 qq = {(f16)(q.x*0.125f), (f16)(q.y*0.125f), (f16)(q.z*0.125f), (f16)(q.w*0.125f)};
    *(f16x4*)&Qs[row][c4*4] = qq;
    float4 cv = *(const float4*)&nc[(long)bh*MM*DD + row*DD + c4*4];
    f16x4 cc = {(f16)cv.x, (f16)cv.y, (f16)cv.z, (f16)cv.w};
    *(f16x4*)&Ncs[row][c4*4] = cc;
    float4 zv = *(const float4*)&Zg[(long)bh*MM*DD + row*DD + c4*4];
    f16x4 zz = {(f16)zv.x, (f16)zv.y, (f16)zv.z, (f16)zv.w};
    *(f16x4*)&Zs[row][c4*4] = zz;
  }
  __syncthreads();

  // B-frags: this wave's 16 Q rows (cols of S^T)
  f16x8 qb0 = *(const f16x8*)&Qs[wave*16 + lm][hi*8];
  f16x8 qb1 = *(const f16x8*)&Qs[wave*16 + lm][32 + hi*8];
  // S^T tiles: rows m (4 tiles of 16), cols n
  f32x4 st[4];
  #pragma unroll
  for (int mt = 0; mt < 4; ++mt) {
    f16x8 a0 = *(const f16x8*)&Ncs[mt*16 + lm][hi*8];
    f16x8 a1 = *(const f16x8*)&Ncs[mt*16 + lm][32 + hi*8];
    f32x4 c = {0.f, 0.f, 0.f, 0.f};
    c = __builtin_amdgcn_mfma_f32_16x16x32_f16(a0, qb0, c, 0, 0, 0);
    c = __builtin_amdgcn_mfma_f32_16x16x32_f16(a1, qb1, c, 0, 0, 0);
    st[mt] = c;
  }
  // P^T -> exp, den over all 64 m, pack A-frags (k=m)
  f16x8 pa[2];
  float dsum = 0.f;
  #pragma unroll
  for (int mt = 0; mt < 4; ++mt) {
    #pragma unroll
    for (int r = 0; r < 4; ++r) {
      float p = __expf(st[mt][r]);
      dsum += p;
      pa[mt >> 1][(mt & 1)*4 + r] = (f16)p;
    }
  }
  float dtot = dsum + __shfl_xor(dsum, 16);
  dtot += __shfl_xor(dtot, 32);            // every lane: den for n = lm
  // X = P @ Z
  f32x4 xacc[4];
  #pragma unroll
  for (int dt = 0; dt < 4; ++dt) {
    f16x8 zb0, zb1;
    #pragma unroll
    for (int j = 0; j < 8; ++j) {
      int mrow = hi*4 + (j & 3) + 16*(j >> 2);
      zb0[j] = Zs[mrow][dt*16 + lm];
      zb1[j] = Zs[32 + mrow][dt*16 + lm];
    }
    f32x4 c = {0.f, 0.f, 0.f, 0.f};
    c = __builtin_amdgcn_mfma_f32_16x16x32_f16(pa[0], zb0, c, 0, 0, 0);
    c = __builtin_amdgcn_mfma_f32_16x16x32_f16(pa[1], zb1, c, 0, 0, 0);
    xacc[dt] = c;
  }
  // divide by den of row n = hi*4+r and store
  float rn[4];
  #pragma unroll
  for (int r = 0; r < 4; ++r) rn[r] = 1.f / __shfl(dtot, hi*4 + r);
  #pragma unroll
  for (int dt = 0; dt < 4; ++dt)
    #pragma unroll
    for (int r = 0; r < 4; ++r)
      Xg[((long)bh*NTOK + n0 + wave*16 + hi*4 + r)*DD + dt*16 + lm] = xacc[dt][r] * rn[r];
}

extern "C" void kernel_launch(void* const* d_in, const int* in_sizes, int n_in,
                              void* d_out, int out_size, void* d_ws, size_t ws_size,
                              hipStream_t stream) {
  (void)in_sizes; (void)n_in; (void)out_size; (void)ws_size;
  const float* Qp = (const float*)d_in[0];
  const float* Kp = (const float*)d_in[1];
  const float* Vp = (const float*)d_in[2];
  const int* maskp = (const int*)d_in[3];
  float* out = (float*)d_out;

  float* wsf = (float*)d_ws;
  float* NUMP = wsf;                                // 32*16*4096
  float* DENP = NUMP + (long)BHN * GPART * MM * DD; // 32*16*64
  float* SMAX = DENP + BHN * GPART * MM;            // 32
  float* NC = SMAX + 32;
  float* NR = NC + BHN * MM * DD;
  float* U  = NR + BHN * MM * DD;
  float* VI = U  + BHN * MM * MM;
  float* Zb = VI + BHN * MM * MM;
  float* SK = Zb + BHN * MM * DD;
  float* SQ = SK + BHN * NTOK;

  k_somme<<<16384, 256, 0, stream>>>(Kp, Qp, maskp, SK, SQ);
  k_select<<<dim3(32, 2), 256, 0, stream>>>(Kp, Qp, SK, SQ, NC, NR);
  k_u<<<32, 256, 0, stream>>>(NC, NR, U, SMAX);
  k_newton<<<32, 256, 0, stream>>>(U, SMAX, VI);
  k_w3<<<dim3(32, GPART), 256, 0, stream>>>(Kp, Vp, maskp, NR, NUMP, DENP);
  k_z<<<32, 256, 0, stream>>>(VI, NUMP, DENP, Zb);
  k_final<<<dim3(32, 64), 256, 0, stream>>>(Qp, NC, Zb, out);
}

// Round 4
// 104.682 us; speedup vs baseline: 5.7026x; 1.3677x over previous
//
#include <hip/hip_runtime.h>
#include <float.h>

#define BB 4
#define HH 8
#define BHN 32
#define NTOK 4096
#define DD 64
#define MM 64
#define PAD 68
#define GPART 16

typedef _Float16 f16;
typedef __attribute__((ext_vector_type(4))) _Float16 f16x4;
typedef __attribute__((ext_vector_type(8))) _Float16 f16x8;
typedef __attribute__((ext_vector_type(4))) float f32x4;

union V8U { f16x8 v; f16x4 q[2]; };

__device__ __forceinline__ void fsplit(float v, f16* h, f16* l) {
  f16 hh = (f16)v;
  *h = hh;
  *l = (f16)(v - (float)hh);
}

// 6-term fp32-faithful f16-split mfma: C = A@B with A=Ah+Al, B=Bh+Bl (drop Al*Bl)
__device__ __forceinline__ f32x4 mm6(f16x8 ah0, f16x8 ah1, f16x8 al0, f16x8 al1,
                                     f16x8 bh0, f16x8 bh1, f16x8 bl0, f16x8 bl1) {
  f32x4 a = {0.f, 0.f, 0.f, 0.f};
  a = __builtin_amdgcn_mfma_f32_16x16x32_f16(ah0, bh0, a, 0, 0, 0);
  a = __builtin_amdgcn_mfma_f32_16x16x32_f16(ah1, bh1, a, 0, 0, 0);
  a = __builtin_amdgcn_mfma_f32_16x16x32_f16(ah0, bl0, a, 0, 0, 0);
  a = __builtin_amdgcn_mfma_f32_16x16x32_f16(ah1, bl1, a, 0, 0, 0);
  a = __builtin_amdgcn_mfma_f32_16x16x32_f16(al0, bh0, a, 0, 0, 0);
  a = __builtin_amdgcn_mfma_f32_16x16x32_f16(al1, bh1, a, 0, 0, 0);
  return a;
}

// ---------------- 4x4-tile 64x64x64 matmul helper (fp32 scalar, small kernels)
template<int LDA, int LDB>
__device__ __forceinline__ void mm_acc(float acc[4][4],
    const float (*A)[LDA], const float (*B)[LDB], int ti, int tj) {
  #pragma unroll
  for (int k4 = 0; k4 < 16; ++k4) {
    float a[4][4], b[4][4];
    #pragma unroll
    for (int x = 0; x < 4; ++x) {
      float4 t = *(const float4*)&A[ti*4+x][k4*4];
      a[x][0]=t.x; a[x][1]=t.y; a[x][2]=t.z; a[x][3]=t.w;
    }
    #pragma unroll
    for (int kk = 0; kk < 4; ++kk) {
      float4 t = *(const float4*)&B[k4*4+kk][tj*4];
      b[kk][0]=t.x; b[kk][1]=t.y; b[kk][2]=t.z; b[kk][3]=t.w;
    }
    #pragma unroll
    for (int kk = 0; kk < 4; ++kk)
      #pragma unroll
      for (int x = 0; x < 4; ++x)
        #pragma unroll
        for (int y = 0; y < 4; ++y)
          acc[x][y] = fmaf(a[x][kk], b[kk][y], acc[x][y]);
  }
}

// ---------------- row sums for selection (both K and Q), mask/token0 -> -FLT_MAX
__global__ __launch_bounds__(256) void k_somme(const float* __restrict__ Kg,
    const float* __restrict__ Qg, const int* __restrict__ mask,
    float* __restrict__ somK, float* __restrict__ somQ) {
  int tid = threadIdx.x;
  int lane = tid & 63;
  long grow = (long)blockIdx.x * 16 + (tid >> 6) * 4 + (lane >> 4);
  int which = grow >= (long)(BHN * NTOK);
  long row = which ? grow - (long)BHN * NTOK : grow;   // bh*N + n
  int n = (int)(row & (NTOK - 1));
  int bh = (int)(row >> 12);
  int b = bh >> 3;
  const float* src = which ? Qg : Kg;
  float4 v = *((const float4*)(src + row * DD) + (lane & 15));
  float s = v.x + v.y + v.z + v.w;
  s += __shfl_xor(s, 1); s += __shfl_xor(s, 2);
  s += __shfl_xor(s, 4); s += __shfl_xor(s, 8);
  if ((lane & 15) == 0) {
    float out = (n == 0 || mask[b * NTOK + n] != 0) ? -FLT_MAX : s;
    (which ? somQ : somK)[row] = out;
  }
}

// ---------------- per-(bh,which): radix top-63 select + token 0 + index-sorted gather
__global__ __launch_bounds__(256) void k_select(const float* __restrict__ Kg,
    const float* __restrict__ Qg, const float* __restrict__ somK,
    const float* __restrict__ somQ, float* __restrict__ nc, float* __restrict__ nr) {
  int bh = blockIdx.x;
  int which = blockIdx.y;           // 0: K -> nc, 1: Q (scaled) -> nr
  __shared__ unsigned int keys[NTOK];      // 16KB
  __shared__ int flg[NTOK];                // 16KB
  __shared__ unsigned int bins[256];
  __shared__ unsigned int cum[257];
  __shared__ int sh_bin, sh_need;
  __shared__ int sel[MM];
  int tid = threadIdx.x;
  const float* som = (which ? somQ : somK) + (long)bh * NTOK;
  for (int i = tid; i < NTOK; i += 256) {
    float f = som[i];
    unsigned int u = __float_as_uint(f);
    u = (u & 0x80000000u) ? ~u : (u | 0x80000000u);   // monotone map, ascending
    if (i == 0) u = 0u;                               // token 0 excluded from competition
    keys[i] = u;
  }
  __syncthreads();

  // --- 4-pass radix select: find exact key of the 63rd largest ---
  unsigned int pref = 0; int need = MM - 1;           // 63
  for (int pass = 0; pass < 4; ++pass) {
    int shift = 24 - pass * 8;
    unsigned int pm = (pass == 0) ? 0u : (0xFFFFFFFFu << (32 - 8 * pass));
    bins[tid] = 0;
    __syncthreads();
    for (int i = tid; i < NTOK; i += 256) {
      unsigned int k = keys[i];
      if ((k & pm) == pref) atomicAdd(&bins[(k >> shift) & 255], 1u);
    }
    __syncthreads();
    // inclusive suffix scan: cum[i] = sum_{j>=i} bins[j]
    cum[tid] = bins[tid];
    __syncthreads();
    for (int st = 1; st < 256; st <<= 1) {
      unsigned int add = (tid + st < 256) ? cum[tid + st] : 0u;
      __syncthreads();
      cum[tid] += add;
      __syncthreads();
    }
    unsigned int above = (tid < 255) ? cum[tid + 1] : 0u;
    if (cum[tid] >= (unsigned)need && above < (unsigned)need) {
      sh_bin = tid; sh_need = need - (int)above;
    }
    __syncthreads();
    pref |= ((unsigned)sh_bin) << shift;
    need = sh_need;
    __syncthreads();
  }
  unsigned int thr = pref;

  // --- tie ranking (ties at thr take smallest indices), contiguous segments ---
  int base = tid * 16;
  int ctie = 0;
  #pragma unroll
  for (int j = 0; j < 16; ++j) ctie += (keys[base + j] == thr);
  cum[tid] = (unsigned)ctie;
  __syncthreads();
  for (int st = 1; st < 256; st <<= 1) {
    unsigned int add = (tid >= st) ? cum[tid - st] : 0u;
    __syncthreads();
    cum[tid] += add;
    __syncthreads();
  }
  int tieoff = (int)cum[tid] - ctie;   // exclusive prefix of ties by index order
  int cnt = 0;
  #pragma unroll
  for (int j = 0; j < 16; ++j) {
    unsigned int k = keys[base + j];
    int f = (k > thr) ? 1 : 0;
    if (k == thr) { f = (tieoff < need) ? 1 : 0; ++tieoff; }
    if (base + j == 0) f = 1;          // always keep token 0
    flg[base + j] = f;
    cnt += f;
  }
  __syncthreads();
  // --- compaction prefix: positions in ascending-index order == sorted ---
  cum[tid] = (unsigned)cnt;
  __syncthreads();
  for (int st = 1; st < 256; st <<= 1) {
    unsigned int add = (tid >= st) ? cum[tid - st] : 0u;
    __syncthreads();
    cum[tid] += add;
    __syncthreads();
  }
  int off = (int)cum[tid] - cnt;
  #pragma unroll
  for (int j = 0; j < 16; ++j)
    if (flg[base + j]) sel[off++] = base + j;
  __syncthreads();

  // --- gather selected rows ---
  const float* src = which ? Qg : Kg;
  float* dst = (which ? nr : nc) + (long)bh * MM * DD;
  float scale = which ? 0.125f : 1.0f;
  for (int e = tid; e < MM * 16; e += 256) {
    int i = e >> 4, d4 = e & 15;
    float4 v = *(const float4*)&src[((long)bh * NTOK + sel[i]) * DD + d4 * 4];
    v.x *= scale; v.y *= scale; v.z *= scale; v.w *= scale;
    *(float4*)&dst[i * DD + d4 * 4] = v;
  }
}

// ---------------- u = row-softmax(nr @ nc^T); write u; per-bh colsum max
__global__ __launch_bounds__(256) void k_u(const float* __restrict__ nc,
    const float* __restrict__ nr, float* __restrict__ u, float* __restrict__ smax) {
  int bh = blockIdx.x, tid = threadIdx.x, ti = tid >> 4, tj = tid & 15;
  __shared__ float A[MM][PAD];
  __shared__ float BT[DD][MM];
  __shared__ float cs[4][MM];
  for (int e = tid; e < 1024; e += 256) {
    int m = e >> 4, d4 = e & 15;
    *(float4*)&A[m][d4*4] = *(const float4*)&nr[(long)bh*MM*DD + m*DD + d4*4];
    float4 c = *(const float4*)&nc[(long)bh*MM*DD + m*DD + d4*4];
    BT[d4*4+0][m] = c.x; BT[d4*4+1][m] = c.y; BT[d4*4+2][m] = c.z; BT[d4*4+3][m] = c.w;
  }
  __syncthreads();
  float acc[4][4] = {};
  mm_acc<PAD, MM>(acc, A, BT, ti, tj);
  float e_[4][4];
  #pragma unroll
  for (int x = 0; x < 4; ++x)
    #pragma unroll
    for (int y = 0; y < 4; ++y) e_[x][y] = expf(acc[x][y]);
  float rsx[4];
  #pragma unroll
  for (int x = 0; x < 4; ++x) {
    rsx[x] = e_[x][0] + e_[x][1] + e_[x][2] + e_[x][3];
    rsx[x] += __shfl_xor(rsx[x], 1); rsx[x] += __shfl_xor(rsx[x], 2);
    rsx[x] += __shfl_xor(rsx[x], 4); rsx[x] += __shfl_xor(rsx[x], 8);
  }
  float cp[4] = {0.f, 0.f, 0.f, 0.f};
  #pragma unroll
  for (int x = 0; x < 4; ++x) {
    float inv = 1.f / rsx[x];
    float v0 = e_[x][0]*inv, v1 = e_[x][1]*inv, v2 = e_[x][2]*inv, v3 = e_[x][3]*inv;
    cp[0] += v0; cp[1] += v1; cp[2] += v2; cp[3] += v3;
    float4 o; o.x = v0; o.y = v1; o.z = v2; o.w = v3;
    *(float4*)&u[(long)bh*MM*MM + (ti*4+x)*MM + tj*4] = o;
  }
  #pragma unroll
  for (int y = 0; y < 4; ++y) {
    cp[y] += __shfl_xor(cp[y], 16);
    cp[y] += __shfl_xor(cp[y], 32);
  }
  if (((tid >> 4) & 3) == 0) {
    #pragma unroll
    for (int y = 0; y < 4; ++y) cs[tid >> 6][tj*4 + y] = cp[y];
  }
  __syncthreads();
  if (tid < 64) {
    float tot = cs[0][tid] + cs[1][tid] + cs[2][tid] + cs[3][tid];
    for (int off = 32; off; off >>= 1) tot = fmaxf(tot, __shfl_xor(tot, off));
    if (tid == 0) smax[bh] = tot;
  }
}

// ---------------- Newton-Schulz inverse via f16-split MFMA, 6 iters, 64x64 per (bh)
// S kept entirely in registers (S^T C-regs -> kappa'-packed A-frags for steps 2,3).
__global__ __launch_bounds__(256) void k_newton(const float* __restrict__ u,
    const float* __restrict__ smax, float* __restrict__ vinv) {
  int bh = blockIdx.x, tid = threadIdx.x;
  int wave = tid >> 6, lane = tid & 63;
  int lm = lane & 15, hi = lane >> 4;
  __shared__ f16 Kr_h[64][72], Kr_l[64][72];   // K (=u) row-major
  __shared__ f16 VT_h[64][72], VT_l[64][72];   // V^T row-major
  __shared__ f16 Vr_h[64][72], Vr_l[64][72];   // V row-major
  __shared__ f16 PT_h[64][72], PT_l[64][72];   // P^T, later reused for W^T
  __shared__ f16 RT_h[64][72], RT_l[64][72];   // R^T

  float gmx = smax[0];
  #pragma unroll
  for (int i = 1; i < 32; ++i) gmx = fmaxf(gmx, smax[i]);
  float c0 = 1.0f / gmx;

  const float* pu = u + (long)bh * MM * MM;
  for (int e = tid; e < 4096; e += 256) {
    int i = e >> 6, j = e & 63;
    float v = pu[e];
    f16 h, l;
    fsplit(v, &h, &l);
    Kr_h[i][j] = h; Kr_l[i][j] = l;
    float sv = v * c0;
    fsplit(sv, &h, &l);
    VT_h[i][j] = h; VT_l[i][j] = l;    // V0^T = c*K
    Vr_h[j][i] = h; Vr_l[j][i] = l;    // V0 = c*K^T
  }
  __syncthreads();

  // hoisted B-frag of K (rows 16w+lm), k contiguous
  f16x8 kb_h[2], kb_l[2];
  kb_h[0] = *(const f16x8*)&Kr_h[wave*16 + lm][hi*8];
  kb_h[1] = *(const f16x8*)&Kr_h[wave*16 + lm][32 + hi*8];
  kb_l[0] = *(const f16x8*)&Kr_l[wave*16 + lm][hi*8];
  kb_l[1] = *(const f16x8*)&Kr_l[wave*16 + lm][32 + hi*8];

  for (int it = 0; it < 6; ++it) {
    // ---- step 1: S^T slice (rows all, cols 16w..16w+16) = mfma(VT rows, K rows) ----
    f32x4 st[4];
    #pragma unroll
    for (int g = 0; g < 4; ++g) {
      f16x8 ah0 = *(const f16x8*)&VT_h[g*16 + lm][hi*8];
      f16x8 ah1 = *(const f16x8*)&VT_h[g*16 + lm][32 + hi*8];
      f16x8 al0 = *(const f16x8*)&VT_l[g*16 + lm][hi*8];
      f16x8 al1 = *(const f16x8*)&VT_l[g*16 + lm][32 + hi*8];
      st[g] = mm6(ah0, ah1, al0, al1, kb_h[0], kb_h[1], kb_l[0], kb_l[1]);
    }
    // S A-frags (S rows 16w+lm, kappa'(hi,j) = hi*4+(j&3)+16*(j>>2) per k-half)
    f16x8 sa_h[2], sa_l[2];
    #pragma unroll
    for (int g = 0; g < 4; ++g)
      #pragma unroll
      for (int r = 0; r < 4; ++r) {
        f16 h, l; fsplit(st[g][r], &h, &l);
        sa_h[g >> 1][(g & 1)*4 + r] = h;
        sa_l[g >> 1][(g & 1)*4 + r] = l;
      }
    // write PT = 7I - S^T
    #pragma unroll
    for (int g = 0; g < 4; ++g)
      #pragma unroll
      for (int r = 0; r < 4; ++r) {
        int i = g*16 + hi*4 + r, j = wave*16 + lm;
        float pv = (i == j ? 7.f : 0.f) - st[g][r];
        f16 h, l; fsplit(pv, &h, &l);
        PT_h[i][j] = h; PT_l[i][j] = l;
      }
    __syncthreads();

    // ---- step 2: R = 15I - S@P (B-frag from PT at kappa'); write RT ----
    #pragma unroll
    for (int cc = 0; cc < 4; ++cc) {
      V8U bh0, bh1, bl0, bl1;
      bh0.q[0] = *(const f16x4*)&PT_h[cc*16 + lm][hi*4];
      bh0.q[1] = *(const f16x4*)&PT_h[cc*16 + lm][16 + hi*4];
      bh1.q[0] = *(const f16x4*)&PT_h[cc*16 + lm][32 + hi*4];
      bh1.q[1] = *(const f16x4*)&PT_h[cc*16 + lm][48 + hi*4];
      bl0.q[0] = *(const f16x4*)&PT_l[cc*16 + lm][hi*4];
      bl0.q[1] = *(const f16x4*)&PT_l[cc*16 + lm][16 + hi*4];
      bl1.q[0] = *(const f16x4*)&PT_l[cc*16 + lm][32 + hi*4];
      bl1.q[1] = *(const f16x4*)&PT_l[cc*16 + lm][48 + hi*4];
      f32x4 a = mm6(sa_h[0], sa_h[1], sa_l[0], sa_l[1], bh0.v, bh1.v, bl0.v, bl1.v);
      f16x4 wh, wl;
      #pragma unroll
      for (int r = 0; r < 4; ++r) {
        int row = wave*16 + hi*4 + r, col = cc*16 + lm;
        float rv = (row == col ? 15.f : 0.f) - a[r];
        f16 h, l; fsplit(rv, &h, &l);
        wh[r] = h; wl[r] = l;
      }
      *(f16x4*)&RT_h[cc*16 + lm][wave*16 + hi*4] = wh;
      *(f16x4*)&RT_l[cc*16 + lm][wave*16 + hi*4] = wl;
    }
    __syncthreads();

    // ---- step 3: W = 13I - S@R (B-frag from RT at kappa'); write WT into PT bufs ----
    #pragma unroll
    for (int cc = 0; cc < 4; ++cc) {
      V8U bh0, bh1, bl0, bl1;
      bh0.q[0] = *(const f16x4*)&RT_h[cc*16 + lm][hi*4];
      bh0.q[1] = *(const f16x4*)&RT_h[cc*16 + lm][16 + hi*4];
      bh1.q[0] = *(const f16x4*)&RT_h[cc*16 + lm][32 + hi*4];
      bh1.q[1] = *(const f16x4*)&RT_h[cc*16 + lm][48 + hi*4];
      bl0.q[0] = *(const f16x4*)&RT_l[cc*16 + lm][hi*4];
      bl0.q[1] = *(const f16x4*)&RT_l[cc*16 + lm][16 + hi*4];
      bl1.q[0] = *(const f16x4*)&RT_l[cc*16 + lm][32 + hi*4];
      bl1.q[1] = *(const f16x4*)&RT_l[cc*16 + lm][48 + hi*4];
      f32x4 a = mm6(sa_h[0], sa_h[1], sa_l[0], sa_l[1], bh0.v, bh1.v, bl0.v, bl1.v);
      f16x4 wh, wl;
      #pragma unroll
      for (int r = 0; r < 4; ++r) {
        int row = wave*16 + hi*4 + r, col = cc*16 + lm;
        float wv = (row == col ? 13.f : 0.f) - a[r];
        f16 h, l; fsplit(wv, &h, &l);
        wh[r] = h; wl[r] = l;
      }
      *(f16x4*)&PT_h[cc*16 + lm][wave*16 + hi*4] = wh;   // WT
      *(f16x4*)&PT_l[cc*16 + lm][wave*16 + hi*4] = wl;
    }
    __syncthreads();

    // ---- step 4: V' = 0.25 V@W = mfma(Vr rows, WT rows) ----
    f16x8 vh0 = *(const f16x8*)&Vr_h[wave*16 + lm][hi*8];
    f16x8 vh1 = *(const f16x8*)&Vr_h[wave*16 + lm][32 + hi*8];
    f16x8 vl0 = *(const f16x8*)&Vr_l[wave*16 + lm][hi*8];
    f16x8 vl1 = *(const f16x8*)&Vr_l[wave*16 + lm][32 + hi*8];
    #pragma unroll
    for (int cc = 0; cc < 4; ++cc) {
      f16x8 wh0 = *(const f16x8*)&PT_h[cc*16 + lm][hi*8];
      f16x8 wh1 = *(const f16x8*)&PT_h[cc*16 + lm][32 + hi*8];
      f16x8 wl0 = *(const f16x8*)&PT_l[cc*16 + lm][hi*8];
      f16x8 wl1 = *(const f16x8*)&PT_l[cc*16 + lm][32 + hi*8];
      f32x4 a = mm6(vh0, vh1, vl0, vl1, wh0, wh1, wl0, wl1);
      if (it == 5) {
        #pragma unroll
        for (int r = 0; r < 4; ++r)
          vinv[(long)bh*MM*MM + (wave*16 + hi*4 + r)*MM + cc*16 + lm] = 0.25f * a[r];
      } else {
        f16x4 th, tl;
        #pragma unroll
        for (int r = 0; r < 4; ++r) {
          float vv = 0.25f * a[r];
          f16 h, l; fsplit(vv, &h, &l);
          Vr_h[wave*16 + hi*4 + r][cc*16 + lm] = h;
          Vr_l[wave*16 + hi*4 + r][cc*16 + lm] = l;
          th[r] = h; tl[r] = l;
        }
        *(f16x4*)&VT_h[cc*16 + lm][wave*16 + hi*4] = th;
        *(f16x4*)&VT_l[cc*16 + lm][wave*16 + hi*4] = tl;
      }
    }
    __syncthreads();
  }
}

// ---------------- MFMA partials of kernel_3 @ V  (exp masked to mask==1), atomic-free
__global__ __launch_bounds__(256) void k_w3(const float* __restrict__ Kg,
    const float* __restrict__ Vg, const int* __restrict__ maskg,
    const float* __restrict__ nr, float* __restrict__ nump, float* __restrict__ denp) {
  int bh = blockIdx.x, grp = blockIdx.y, b = bh >> 3;
  int tid = threadIdx.x;
  int wave = tid >> 6, lane = tid & 63;
  int lm = lane & 15, hi = lane >> 4;
  __shared__ f16 Ks[64][72];
  __shared__ f16 Vs[64][72];
  __shared__ float kmul[64];

  int m0 = wave * 16;
  f16x8 nrf[2];
  {
    const float* p = nr + (long)bh*MM*DD + (long)(m0 + lm)*DD + hi*8;
    float4 q0 = *(const float4*)p;
    float4 q1 = *(const float4*)(p + 4);
    float4 q2 = *(const float4*)(p + 32);
    float4 q3 = *(const float4*)(p + 36);
    nrf[0][0]=(f16)q0.x; nrf[0][1]=(f16)q0.y; nrf[0][2]=(f16)q0.z; nrf[0][3]=(f16)q0.w;
    nrf[0][4]=(f16)q1.x; nrf[0][5]=(f16)q1.y; nrf[0][6]=(f16)q1.z; nrf[0][7]=(f16)q1.w;
    nrf[1][0]=(f16)q2.x; nrf[1][1]=(f16)q2.y; nrf[1][2]=(f16)q2.z; nrf[1][3]=(f16)q2.w;
    nrf[1][4]=(f16)q3.x; nrf[1][5]=(f16)q3.y; nrf[1][6]=(f16)q3.z; nrf[1][7]=(f16)q3.w;
  }

  f32x4 nacc[4];
  #pragma unroll
  for (int dt = 0; dt < 4; ++dt) nacc[dt] = (f32x4){0.f, 0.f, 0.f, 0.f};
  float dsum = 0.f;

  for (int sc = 0; sc < 4; ++sc) {
    int n0c = (grp * 4 + sc) * 64;
    if (sc) __syncthreads();
    for (int s = tid; s < 1024; s += 256) {
      int row = s >> 4, c4 = s & 15;
      float4 kv = *(const float4*)&Kg[((long)bh*NTOK + n0c + row)*DD + c4*4];
      float4 vv = *(const float4*)&Vg[((long)bh*NTOK + n0c + row)*DD + c4*4];
      f16x4 kk = {(f16)kv.x, (f16)kv.y, (f16)kv.z, (f16)kv.w};
      f16x4 vv4 = {(f16)vv.x, (f16)vv.y, (f16)vv.z, (f16)vv.w};
      *(f16x4*)&Ks[row][c4*4] = kk;
      *(f16x4*)&Vs[row][c4*4] = vv4;
    }
    if (tid < 64) kmul[tid] = maskg[b * NTOK + n0c + tid] ? 1.f : 0.f;
    __syncthreads();

    f32x4 stv[4];
    #pragma unroll
    for (int g = 0; g < 4; ++g) {
      f16x8 a0 = *(const f16x8*)&Ks[g*16 + lm][hi*8];
      f16x8 a1 = *(const f16x8*)&Ks[g*16 + lm][32 + hi*8];
      f32x4 c = {0.f, 0.f, 0.f, 0.f};
      c = __builtin_amdgcn_mfma_f32_16x16x32_f16(a0, nrf[0], c, 0, 0, 0);
      c = __builtin_amdgcn_mfma_f32_16x16x32_f16(a1, nrf[1], c, 0, 0, 0);
      stv[g] = c;
    }
    f16x8 pa[2];
    #pragma unroll
    for (int g = 0; g < 4; ++g) {
      #pragma unroll
      for (int r = 0; r < 4; ++r) {
        float p = __expf(stv[g][r]) * kmul[g*16 + hi*4 + r];
        dsum += p;
        pa[g >> 1][(g & 1)*4 + r] = (f16)p;
      }
    }
    #pragma unroll
    for (int dt = 0; dt < 4; ++dt) {
      f16x8 vb0, vb1;
      #pragma unroll
      for (int j = 0; j < 8; ++j) {
        int nrow = hi*4 + (j & 3) + 16*(j >> 2);
        vb0[j] = Vs[nrow][dt*16 + lm];
        vb1[j] = Vs[32 + nrow][dt*16 + lm];
      }
      nacc[dt] = __builtin_amdgcn_mfma_f32_16x16x32_f16(pa[0], vb0, nacc[dt], 0, 0, 0);
      nacc[dt] = __builtin_amdgcn_mfma_f32_16x16x32_f16(pa[1], vb1, nacc[dt], 0, 0, 0);
    }
  }
  float* pnum = nump + ((long)bh * GPART + grp) * (MM * DD);
  #pragma unroll
  for (int dt = 0; dt < 4; ++dt)
    #pragma unroll
    for (int r = 0; r < 4; ++r)
      pnum[(m0 + hi*4 + r)*DD + dt*16 + lm] = nacc[dt][r];
  float d2 = dsum + __shfl_xor(dsum, 16);
  d2 += __shfl_xor(d2, 32);
  if (lane < 16)
    denp[((long)bh * GPART + grp) * MM + m0 + lane] = d2;
}

// ---------------- Z = Vinv @ (sum_g num_g / sum_g den_g)
__global__ __launch_bounds__(256) void k_z(const float* __restrict__ vinv,
    const float* __restrict__ nump, const float* __restrict__ denp, float* __restrict__ Zg) {
  int bh = blockIdx.x, tid = threadIdx.x, ti = tid >> 4, tj = tid & 15;
  __shared__ float A[MM][PAD];
  __shared__ float W[MM][MM];
  __shared__ float dn[MM];
  if (tid < 64) {
    float s = 0.f;
    #pragma unroll
    for (int g = 0; g < GPART; ++g) s += denp[((long)bh * GPART + g) * MM + tid];
    dn[tid] = s;
  }
  for (int e = tid; e < 1024; e += 256) {
    int m = e >> 4, d4 = e & 15;
    *(float4*)&A[m][d4*4] = *(const float4*)&vinv[(long)bh*MM*MM + m*MM + d4*4];
  }
  __syncthreads();
  for (int e = tid; e < 1024; e += 256) {
    int m = e >> 4, d4 = e & 15;
    float4 s = {0.f, 0.f, 0.f, 0.f};
    #pragma unroll
    for (int g = 0; g < GPART; ++g) {
      float4 t = *(const float4*)&nump[((long)bh * GPART + g) * (MM*DD) + m*DD + d4*4];
      s.x += t.x; s.y += t.y; s.z += t.z; s.w += t.w;
    }
    float inv = 1.f / dn[m];
    s.x *= inv; s.y *= inv; s.z *= inv; s.w *= inv;
    *(float4*)&W[m][d4*4] = s;
  }
  __syncthreads();
  float acc[4][4] = {};
  mm_acc<PAD, MM>(acc, A, W, ti, tj);
  #pragma unroll
  for (int x = 0; x < 4; ++x) {
    float4 o; o.x = acc[x][0]; o.y = acc[x][1]; o.z = acc[x][2]; o.w = acc[x][3];
    *(float4*)&Zg[(long)bh*MM*DD + (ti*4+x)*DD + tj*4] = o;
  }
}

// ---------------- MFMA X = row-softmax(Qs @ nc^T) @ Z  (swapped S^T trick)
__global__ __launch_bounds__(256) void k_final(const float* __restrict__ Qg,
    const float* __restrict__ nc, const float* __restrict__ Zg, float* __restrict__ Xg) {
  int bh = blockIdx.x, chunk = blockIdx.y;
  int tid = threadIdx.x;
  int wave = tid >> 6, lane = tid & 63;
  int lm = lane & 15, hi = lane >> 4;
  int n0 = chunk * 64;
  __shared__ f16 Qs[64][72];
  __shared__ f16 Ncs[64][72];
  __shared__ f16 Zs[64][72];
  for (int s = tid; s < 1024; s += 256) {
    int row = s >> 4, c4 = s & 15;
    float4 q = *(const float4*)&Qg[((long)bh*NTOK + n0 + row)*DD + c4*4];
    f16x4 qq = {(f16)(q.x*0.125f), (f16)(q.y*0.125f), (f16)(q.z*0.125f), (f16)(q.w*0.125f)};
    *(f16x4*)&Qs[row][c4*4] = qq;
    float4 cv = *(const float4*)&nc[(long)bh*MM*DD + row*DD + c4*4];
    f16x4 cc = {(f16)cv.x, (f16)cv.y, (f16)cv.z, (f16)cv.w};
    *(f16x4*)&Ncs[row][c4*4] = cc;
    float4 zv = *(const float4*)&Zg[(long)bh*MM*DD + row*DD + c4*4];
    f16x4 zz = {(f16)zv.x, (f16)zv.y, (f16)zv.z, (f16)zv.w};
    *(f16x4*)&Zs[row][c4*4] = zz;
  }
  __syncthreads();

  f16x8 qb0 = *(const f16x8*)&Qs[wave*16 + lm][hi*8];
  f16x8 qb1 = *(const f16x8*)&Qs[wave*16 + lm][32 + hi*8];
  f32x4 stv[4];
  #pragma unroll
  for (int mt = 0; mt < 4; ++mt) {
    f16x8 a0 = *(const f16x8*)&Ncs[mt*16 + lm][hi*8];
    f16x8 a1 = *(const f16x8*)&Ncs[mt*16 + lm][32 + hi*8];
    f32x4 c = {0.f, 0.f, 0.f, 0.f};
    c = __builtin_amdgcn_mfma_f32_16x16x32_f16(a0, qb0, c, 0, 0, 0);
    c = __builtin_amdgcn_mfma_f32_16x16x32_f16(a1, qb1, c, 0, 0, 0);
    stv[mt] = c;
  }
  f16x8 pa[2];
  float dsum = 0.f;
  #pragma unroll
  for (int mt = 0; mt < 4; ++mt) {
    #pragma unroll
    for (int r = 0; r < 4; ++r) {
      float p = __expf(stv[mt][r]);
      dsum += p;
      pa[mt >> 1][(mt & 1)*4 + r] = (f16)p;
    }
  }
  float dtot = dsum + __shfl_xor(dsum, 16);
  dtot += __shfl_xor(dtot, 32);
  f32x4 xacc[4];
  #pragma unroll
  for (int dt = 0; dt < 4; ++dt) {
    f16x8 zb0, zb1;
    #pragma unroll
    for (int j = 0; j < 8; ++j) {
      int mrow = hi*4 + (j & 3) + 16*(j >> 2);
      zb0[j] = Zs[mrow][dt*16 + lm];
      zb1[j] = Zs[32 + mrow][dt*16 + lm];
    }
    f32x4 c = {0.f, 0.f, 0.f, 0.f};
    c = __builtin_amdgcn_mfma_f32_16x16x32_f16(pa[0], zb0, c, 0, 0, 0);
    c = __builtin_amdgcn_mfma_f32_16x16x32_f16(pa[1], zb1, c, 0, 0, 0);
    xacc[dt] = c;
  }
  float rn[4];
  #pragma unroll
  for (int r = 0; r < 4; ++r) rn[r] = 1.f / __shfl(dtot, hi*4 + r);
  #pragma unroll
  for (int dt = 0; dt < 4; ++dt)
    #pragma unroll
    for (int r = 0; r < 4; ++r)
      Xg[((long)bh*NTOK + n0 + wave*16 + hi*4 + r)*DD + dt*16 + lm] = xacc[dt][r] * rn[r];
}

extern "C" void kernel_launch(void* const* d_in, const int* in_sizes, int n_in,
                              void* d_out, int out_size, void* d_ws, size_t ws_size,
                              hipStream_t stream) {
  (void)in_sizes; (void)n_in; (void)out_size; (void)ws_size;
  const float* Qp = (const float*)d_in[0];
  const float* Kp = (const float*)d_in[1];
  const float* Vp = (const float*)d_in[2];
  const int* maskp = (const int*)d_in[3];
  float* out = (float*)d_out;

  float* wsf = (float*)d_ws;
  float* NUMP = wsf;                                // 32*16*4096
  float* DENP = NUMP + (long)BHN * GPART * MM * DD; // 32*16*64
  float* SMAX = DENP + BHN * GPART * MM;            // 32
  float* NC = SMAX + 32;
  float* NR = NC + BHN * MM * DD;
  float* U  = NR + BHN * MM * DD;
  float* VI = U  + BHN * MM * MM;
  float* Zb = VI + BHN * MM * MM;
  float* SK = Zb + BHN * MM * DD;
  float* SQ = SK + BHN * NTOK;

  k_somme<<<16384, 256, 0, stream>>>(Kp, Qp, maskp, SK, SQ);
  k_select<<<dim3(32, 2), 256, 0, stream>>>(Kp, Qp, SK, SQ, NC, NR);
  k_u<<<32, 256, 0, stream>>>(NC, NR, U, SMAX);
  k_newton<<<32, 256, 0, stream>>>(U, SMAX, VI);
  k_w3<<<dim3(32, GPART), 256, 0, stream>>>(Kp, Vp, maskp, NR, NUMP, DENP);
  k_z<<<32, 256, 0, stream>>>(VI, NUMP, DENP, Zb);
  k_final<<<dim3(32, 64), 256, 0, stream>>>(Qp, NC, Zb, out);
}

// Round 5
// 96.922 us; speedup vs baseline: 6.1591x; 1.0801x over previous
//
#include <hip/hip_runtime.h>
#include <float.h>

#define BB 4
#define HH 8
#define BHN 32
#define NTOK 4096
#define DD 64
#define MM 64
#define PAD 68
#define GPART 16

typedef _Float16 f16;
typedef __attribute__((ext_vector_type(4))) _Float16 f16x4;
typedef __attribute__((ext_vector_type(8))) _Float16 f16x8;
typedef __attribute__((ext_vector_type(4))) float f32x4;

union V8U { f16x8 v; f16x4 q[2]; };

__device__ __forceinline__ void fsplit(float v, f16* h, f16* l) {
  f16 hh = (f16)v;
  *h = hh;
  *l = (f16)(v - (float)hh);
}

// 6-term fp32-faithful f16-split mfma: C = A@B with A=Ah+Al, B=Bh+Bl (drop Al*Bl)
__device__ __forceinline__ f32x4 mm6(f16x8 ah0, f16x8 ah1, f16x8 al0, f16x8 al1,
                                     f16x8 bh0, f16x8 bh1, f16x8 bl0, f16x8 bl1) {
  f32x4 a = {0.f, 0.f, 0.f, 0.f};
  a = __builtin_amdgcn_mfma_f32_16x16x32_f16(ah0, bh0, a, 0, 0, 0);
  a = __builtin_amdgcn_mfma_f32_16x16x32_f16(ah1, bh1, a, 0, 0, 0);
  a = __builtin_amdgcn_mfma_f32_16x16x32_f16(ah0, bl0, a, 0, 0, 0);
  a = __builtin_amdgcn_mfma_f32_16x16x32_f16(ah1, bl1, a, 0, 0, 0);
  a = __builtin_amdgcn_mfma_f32_16x16x32_f16(al0, bh0, a, 0, 0, 0);
  a = __builtin_amdgcn_mfma_f32_16x16x32_f16(al1, bh1, a, 0, 0, 0);
  return a;
}

// ---------------- 4x4-tile 64x64x64 matmul helper (fp32 scalar, small kernels)
template<int LDA, int LDB>
__device__ __forceinline__ void mm_acc(float acc[4][4],
    const float (*A)[LDA], const float (*B)[LDB], int ti, int tj) {
  #pragma unroll
  for (int k4 = 0; k4 < 16; ++k4) {
    float a[4][4], b[4][4];
    #pragma unroll
    for (int x = 0; x < 4; ++x) {
      float4 t = *(const float4*)&A[ti*4+x][k4*4];
      a[x][0]=t.x; a[x][1]=t.y; a[x][2]=t.z; a[x][3]=t.w;
    }
    #pragma unroll
    for (int kk = 0; kk < 4; ++kk) {
      float4 t = *(const float4*)&B[k4*4+kk][tj*4];
      b[kk][0]=t.x; b[kk][1]=t.y; b[kk][2]=t.z; b[kk][3]=t.w;
    }
    #pragma unroll
    for (int kk = 0; kk < 4; ++kk)
      #pragma unroll
      for (int x = 0; x < 4; ++x)
        #pragma unroll
        for (int y = 0; y < 4; ++y)
          acc[x][y] = fmaf(a[x][kk], b[kk][y], acc[x][y]);
  }
}

// ---------------- row sums for selection (both K and Q), mask/token0 -> -FLT_MAX
__global__ __launch_bounds__(256) void k_somme(const float* __restrict__ Kg,
    const float* __restrict__ Qg, const int* __restrict__ mask,
    float* __restrict__ somK, float* __restrict__ somQ) {
  int tid = threadIdx.x;
  int lane = tid & 63;
  long grow = (long)blockIdx.x * 16 + (tid >> 6) * 4 + (lane >> 4);
  int which = grow >= (long)(BHN * NTOK);
  long row = which ? grow - (long)BHN * NTOK : grow;   // bh*N + n
  int n = (int)(row & (NTOK - 1));
  int bh = (int)(row >> 12);
  int b = bh >> 3;
  const float* src = which ? Qg : Kg;
  float4 v = *((const float4*)(src + row * DD) + (lane & 15));
  float s = v.x + v.y + v.z + v.w;
  s += __shfl_xor(s, 1); s += __shfl_xor(s, 2);
  s += __shfl_xor(s, 4); s += __shfl_xor(s, 8);
  if ((lane & 15) == 0) {
    float out = (n == 0 || mask[b * NTOK + n] != 0) ? -FLT_MAX : s;
    (which ? somQ : somK)[row] = out;
  }
}

// ---------------- per-(bh,which): radix top-63 select (wave-shfl scans) + gather
__global__ __launch_bounds__(256) void k_select(const float* __restrict__ Kg,
    const float* __restrict__ Qg, const float* __restrict__ somK,
    const float* __restrict__ somQ, float* __restrict__ nc, float* __restrict__ nr) {
  int bh = blockIdx.x;
  int which = blockIdx.y;           // 0: K -> nc, 1: Q (scaled) -> nr
  __shared__ unsigned int keys[NTOK];       // 16KB
  __shared__ unsigned int wb[4][256];       // per-wave histograms, 4KB
  __shared__ int wsum[4];
  __shared__ int wsumB[4];
  __shared__ int sh_bin, sh_need;
  __shared__ int sel[MM];
  int tid = threadIdx.x, wave = tid >> 6, lane = tid & 63;
  const float* som = (which ? somQ : somK) + (long)bh * NTOK;
  for (int i = tid; i < NTOK; i += 256) {
    float f = som[i];
    unsigned int u = __float_as_uint(f);
    u = (u & 0x80000000u) ? ~u : (u | 0x80000000u);   // monotone map, ascending
    keys[i] = (i == 0) ? 0u : u;                      // token 0 out of competition
  }
  unsigned int pref = 0; int need = MM - 1;           // 63
  for (int pass = 0; pass < 4; ++pass) {
    int shift = 24 - pass * 8;
    unsigned int pm = (pass == 0) ? 0u : (0xFFFFFFFFu << (32 - 8 * pass));
    unsigned int* wbf = (unsigned int*)wb;
    wbf[tid] = 0; wbf[tid + 256] = 0; wbf[tid + 512] = 0; wbf[tid + 768] = 0;
    __syncthreads();                                  // B1: keys + zeroed bins visible
    for (int i = tid; i < NTOK; i += 256) {
      unsigned int k = keys[i];
      if ((k & pm) == pref) atomicAdd(&wb[wave][(k >> shift) & 255], 1u);
    }
    __syncthreads();                                  // B2: histogram done
    int binr = 255 - tid;                             // reversed position -> suffix sum
    int cnt = (int)(wb[0][binr] + wb[1][binr] + wb[2][binr] + wb[3][binr]);
    int v = cnt;
    #pragma unroll
    for (int d = 1; d < 64; d <<= 1) {
      int t = __shfl_up(v, d);
      if (lane >= d) v += t;
    }
    if (lane == 63) wsum[wave] = v;
    __syncthreads();                                  // B3: wave totals ready
    int off = 0;
    #pragma unroll
    for (int w = 0; w < 4; ++w) off += (w < wave) ? wsum[w] : 0;
    v += off;                                         // v = cum[binr] = sum_{j>=binr}
    int above = v - cnt;
    if (v >= need && above < need) { sh_bin = binr; sh_need = need - above; }
    __syncthreads();                                  // B4: publish
    pref |= ((unsigned int)sh_bin) << shift;
    need = sh_need;
  }
  unsigned int thr = pref;

  // --- tie ranking: exclusive prefix of tie counts by index order ---
  int base = tid * 16;
  int ctie = 0;
  #pragma unroll
  for (int j = 0; j < 16; ++j) ctie += (keys[base + j] == thr);
  int v2 = ctie;
  #pragma unroll
  for (int d = 1; d < 64; d <<= 1) {
    int t = __shfl_up(v2, d);
    if (lane >= d) v2 += t;
  }
  if (lane == 63) wsum[wave] = v2;                    // safe: B4 ordered prior reads
  __syncthreads();                                    // B5
  int offt = 0;
  #pragma unroll
  for (int w = 0; w < 4; ++w) offt += (w < wave) ? wsum[w] : 0;
  int tie_excl = v2 + offt - ctie;

  // --- flag counts + compaction prefix ---
  int tieoff = tie_excl, cnt2 = 0;
  #pragma unroll
  for (int j = 0; j < 16; ++j) {
    unsigned int k = keys[base + j];
    int f = (k > thr) ? 1 : 0;
    if (k == thr) { f = (tieoff < need) ? 1 : 0; ++tieoff; }
    if (base + j == 0) f = 1;
    cnt2 += f;
  }
  int v3 = cnt2;
  #pragma unroll
  for (int d = 1; d < 64; d <<= 1) {
    int t = __shfl_up(v3, d);
    if (lane >= d) v3 += t;
  }
  if (lane == 63) wsumB[wave] = v3;
  __syncthreads();                                    // B6
  int offc = 0;
  #pragma unroll
  for (int w = 0; w < 4; ++w) offc += (w < wave) ? wsumB[w] : 0;
  int o = v3 + offc - cnt2;
  tieoff = tie_excl;
  #pragma unroll
  for (int j = 0; j < 16; ++j) {
    unsigned int k = keys[base + j];
    int f = (k > thr) ? 1 : 0;
    if (k == thr) { f = (tieoff < need) ? 1 : 0; ++tieoff; }
    if (base + j == 0) f = 1;
    if (f) sel[o++] = base + j;
  }
  __syncthreads();                                    // B7: sel ready

  // --- gather selected rows ---
  const float* src = which ? Qg : Kg;
  float* dst = (which ? nr : nc) + (long)bh * MM * DD;
  float scale = which ? 0.125f : 1.0f;
  for (int e = tid; e < MM * 16; e += 256) {
    int i = e >> 4, d4 = e & 15;
    float4 v = *(const float4*)&src[((long)bh * NTOK + sel[i]) * DD + d4 * 4];
    v.x *= scale; v.y *= scale; v.z *= scale; v.w *= scale;
    *(float4*)&dst[i * DD + d4 * 4] = v;
  }
}

// ---------------- u = row-softmax(nr @ nc^T); write u; per-bh colsum max
__global__ __launch_bounds__(256) void k_u(const float* __restrict__ nc,
    const float* __restrict__ nr, float* __restrict__ u, float* __restrict__ smax) {
  int bh = blockIdx.x, tid = threadIdx.x, ti = tid >> 4, tj = tid & 15;
  __shared__ float A[MM][PAD];
  __shared__ float BT[DD][MM];
  __shared__ float cs[4][MM];
  for (int e = tid; e < 1024; e += 256) {
    int m = e >> 4, d4 = e & 15;
    *(float4*)&A[m][d4*4] = *(const float4*)&nr[(long)bh*MM*DD + m*DD + d4*4];
    float4 c = *(const float4*)&nc[(long)bh*MM*DD + m*DD + d4*4];
    BT[d4*4+0][m] = c.x; BT[d4*4+1][m] = c.y; BT[d4*4+2][m] = c.z; BT[d4*4+3][m] = c.w;
  }
  __syncthreads();
  float acc[4][4] = {};
  mm_acc<PAD, MM>(acc, A, BT, ti, tj);
  float e_[4][4];
  #pragma unroll
  for (int x = 0; x < 4; ++x)
    #pragma unroll
    for (int y = 0; y < 4; ++y) e_[x][y] = expf(acc[x][y]);
  float rsx[4];
  #pragma unroll
  for (int x = 0; x < 4; ++x) {
    rsx[x] = e_[x][0] + e_[x][1] + e_[x][2] + e_[x][3];
    rsx[x] += __shfl_xor(rsx[x], 1); rsx[x] += __shfl_xor(rsx[x], 2);
    rsx[x] += __shfl_xor(rsx[x], 4); rsx[x] += __shfl_xor(rsx[x], 8);
  }
  float cp[4] = {0.f, 0.f, 0.f, 0.f};
  #pragma unroll
  for (int x = 0; x < 4; ++x) {
    float inv = 1.f / rsx[x];
    float v0 = e_[x][0]*inv, v1 = e_[x][1]*inv, v2 = e_[x][2]*inv, v3 = e_[x][3]*inv;
    cp[0] += v0; cp[1] += v1; cp[2] += v2; cp[3] += v3;
    float4 o; o.x = v0; o.y = v1; o.z = v2; o.w = v3;
    *(float4*)&u[(long)bh*MM*MM + (ti*4+x)*MM + tj*4] = o;
  }
  #pragma unroll
  for (int y = 0; y < 4; ++y) {
    cp[y] += __shfl_xor(cp[y], 16);
    cp[y] += __shfl_xor(cp[y], 32);
  }
  if (((tid >> 4) & 3) == 0) {
    #pragma unroll
    for (int y = 0; y < 4; ++y) cs[tid >> 6][tj*4 + y] = cp[y];
  }
  __syncthreads();
  if (tid < 64) {
    float tot = cs[0][tid] + cs[1][tid] + cs[2][tid] + cs[3][tid];
    for (int off = 32; off; off >>= 1) tot = fmaxf(tot, __shfl_xor(tot, off));
    if (tid == 0) smax[bh] = tot;
  }
}

// ---------------- Newton-Schulz (f16-split MFMA) FUSED with Z = Vinv @ (num/den)
__global__ __launch_bounds__(256) void k_newton(const float* __restrict__ u,
    const float* __restrict__ smax, const float* __restrict__ nump,
    const float* __restrict__ denp, float* __restrict__ Zg) {
  __shared__ f16 VT_h[64][72], VT_l[64][72];   // V^T row-major
  __shared__ f16 Vr_h[64][72], Vr_l[64][72];   // V row-major
  __shared__ f16 PT_h[64][72], PT_l[64][72];   // P^T, later W^T
  __shared__ f16 RT_h[64][72], RT_l[64][72];   // R^T
  __shared__ float Vi[64][68];                 // Vinv fp32 (for Z)
  __shared__ float Wf[64][68];                 // W = sum(num)/den fp32
  __shared__ float dn[64];
  int bh = blockIdx.x, tid = threadIdx.x;
  int wave = tid >> 6, lane = tid & 63;
  int lm = lane & 15, hi = lane >> 4;

  float gmx = smax[0];
  #pragma unroll
  for (int i = 1; i < 32; ++i) gmx = fmaxf(gmx, smax[i]);
  float c0 = 1.0f / gmx;

  const float* pu = u + (long)bh * MM * MM;
  for (int e = tid; e < 4096; e += 256) {
    int i = e >> 6, j = e & 63;
    float sv = pu[e] * c0;
    f16 h, l;
    fsplit(sv, &h, &l);
    VT_h[i][j] = h; VT_l[i][j] = l;    // V0^T = c*K
    Vr_h[j][i] = h; Vr_l[j][i] = l;    // V0 = c*K^T
  }
  // K B-frag straight from global (u is L2-hot; no LDS staging needed)
  f16x8 kb_h[2], kb_l[2];
  {
    const float* p = pu + (wave*16 + lm) * 64;
    float4 q0 = *(const float4*)(p + hi*8);
    float4 q1 = *(const float4*)(p + hi*8 + 4);
    float4 q2 = *(const float4*)(p + 32 + hi*8);
    float4 q3 = *(const float4*)(p + 36 + hi*8);
    f16 h, l;
    fsplit(q0.x,&h,&l); kb_h[0][0]=h; kb_l[0][0]=l;
    fsplit(q0.y,&h,&l); kb_h[0][1]=h; kb_l[0][1]=l;
    fsplit(q0.z,&h,&l); kb_h[0][2]=h; kb_l[0][2]=l;
    fsplit(q0.w,&h,&l); kb_h[0][3]=h; kb_l[0][3]=l;
    fsplit(q1.x,&h,&l); kb_h[0][4]=h; kb_l[0][4]=l;
    fsplit(q1.y,&h,&l); kb_h[0][5]=h; kb_l[0][5]=l;
    fsplit(q1.z,&h,&l); kb_h[0][6]=h; kb_l[0][6]=l;
    fsplit(q1.w,&h,&l); kb_h[0][7]=h; kb_l[0][7]=l;
    fsplit(q2.x,&h,&l); kb_h[1][0]=h; kb_l[1][0]=l;
    fsplit(q2.y,&h,&l); kb_h[1][1]=h; kb_l[1][1]=l;
    fsplit(q2.z,&h,&l); kb_h[1][2]=h; kb_l[1][2]=l;
    fsplit(q2.w,&h,&l); kb_h[1][3]=h; kb_l[1][3]=l;
    fsplit(q3.x,&h,&l); kb_h[1][4]=h; kb_l[1][4]=l;
    fsplit(q3.y,&h,&l); kb_h[1][5]=h; kb_l[1][5]=l;
    fsplit(q3.z,&h,&l); kb_h[1][6]=h; kb_l[1][6]=l;
    fsplit(q3.w,&h,&l); kb_h[1][7]=h; kb_l[1][7]=l;
  }
  __syncthreads();

  for (int it = 0; it < 6; ++it) {
    // ---- step 1: S^T slice = mfma(VT rows, K rows) ----
    f32x4 st[4];
    #pragma unroll
    for (int g = 0; g < 4; ++g) {
      f16x8 ah0 = *(const f16x8*)&VT_h[g*16 + lm][hi*8];
      f16x8 ah1 = *(const f16x8*)&VT_h[g*16 + lm][32 + hi*8];
      f16x8 al0 = *(const f16x8*)&VT_l[g*16 + lm][hi*8];
      f16x8 al1 = *(const f16x8*)&VT_l[g*16 + lm][32 + hi*8];
      st[g] = mm6(ah0, ah1, al0, al1, kb_h[0], kb_h[1], kb_l[0], kb_l[1]);
    }
    f16x8 sa_h[2], sa_l[2];
    #pragma unroll
    for (int g = 0; g < 4; ++g)
      #pragma unroll
      for (int r = 0; r < 4; ++r) {
        f16 h, l; fsplit(st[g][r], &h, &l);
        sa_h[g >> 1][(g & 1)*4 + r] = h;
        sa_l[g >> 1][(g & 1)*4 + r] = l;
      }
    #pragma unroll
    for (int g = 0; g < 4; ++g)
      #pragma unroll
      for (int r = 0; r < 4; ++r) {
        int i = g*16 + hi*4 + r, j = wave*16 + lm;
        float pv = (i == j ? 7.f : 0.f) - st[g][r];
        f16 h, l; fsplit(pv, &h, &l);
        PT_h[i][j] = h; PT_l[i][j] = l;
      }
    __syncthreads();

    // ---- step 2: R = 15I - S@P ----
    #pragma unroll
    for (int cc = 0; cc < 4; ++cc) {
      V8U bh0, bh1, bl0, bl1;
      bh0.q[0] = *(const f16x4*)&PT_h[cc*16 + lm][hi*4];
      bh0.q[1] = *(const f16x4*)&PT_h[cc*16 + lm][16 + hi*4];
      bh1.q[0] = *(const f16x4*)&PT_h[cc*16 + lm][32 + hi*4];
      bh1.q[1] = *(const f16x4*)&PT_h[cc*16 + lm][48 + hi*4];
      bl0.q[0] = *(const f16x4*)&PT_l[cc*16 + lm][hi*4];
      bl0.q[1] = *(const f16x4*)&PT_l[cc*16 + lm][16 + hi*4];
      bl1.q[0] = *(const f16x4*)&PT_l[cc*16 + lm][32 + hi*4];
      bl1.q[1] = *(const f16x4*)&PT_l[cc*16 + lm][48 + hi*4];
      f32x4 a = mm6(sa_h[0], sa_h[1], sa_l[0], sa_l[1], bh0.v, bh1.v, bl0.v, bl1.v);
      f16x4 wh, wl;
      #pragma unroll
      for (int r = 0; r < 4; ++r) {
        int row = wave*16 + hi*4 + r, col = cc*16 + lm;
        float rv = (row == col ? 15.f : 0.f) - a[r];
        f16 h, l; fsplit(rv, &h, &l);
        wh[r] = h; wl[r] = l;
      }
      *(f16x4*)&RT_h[cc*16 + lm][wave*16 + hi*4] = wh;
      *(f16x4*)&RT_l[cc*16 + lm][wave*16 + hi*4] = wl;
    }
    __syncthreads();

    // ---- step 3: W = 13I - S@R  (write W^T into PT bufs) ----
    #pragma unroll
    for (int cc = 0; cc < 4; ++cc) {
      V8U bh0, bh1, bl0, bl1;
      bh0.q[0] = *(const f16x4*)&RT_h[cc*16 + lm][hi*4];
      bh0.q[1] = *(const f16x4*)&RT_h[cc*16 + lm][16 + hi*4];
      bh1.q[0] = *(const f16x4*)&RT_h[cc*16 + lm][32 + hi*4];
      bh1.q[1] = *(const f16x4*)&RT_h[cc*16 + lm][48 + hi*4];
      bl0.q[0] = *(const f16x4*)&RT_l[cc*16 + lm][hi*4];
      bl0.q[1] = *(const f16x4*)&RT_l[cc*16 + lm][16 + hi*4];
      bl1.q[0] = *(const f16x4*)&RT_l[cc*16 + lm][32 + hi*4];
      bl1.q[1] = *(const f16x4*)&RT_l[cc*16 + lm][48 + hi*4];
      f32x4 a = mm6(sa_h[0], sa_h[1], sa_l[0], sa_l[1], bh0.v, bh1.v, bl0.v, bl1.v);
      f16x4 wh, wl;
      #pragma unroll
      for (int r = 0; r < 4; ++r) {
        int row = wave*16 + hi*4 + r, col = cc*16 + lm;
        float wv = (row == col ? 13.f : 0.f) - a[r];
        f16 h, l; fsplit(wv, &h, &l);
        wh[r] = h; wl[r] = l;
      }
      *(f16x4*)&PT_h[cc*16 + lm][wave*16 + hi*4] = wh;
      *(f16x4*)&PT_l[cc*16 + lm][wave*16 + hi*4] = wl;
    }
    __syncthreads();

    // ---- step 4: V' = 0.25 V@W ----
    f16x8 vh0 = *(const f16x8*)&Vr_h[wave*16 + lm][hi*8];
    f16x8 vh1 = *(const f16x8*)&Vr_h[wave*16 + lm][32 + hi*8];
    f16x8 vl0 = *(const f16x8*)&Vr_l[wave*16 + lm][hi*8];
    f16x8 vl1 = *(const f16x8*)&Vr_l[wave*16 + lm][32 + hi*8];
    #pragma unroll
    for (int cc = 0; cc < 4; ++cc) {
      f16x8 wh0 = *(const f16x8*)&PT_h[cc*16 + lm][hi*8];
      f16x8 wh1 = *(const f16x8*)&PT_h[cc*16 + lm][32 + hi*8];
      f16x8 wl0 = *(const f16x8*)&PT_l[cc*16 + lm][hi*8];
      f16x8 wl1 = *(const f16x8*)&PT_l[cc*16 + lm][32 + hi*8];
      f32x4 a = mm6(vh0, vh1, vl0, vl1, wh0, wh1, wl0, wl1);
      if (it == 5) {
        #pragma unroll
        for (int r = 0; r < 4; ++r)
          Vi[wave*16 + hi*4 + r][cc*16 + lm] = 0.25f * a[r];
      } else {
        f16x4 th, tl;
        #pragma unroll
        for (int r = 0; r < 4; ++r) {
          float vv = 0.25f * a[r];
          f16 h, l; fsplit(vv, &h, &l);
          Vr_h[wave*16 + hi*4 + r][cc*16 + lm] = h;
          Vr_l[wave*16 + hi*4 + r][cc*16 + lm] = l;
          th[r] = h; tl[r] = l;
        }
        *(f16x4*)&VT_h[cc*16 + lm][wave*16 + hi*4] = th;
        *(f16x4*)&VT_l[cc*16 + lm][wave*16 + hi*4] = tl;
      }
    }
    __syncthreads();
  }

  // ---- fused Z = Vinv @ (sum_g num_g / sum_g den_g) ----
  if (tid < 64) {
    float s = 0.f;
    #pragma unroll
    for (int g = 0; g < GPART; ++g) s += denp[((long)bh * GPART + g) * MM + tid];
    dn[tid] = s;
  }
  __syncthreads();
  for (int e = tid; e < 1024; e += 256) {
    int m = e >> 4, d4 = e & 15;
    float4 s = {0.f, 0.f, 0.f, 0.f};
    #pragma unroll
    for (int g = 0; g < GPART; ++g) {
      float4 t = *(const float4*)&nump[((long)bh * GPART + g) * (MM*DD) + m*DD + d4*4];
      s.x += t.x; s.y += t.y; s.z += t.z; s.w += t.w;
    }
    float inv = 1.f / dn[m];
    s.x *= inv; s.y *= inv; s.z *= inv; s.w *= inv;
    *(float4*)&Wf[m][d4*4] = s;
  }
  __syncthreads();
  int ti = tid >> 4, tj = tid & 15;
  float acc[4][4] = {};
  mm_acc<68, 68>(acc, Vi, Wf, ti, tj);
  #pragma unroll
  for (int x = 0; x < 4; ++x) {
    float4 o; o.x = acc[x][0]; o.y = acc[x][1]; o.z = acc[x][2]; o.w = acc[x][3];
    *(float4*)&Zg[(long)bh*MM*DD + (ti*4+x)*DD + tj*4] = o;
  }
}

// ---------------- MFMA partials of kernel_3 @ V  (exp masked to mask==1), atomic-free
__global__ __launch_bounds__(256) void k_w3(const float* __restrict__ Kg,
    const float* __restrict__ Vg, const int* __restrict__ maskg,
    const float* __restrict__ nr, float* __restrict__ nump, float* __restrict__ denp) {
  int bh = blockIdx.x, grp = blockIdx.y, b = bh >> 3;
  int tid = threadIdx.x;
  int wave = tid >> 6, lane = tid & 63;
  int lm = lane & 15, hi = lane >> 4;
  __shared__ f16 Ks[64][72];
  __shared__ f16 Vs[64][72];
  __shared__ float kmul[64];

  int m0 = wave * 16;
  f16x8 nrf[2];
  {
    const float* p = nr + (long)bh*MM*DD + (long)(m0 + lm)*DD + hi*8;
    float4 q0 = *(const float4*)p;
    float4 q1 = *(const float4*)(p + 4);
    float4 q2 = *(const float4*)(p + 32);
    float4 q3 = *(const float4*)(p + 36);
    nrf[0][0]=(f16)q0.x; nrf[0][1]=(f16)q0.y; nrf[0][2]=(f16)q0.z; nrf[0][3]=(f16)q0.w;
    nrf[0][4]=(f16)q1.x; nrf[0][5]=(f16)q1.y; nrf[0][6]=(f16)q1.z; nrf[0][7]=(f16)q1.w;
    nrf[1][0]=(f16)q2.x; nrf[1][1]=(f16)q2.y; nrf[1][2]=(f16)q2.z; nrf[1][3]=(f16)q2.w;
    nrf[1][4]=(f16)q3.x; nrf[1][5]=(f16)q3.y; nrf[1][6]=(f16)q3.z; nrf[1][7]=(f16)q3.w;
  }

  f32x4 nacc[4];
  #pragma unroll
  for (int dt = 0; dt < 4; ++dt) nacc[dt] = (f32x4){0.f, 0.f, 0.f, 0.f};
  float dsum = 0.f;

  for (int sc = 0; sc < 4; ++sc) {
    int n0c = (grp * 4 + sc) * 64;
    if (sc) __syncthreads();
    for (int s = tid; s < 1024; s += 256) {
      int row = s >> 4, c4 = s & 15;
      float4 kv = *(const float4*)&Kg[((long)bh*NTOK + n0c + row)*DD + c4*4];
      float4 vv = *(const float4*)&Vg[((long)bh*NTOK + n0c + row)*DD + c4*4];
      f16x4 kk = {(f16)kv.x, (f16)kv.y, (f16)kv.z, (f16)kv.w};
      f16x4 vv4 = {(f16)vv.x, (f16)vv.y, (f16)vv.z, (f16)vv.w};
      *(f16x4*)&Ks[row][c4*4] = kk;
      *(f16x4*)&Vs[row][c4*4] = vv4;
    }
    if (tid < 64) kmul[tid] = maskg[b * NTOK + n0c + tid] ? 1.f : 0.f;
    __syncthreads();

    f32x4 stv[4];
    #pragma unroll
    for (int g = 0; g < 4; ++g) {
      f16x8 a0 = *(const f16x8*)&Ks[g*16 + lm][hi*8];
      f16x8 a1 = *(const f16x8*)&Ks[g*16 + lm][32 + hi*8];
      f32x4 c = {0.f, 0.f, 0.f, 0.f};
      c = __builtin_amdgcn_mfma_f32_16x16x32_f16(a0, nrf[0], c, 0, 0, 0);
      c = __builtin_amdgcn_mfma_f32_16x16x32_f16(a1, nrf[1], c, 0, 0, 0);
      stv[g] = c;
    }
    f16x8 pa[2];
    #pragma unroll
    for (int g = 0; g < 4; ++g) {
      #pragma unroll
      for (int r = 0; r < 4; ++r) {
        float p = __expf(stv[g][r]) * kmul[g*16 + hi*4 + r];
        dsum += p;
        pa[g >> 1][(g & 1)*4 + r] = (f16)p;
      }
    }
    #pragma unroll
    for (int dt = 0; dt < 4; ++dt) {
      f16x8 vb0, vb1;
      #pragma unroll
      for (int j = 0; j < 8; ++j) {
        int nrow = hi*4 + (j & 3) + 16*(j >> 2);
        vb0[j] = Vs[nrow][dt*16 + lm];
        vb1[j] = Vs[32 + nrow][dt*16 + lm];
      }
      nacc[dt] = __builtin_amdgcn_mfma_f32_16x16x32_f16(pa[0], vb0, nacc[dt], 0, 0, 0);
      nacc[dt] = __builtin_amdgcn_mfma_f32_16x16x32_f16(pa[1], vb1, nacc[dt], 0, 0, 0);
    }
  }
  float* pnum = nump + ((long)bh * GPART + grp) * (MM * DD);
  #pragma unroll
  for (int dt = 0; dt < 4; ++dt)
    #pragma unroll
    for (int r = 0; r < 4; ++r)
      pnum[(m0 + hi*4 + r)*DD + dt*16 + lm] = nacc[dt][r];
  float d2 = dsum + __shfl_xor(dsum, 16);
  d2 += __shfl_xor(d2, 32);
  if (lane < 16)
    denp[((long)bh * GPART + grp) * MM + m0 + lane] = d2;
}

// ---------------- MFMA X = row-softmax(Qs @ nc^T) @ Z  (swapped S^T trick)
__global__ __launch_bounds__(256) void k_final(const float* __restrict__ Qg,
    const float* __restrict__ nc, const float* __restrict__ Zg, float* __restrict__ Xg) {
  int bh = blockIdx.x, chunk = blockIdx.y;
  int tid = threadIdx.x;
  int wave = tid >> 6, lane = tid & 63;
  int lm = lane & 15, hi = lane >> 4;
  int n0 = chunk * 64;
  __shared__ f16 Qs[64][72];
  __shared__ f16 Ncs[64][72];
  __shared__ f16 Zs[64][72];
  for (int s = tid; s < 1024; s += 256) {
    int row = s >> 4, c4 = s & 15;
    float4 q = *(const float4*)&Qg[((long)bh*NTOK + n0 + row)*DD + c4*4];
    f16x4 qq = {(f16)(q.x*0.125f), (f16)(q.y*0.125f), (f16)(q.z*0.125f), (f16)(q.w*0.125f)};
    *(f16x4*)&Qs[row][c4*4] = qq;
    float4 cv = *(const float4*)&nc[(long)bh*MM*DD + row*DD + c4*4];
    f16x4 cc = {(f16)cv.x, (f16)cv.y, (f16)cv.z, (f16)cv.w};
    *(f16x4*)&Ncs[row][c4*4] = cc;
    float4 zv = *(const float4*)&Zg[(long)bh*MM*DD + row*DD + c4*4];
    f16x4 zz = {(f16)zv.x, (f16)zv.y, (f16)zv.z, (f16)zv.w};
    *(f16x4*)&Zs[row][c4*4] = zz;
  }
  __syncthreads();

  f16x8 qb0 = *(const f16x8*)&Qs[wave*16 + lm][hi*8];
  f16x8 qb1 = *(const f16x8*)&Qs[wave*16 + lm][32 + hi*8];
  f32x4 stv[4];
  #pragma unroll
  for (int mt = 0; mt < 4; ++mt) {
    f16x8 a0 = *(const f16x8*)&Ncs[mt*16 + lm][hi*8];
    f16x8 a1 = *(const f16x8*)&Ncs[mt*16 + lm][32 + hi*8];
    f32x4 c = {0.f, 0.f, 0.f, 0.f};
    c = __builtin_amdgcn_mfma_f32_16x16x32_f16(a0, qb0, c, 0, 0, 0);
    c = __builtin_amdgcn_mfma_f32_16x16x32_f16(a1, qb1, c, 0, 0, 0);
    stv[mt] = c;
  }
  f16x8 pa[2];
  float dsum = 0.f;
  #pragma unroll
  for (int mt = 0; mt < 4; ++mt) {
    #pragma unroll
    for (int r = 0; r < 4; ++r) {
      float p = __expf(stv[mt][r]);
      dsum += p;
      pa[mt >> 1][(mt & 1)*4 + r] = (f16)p;
    }
  }
  float dtot = dsum + __shfl_xor(dsum, 16);
  dtot += __shfl_xor(dtot, 32);
  f32x4 xacc[4];
  #pragma unroll
  for (int dt = 0; dt < 4; ++dt) {
    f16x8 zb0, zb1;
    #pragma unroll
    for (int j = 0; j < 8; ++j) {
      int mrow = hi*4 + (j & 3) + 16*(j >> 2);
      zb0[j] = Zs[mrow][dt*16 + lm];
      zb1[j] = Zs[32 + mrow][dt*16 + lm];
    }
    f32x4 c = {0.f, 0.f, 0.f, 0.f};
    c = __builtin_amdgcn_mfma_f32_16x16x32_f16(pa[0], zb0, c, 0, 0, 0);
    c = __builtin_amdgcn_mfma_f32_16x16x32_f16(pa[1], zb1, c, 0, 0, 0);
    xacc[dt] = c;
  }
  float rn[4];
  #pragma unroll
  for (int r = 0; r < 4; ++r) rn[r] = 1.f / __shfl(dtot, hi*4 + r);
  #pragma unroll
  for (int dt = 0; dt < 4; ++dt)
    #pragma unroll
    for (int r = 0; r < 4; ++r)
      Xg[((long)bh*NTOK + n0 + wave*16 + hi*4 + r)*DD + dt*16 + lm] = xacc[dt][r] * rn[r];
}

extern "C" void kernel_launch(void* const* d_in, const int* in_sizes, int n_in,
                              void* d_out, int out_size, void* d_ws, size_t ws_size,
                              hipStream_t stream) {
  (void)in_sizes; (void)n_in; (void)out_size; (void)ws_size;
  const float* Qp = (const float*)d_in[0];
  const float* Kp = (const float*)d_in[1];
  const float* Vp = (const float*)d_in[2];
  const int* maskp = (const int*)d_in[3];
  float* out = (float*)d_out;

  float* wsf = (float*)d_ws;
  float* NUMP = wsf;                                // 32*16*4096
  float* DENP = NUMP + (long)BHN * GPART * MM * DD; // 32*16*64
  float* SMAX = DENP + BHN * GPART * MM;            // 32
  float* NC = SMAX + 32;
  float* NR = NC + BHN * MM * DD;
  float* U  = NR + BHN * MM * DD;
  float* Zb = U  + BHN * MM * MM;
  float* SK = Zb + BHN * MM * DD;
  float* SQ = SK + BHN * NTOK;

  k_somme<<<16384, 256, 0, stream>>>(Kp, Qp, maskp, SK, SQ);
  k_select<<<dim3(32, 2), 256, 0, stream>>>(Kp, Qp, SK, SQ, NC, NR);
  k_u<<<32, 256, 0, stream>>>(NC, NR, U, SMAX);
  k_w3<<<dim3(32, GPART), 256, 0, stream>>>(Kp, Vp, maskp, NR, NUMP, DENP);
  k_newton<<<32, 256, 0, stream>>>(U, SMAX, NUMP, DENP, Zb);
  k_final<<<dim3(32, 64), 256, 0, stream>>>(Qp, NC, Zb, out);
}

// Round 6
// 82.432 us; speedup vs baseline: 7.2418x; 1.1758x over previous
//
#include <hip/hip_runtime.h>
#include <float.h>

#define BB 4
#define HH 8
#define BHN 32
#define NTOK 4096
#define DD 64
#define MM 64
#define PAD 68
#define GPART 16

typedef _Float16 f16;
typedef __attribute__((ext_vector_type(4))) _Float16 f16x4;
typedef __attribute__((ext_vector_type(8))) _Float16 f16x8;
typedef __attribute__((ext_vector_type(4))) float f32x4;

union V8U { f16x8 v; f16x4 q[2]; };

__device__ __forceinline__ void fsplit(float v, f16* h, f16* l) {
  f16 hh = (f16)v;
  *h = hh;
  *l = (f16)(v - (float)hh);
}

// plain f16 (2-chain)
__device__ __forceinline__ f32x4 mm2(f16x8 a0, f16x8 a1, f16x8 b0, f16x8 b1) {
  f32x4 c = {0.f, 0.f, 0.f, 0.f};
  c = __builtin_amdgcn_mfma_f32_16x16x32_f16(a0, b0, c, 0, 0, 0);
  c = __builtin_amdgcn_mfma_f32_16x16x32_f16(a1, b1, c, 0, 0, 0);
  return c;
}

// 6-term fp32-faithful f16-split, as two independent 3-chains
__device__ __forceinline__ f32x4 mm6(f16x8 ah0, f16x8 ah1, f16x8 al0, f16x8 al1,
                                     f16x8 bh0, f16x8 bh1, f16x8 bl0, f16x8 bl1) {
  f32x4 a = {0.f, 0.f, 0.f, 0.f};
  f32x4 b = {0.f, 0.f, 0.f, 0.f};
  a = __builtin_amdgcn_mfma_f32_16x16x32_f16(ah0, bh0, a, 0, 0, 0);
  a = __builtin_amdgcn_mfma_f32_16x16x32_f16(ah0, bl0, a, 0, 0, 0);
  a = __builtin_amdgcn_mfma_f32_16x16x32_f16(al0, bh0, a, 0, 0, 0);
  b = __builtin_amdgcn_mfma_f32_16x16x32_f16(ah1, bh1, b, 0, 0, 0);
  b = __builtin_amdgcn_mfma_f32_16x16x32_f16(ah1, bl1, b, 0, 0, 0);
  b = __builtin_amdgcn_mfma_f32_16x16x32_f16(al1, bh1, b, 0, 0, 0);
  return a + b;
}

// ---------------- 4x4-tile 64x64x64 matmul helper (fp32 scalar, small kernels)
template<int LDA, int LDB>
__device__ __forceinline__ void mm_acc(float acc[4][4],
    const float (*A)[LDA], const float (*B)[LDB], int ti, int tj) {
  #pragma unroll
  for (int k4 = 0; k4 < 16; ++k4) {
    float a[4][4], b[4][4];
    #pragma unroll
    for (int x = 0; x < 4; ++x) {
      float4 t = *(const float4*)&A[ti*4+x][k4*4];
      a[x][0]=t.x; a[x][1]=t.y; a[x][2]=t.z; a[x][3]=t.w;
    }
    #pragma unroll
    for (int kk = 0; kk < 4; ++kk) {
      float4 t = *(const float4*)&B[k4*4+kk][tj*4];
      b[kk][0]=t.x; b[kk][1]=t.y; b[kk][2]=t.z; b[kk][3]=t.w;
    }
    #pragma unroll
    for (int kk = 0; kk < 4; ++kk)
      #pragma unroll
      for (int x = 0; x < 4; ++x)
        #pragma unroll
        for (int y = 0; y < 4; ++y)
          acc[x][y] = fmaf(a[x][kk], b[kk][y], acc[x][y]);
  }
}

// ---------------- row sums for selection (both K and Q), mask/token0 -> -FLT_MAX
__global__ __launch_bounds__(256) void k_somme(const float* __restrict__ Kg,
    const float* __restrict__ Qg, const int* __restrict__ mask,
    float* __restrict__ somK, float* __restrict__ somQ) {
  int tid = threadIdx.x;
  int lane = tid & 63;
  long grow = (long)blockIdx.x * 16 + (tid >> 6) * 4 + (lane >> 4);
  int which = grow >= (long)(BHN * NTOK);
  long row = which ? grow - (long)BHN * NTOK : grow;   // bh*N + n
  int n = (int)(row & (NTOK - 1));
  int bh = (int)(row >> 12);
  int b = bh >> 3;
  const float* src = which ? Qg : Kg;
  float4 v = *((const float4*)(src + row * DD) + (lane & 15));
  float s = v.x + v.y + v.z + v.w;
  s += __shfl_xor(s, 1); s += __shfl_xor(s, 2);
  s += __shfl_xor(s, 4); s += __shfl_xor(s, 8);
  if ((lane & 15) == 0) {
    float out = (n == 0 || mask[b * NTOK + n] != 0) ? -FLT_MAX : s;
    (which ? somQ : somK)[row] = out;
  }
}

// ---------------- per-(bh,which): radix top-63 select (wave-shfl scans) + gather
__global__ __launch_bounds__(256) void k_select(const float* __restrict__ Kg,
    const float* __restrict__ Qg, const float* __restrict__ somK,
    const float* __restrict__ somQ, float* __restrict__ nc, float* __restrict__ nr) {
  int bh = blockIdx.x;
  int which = blockIdx.y;           // 0: K -> nc, 1: Q (scaled) -> nr
  __shared__ unsigned int keys[NTOK];       // 16KB
  __shared__ unsigned int wb[4][256];       // per-wave histograms, 4KB
  __shared__ int wsum[4];
  __shared__ int wsumB[4];
  __shared__ int sh_bin, sh_need;
  __shared__ int sel[MM];
  int tid = threadIdx.x, wave = tid >> 6, lane = tid & 63;
  const float* som = (which ? somQ : somK) + (long)bh * NTOK;
  for (int i = tid; i < NTOK; i += 256) {
    float f = som[i];
    unsigned int u = __float_as_uint(f);
    u = (u & 0x80000000u) ? ~u : (u | 0x80000000u);   // monotone map, ascending
    keys[i] = (i == 0) ? 0u : u;                      // token 0 out of competition
  }
  unsigned int pref = 0; int need = MM - 1;           // 63
  for (int pass = 0; pass < 4; ++pass) {
    int shift = 24 - pass * 8;
    unsigned int pm = (pass == 0) ? 0u : (0xFFFFFFFFu << (32 - 8 * pass));
    unsigned int* wbf = (unsigned int*)wb;
    wbf[tid] = 0; wbf[tid + 256] = 0; wbf[tid + 512] = 0; wbf[tid + 768] = 0;
    __syncthreads();
    for (int i = tid; i < NTOK; i += 256) {
      unsigned int k = keys[i];
      if ((k & pm) == pref) atomicAdd(&wb[wave][(k >> shift) & 255], 1u);
    }
    __syncthreads();
    int binr = 255 - tid;                             // reversed position -> suffix sum
    int cnt = (int)(wb[0][binr] + wb[1][binr] + wb[2][binr] + wb[3][binr]);
    int v = cnt;
    #pragma unroll
    for (int d = 1; d < 64; d <<= 1) {
      int t = __shfl_up(v, d);
      if (lane >= d) v += t;
    }
    if (lane == 63) wsum[wave] = v;
    __syncthreads();
    int off = 0;
    #pragma unroll
    for (int w = 0; w < 4; ++w) off += (w < wave) ? wsum[w] : 0;
    v += off;
    int above = v - cnt;
    if (v >= need && above < need) { sh_bin = binr; sh_need = need - above; }
    __syncthreads();
    pref |= ((unsigned int)sh_bin) << shift;
    need = sh_need;
  }
  unsigned int thr = pref;

  int base = tid * 16;
  int ctie = 0;
  #pragma unroll
  for (int j = 0; j < 16; ++j) ctie += (keys[base + j] == thr);
  int v2 = ctie;
  #pragma unroll
  for (int d = 1; d < 64; d <<= 1) {
    int t = __shfl_up(v2, d);
    if (lane >= d) v2 += t;
  }
  if (lane == 63) wsum[wave] = v2;
  __syncthreads();
  int offt = 0;
  #pragma unroll
  for (int w = 0; w < 4; ++w) offt += (w < wave) ? wsum[w] : 0;
  int tie_excl = v2 + offt - ctie;

  int tieoff = tie_excl, cnt2 = 0;
  #pragma unroll
  for (int j = 0; j < 16; ++j) {
    unsigned int k = keys[base + j];
    int f = (k > thr) ? 1 : 0;
    if (k == thr) { f = (tieoff < need) ? 1 : 0; ++tieoff; }
    if (base + j == 0) f = 1;
    cnt2 += f;
  }
  int v3 = cnt2;
  #pragma unroll
  for (int d = 1; d < 64; d <<= 1) {
    int t = __shfl_up(v3, d);
    if (lane >= d) v3 += t;
  }
  if (lane == 63) wsumB[wave] = v3;
  __syncthreads();
  int offc = 0;
  #pragma unroll
  for (int w = 0; w < 4; ++w) offc += (w < wave) ? wsumB[w] : 0;
  int o = v3 + offc - cnt2;
  tieoff = tie_excl;
  #pragma unroll
  for (int j = 0; j < 16; ++j) {
    unsigned int k = keys[base + j];
    int f = (k > thr) ? 1 : 0;
    if (k == thr) { f = (tieoff < need) ? 1 : 0; ++tieoff; }
    if (base + j == 0) f = 1;
    if (f) sel[o++] = base + j;
  }
  __syncthreads();

  const float* src = which ? Qg : Kg;
  float* dst = (which ? nr : nc) + (long)bh * MM * DD;
  float scale = which ? 0.125f : 1.0f;
  for (int e = tid; e < MM * 16; e += 256) {
    int i = e >> 4, d4 = e & 15;
    float4 v = *(const float4*)&src[((long)bh * NTOK + sel[i]) * DD + d4 * 4];
    v.x *= scale; v.y *= scale; v.z *= scale; v.w *= scale;
    *(float4*)&dst[i * DD + d4 * 4] = v;
  }
}

// ---------------- u = row-softmax(nr @ nc^T); write u; per-bh colsum max
__global__ __launch_bounds__(256) void k_u(const float* __restrict__ nc,
    const float* __restrict__ nr, float* __restrict__ u, float* __restrict__ smax) {
  int bh = blockIdx.x, tid = threadIdx.x, ti = tid >> 4, tj = tid & 15;
  __shared__ float A[MM][PAD];
  __shared__ float BT[DD][MM];
  __shared__ float cs[4][MM];
  for (int e = tid; e < 1024; e += 256) {
    int m = e >> 4, d4 = e & 15;
    *(float4*)&A[m][d4*4] = *(const float4*)&nr[(long)bh*MM*DD + m*DD + d4*4];
    float4 c = *(const float4*)&nc[(long)bh*MM*DD + m*DD + d4*4];
    BT[d4*4+0][m] = c.x; BT[d4*4+1][m] = c.y; BT[d4*4+2][m] = c.z; BT[d4*4+3][m] = c.w;
  }
  __syncthreads();
  float acc[4][4] = {};
  mm_acc<PAD, MM>(acc, A, BT, ti, tj);
  float e_[4][4];
  #pragma unroll
  for (int x = 0; x < 4; ++x)
    #pragma unroll
    for (int y = 0; y < 4; ++y) e_[x][y] = expf(acc[x][y]);
  float rsx[4];
  #pragma unroll
  for (int x = 0; x < 4; ++x) {
    rsx[x] = e_[x][0] + e_[x][1] + e_[x][2] + e_[x][3];
    rsx[x] += __shfl_xor(rsx[x], 1); rsx[x] += __shfl_xor(rsx[x], 2);
    rsx[x] += __shfl_xor(rsx[x], 4); rsx[x] += __shfl_xor(rsx[x], 8);
  }
  float cp[4] = {0.f, 0.f, 0.f, 0.f};
  #pragma unroll
  for (int x = 0; x < 4; ++x) {
    float inv = 1.f / rsx[x];
    float v0 = e_[x][0]*inv, v1 = e_[x][1]*inv, v2 = e_[x][2]*inv, v3 = e_[x][3]*inv;
    cp[0] += v0; cp[1] += v1; cp[2] += v2; cp[3] += v3;
    float4 o; o.x = v0; o.y = v1; o.z = v2; o.w = v3;
    *(float4*)&u[(long)bh*MM*MM + (ti*4+x)*MM + tj*4] = o;
  }
  #pragma unroll
  for (int y = 0; y < 4; ++y) {
    cp[y] += __shfl_xor(cp[y], 16);
    cp[y] += __shfl_xor(cp[y], 32);
  }
  if (((tid >> 4) & 3) == 0) {
    #pragma unroll
    for (int y = 0; y < 4; ++y) cs[tid >> 6][tj*4 + y] = cp[y];
  }
  __syncthreads();
  if (tid < 64) {
    float tot = cs[0][tid] + cs[1][tid] + cs[2][tid] + cs[3][tid];
    for (int off = 32; off; off >>= 1) tot = fmaxf(tot, __shfl_xor(tot, off));
    if (tid == 0) smax[bh] = tot;
  }
}

// =============== Newton iteration body (8 waves, PR = fp32-faithful split) ===============
template<bool PR>
__device__ __forceinline__ void ns_iter(
    f16 (*VT_h)[72], f16 (*VT_l)[72], f16 (*Vr_h)[72], f16 (*Vr_l)[72],
    f16 (*PT_h)[72], f16 (*PT_l)[72], f16 (*RT_h)[72], f16 (*RT_l)[72],
    const f16x8 kb_h[2], const f16x8 kb_l[2],
    int wr, int wc, int lm, int hi, bool last, float* __restrict__ vout) {
  // ---- step 1: S^T slices (all 4 g, duplicated across wc) ----
  f32x4 st[4];
  #pragma unroll
  for (int g = 0; g < 4; ++g) {
    f16x8 ah0 = *(const f16x8*)&VT_h[g*16 + lm][hi*8];
    f16x8 ah1 = *(const f16x8*)&VT_h[g*16 + lm][32 + hi*8];
    if (PR) {
      f16x8 al0 = *(const f16x8*)&VT_l[g*16 + lm][hi*8];
      f16x8 al1 = *(const f16x8*)&VT_l[g*16 + lm][32 + hi*8];
      st[g] = mm6(ah0, ah1, al0, al1, kb_h[0], kb_h[1], kb_l[0], kb_l[1]);
    } else {
      st[g] = mm2(ah0, ah1, kb_h[0], kb_h[1]);
    }
  }
  f16x8 sa_h[2], sa_l[2];
  #pragma unroll
  for (int g = 0; g < 4; ++g)
    #pragma unroll
    for (int r = 0; r < 4; ++r) {
      if (PR) {
        f16 h, l; fsplit(st[g][r], &h, &l);
        sa_h[g >> 1][(g & 1)*4 + r] = h;
        sa_l[g >> 1][(g & 1)*4 + r] = l;
      } else {
        sa_h[g >> 1][(g & 1)*4 + r] = (f16)st[g][r];
      }
    }
  if (wc == 0) {
    #pragma unroll
    for (int g = 0; g < 4; ++g)
      #pragma unroll
      for (int r = 0; r < 4; ++r) {
        int i = g*16 + hi*4 + r, j = wr*16 + lm;
        float pv = (i == j ? 7.f : 0.f) - st[g][r];
        if (PR) {
          f16 h, l; fsplit(pv, &h, &l);
          PT_h[i][j] = h; PT_l[i][j] = l;
        } else {
          PT_h[i][j] = (f16)pv;
        }
      }
  }
  __syncthreads();

  // ---- step 2: R = 15I - S@P -> RT ----
  #pragma unroll
  for (int cc2 = 0; cc2 < 2; ++cc2) {
    int cc = wc*2 + cc2;
    V8U bh0, bh1, bl0, bl1;
    bh0.q[0] = *(const f16x4*)&PT_h[cc*16 + lm][hi*4];
    bh0.q[1] = *(const f16x4*)&PT_h[cc*16 + lm][16 + hi*4];
    bh1.q[0] = *(const f16x4*)&PT_h[cc*16 + lm][32 + hi*4];
    bh1.q[1] = *(const f16x4*)&PT_h[cc*16 + lm][48 + hi*4];
    f32x4 a;
    if (PR) {
      bl0.q[0] = *(const f16x4*)&PT_l[cc*16 + lm][hi*4];
      bl0.q[1] = *(const f16x4*)&PT_l[cc*16 + lm][16 + hi*4];
      bl1.q[0] = *(const f16x4*)&PT_l[cc*16 + lm][32 + hi*4];
      bl1.q[1] = *(const f16x4*)&PT_l[cc*16 + lm][48 + hi*4];
      a = mm6(sa_h[0], sa_h[1], sa_l[0], sa_l[1], bh0.v, bh1.v, bl0.v, bl1.v);
    } else {
      a = mm2(sa_h[0], sa_h[1], bh0.v, bh1.v);
    }
    f16x4 wh, wl;
    #pragma unroll
    for (int r = 0; r < 4; ++r) {
      int row = wr*16 + hi*4 + r, col = cc*16 + lm;
      float rv = (row == col ? 15.f : 0.f) - a[r];
      if (PR) { f16 h, l; fsplit(rv, &h, &l); wh[r] = h; wl[r] = l; }
      else wh[r] = (f16)rv;
    }
    *(f16x4*)&RT_h[cc*16 + lm][wr*16 + hi*4] = wh;
    if (PR) *(f16x4*)&RT_l[cc*16 + lm][wr*16 + hi*4] = wl;
  }
  __syncthreads();

  // ---- step 3: W = 13I - S@R -> WT (into PT bufs) ----
  #pragma unroll
  for (int cc2 = 0; cc2 < 2; ++cc2) {
    int cc = wc*2 + cc2;
    V8U bh0, bh1, bl0, bl1;
    bh0.q[0] = *(const f16x4*)&RT_h[cc*16 + lm][hi*4];
    bh0.q[1] = *(const f16x4*)&RT_h[cc*16 + lm][16 + hi*4];
    bh1.q[0] = *(const f16x4*)&RT_h[cc*16 + lm][32 + hi*4];
    bh1.q[1] = *(const f16x4*)&RT_h[cc*16 + lm][48 + hi*4];
    f32x4 a;
    if (PR) {
      bl0.q[0] = *(const f16x4*)&RT_l[cc*16 + lm][hi*4];
      bl0.q[1] = *(const f16x4*)&RT_l[cc*16 + lm][16 + hi*4];
      bl1.q[0] = *(const f16x4*)&RT_l[cc*16 + lm][32 + hi*4];
      bl1.q[1] = *(const f16x4*)&RT_l[cc*16 + lm][48 + hi*4];
      a = mm6(sa_h[0], sa_h[1], sa_l[0], sa_l[1], bh0.v, bh1.v, bl0.v, bl1.v);
    } else {
      a = mm2(sa_h[0], sa_h[1], bh0.v, bh1.v);
    }
    f16x4 wh, wl;
    #pragma unroll
    for (int r = 0; r < 4; ++r) {
      int row = wr*16 + hi*4 + r, col = cc*16 + lm;
      float wv = (row == col ? 13.f : 0.f) - a[r];
      if (PR) { f16 h, l; fsplit(wv, &h, &l); wh[r] = h; wl[r] = l; }
      else wh[r] = (f16)wv;
    }
    *(f16x4*)&PT_h[cc*16 + lm][wr*16 + hi*4] = wh;
    if (PR) *(f16x4*)&PT_l[cc*16 + lm][wr*16 + hi*4] = wl;
  }
  __syncthreads();

  // ---- step 4: V' = 0.25 V@W ----
  f16x8 vh0 = *(const f16x8*)&Vr_h[wr*16 + lm][hi*8];
  f16x8 vh1 = *(const f16x8*)&Vr_h[wr*16 + lm][32 + hi*8];
  f16x8 vl0, vl1;
  if (PR) {
    vl0 = *(const f16x8*)&Vr_l[wr*16 + lm][hi*8];
    vl1 = *(const f16x8*)&Vr_l[wr*16 + lm][32 + hi*8];
  }
  #pragma unroll
  for (int cc2 = 0; cc2 < 2; ++cc2) {
    int cc = wc*2 + cc2;
    f16x8 wh0 = *(const f16x8*)&PT_h[cc*16 + lm][hi*8];
    f16x8 wh1 = *(const f16x8*)&PT_h[cc*16 + lm][32 + hi*8];
    f32x4 a;
    if (PR) {
      f16x8 wl0 = *(const f16x8*)&PT_l[cc*16 + lm][hi*8];
      f16x8 wl1 = *(const f16x8*)&PT_l[cc*16 + lm][32 + hi*8];
      a = mm6(vh0, vh1, vl0, vl1, wh0, wh1, wl0, wl1);
    } else {
      a = mm2(vh0, vh1, wh0, wh1);
    }
    if (last) {
      #pragma unroll
      for (int r = 0; r < 4; ++r)
        vout[(wr*16 + hi*4 + r)*MM + cc*16 + lm] = 0.25f * a[r];
    } else {
      f16x4 th, tl;
      #pragma unroll
      for (int r = 0; r < 4; ++r) {
        float vv = 0.25f * a[r];
        f16 h, l; fsplit(vv, &h, &l);         // always h+l so first PR iter is clean
        Vr_h[wr*16 + hi*4 + r][cc*16 + lm] = h;
        Vr_l[wr*16 + hi*4 + r][cc*16 + lm] = l;
        th[r] = h; tl[r] = l;
      }
      *(f16x4*)&VT_h[cc*16 + lm][wr*16 + hi*4] = th;
      *(f16x4*)&VT_l[cc*16 + lm][wr*16 + hi*4] = tl;
    }
  }
  __syncthreads();
}

__device__ void newton_dev(char* smem, const float* __restrict__ u,
    const float* __restrict__ smax, float* __restrict__ vinv, int bh) {
  f16 (*VT_h)[72] = (f16(*)[72])(smem);
  f16 (*VT_l)[72] = (f16(*)[72])(smem + 9216);
  f16 (*Vr_h)[72] = (f16(*)[72])(smem + 18432);
  f16 (*Vr_l)[72] = (f16(*)[72])(smem + 27648);
  f16 (*PT_h)[72] = (f16(*)[72])(smem + 36864);
  f16 (*PT_l)[72] = (f16(*)[72])(smem + 46080);
  f16 (*RT_h)[72] = (f16(*)[72])(smem + 55296);
  f16 (*RT_l)[72] = (f16(*)[72])(smem + 64512);
  int tid = threadIdx.x;
  int wave = tid >> 6, lane = tid & 63;
  int wr = wave >> 1, wc = wave & 1;
  int lm = lane & 15, hi = lane >> 4;

  float gmx = smax[0];
  #pragma unroll
  for (int i = 1; i < 32; ++i) gmx = fmaxf(gmx, smax[i]);
  float c0 = 1.0f / gmx;

  const float* pu = u + (long)bh * MM * MM;
  for (int e = tid; e < 4096; e += 512) {
    int i = e >> 6, j = e & 63;
    float sv = pu[e] * c0;
    f16 h, l;
    fsplit(sv, &h, &l);
    VT_h[i][j] = h; VT_l[i][j] = l;    // V0^T = c*K
    Vr_h[j][i] = h; Vr_l[j][i] = l;    // V0 = c*K^T
  }
  // K B-frag straight from global (u is L2-hot)
  f16x8 kb_h[2], kb_l[2];
  {
    const float* p = pu + (wr*16 + lm) * 64;
    float kv[16];
    *(float4*)&kv[0]  = *(const float4*)(p + hi*8);
    *(float4*)&kv[4]  = *(const float4*)(p + hi*8 + 4);
    *(float4*)&kv[8]  = *(const float4*)(p + 32 + hi*8);
    *(float4*)&kv[12] = *(const float4*)(p + 36 + hi*8);
    #pragma unroll
    for (int j = 0; j < 8; ++j) {
      f16 h, l;
      fsplit(kv[j], &h, &l);     kb_h[0][j] = h; kb_l[0][j] = l;
      fsplit(kv[8+j], &h, &l);   kb_h[1][j] = h; kb_l[1][j] = l;
    }
  }
  __syncthreads();

  ns_iter<false>(VT_h, VT_l, Vr_h, Vr_l, PT_h, PT_l, RT_h, RT_l, kb_h, kb_l, wr, wc, lm, hi, false, nullptr);
  ns_iter<false>(VT_h, VT_l, Vr_h, Vr_l, PT_h, PT_l, RT_h, RT_l, kb_h, kb_l, wr, wc, lm, hi, false, nullptr);
  ns_iter<false>(VT_h, VT_l, Vr_h, Vr_l, PT_h, PT_l, RT_h, RT_l, kb_h, kb_l, wr, wc, lm, hi, false, nullptr);
  ns_iter<true >(VT_h, VT_l, Vr_h, Vr_l, PT_h, PT_l, RT_h, RT_l, kb_h, kb_l, wr, wc, lm, hi, false, nullptr);
  ns_iter<true >(VT_h, VT_l, Vr_h, Vr_l, PT_h, PT_l, RT_h, RT_l, kb_h, kb_l, wr, wc, lm, hi, false, nullptr);
  ns_iter<true >(VT_h, VT_l, Vr_h, Vr_l, PT_h, PT_l, RT_h, RT_l, kb_h, kb_l, wr, wc, lm, hi, true,
                 vinv + (long)bh * MM * MM);
}

// w3 as two independent 256-thread halves in a 512-thread block
__device__ void w3_dev(char* smem, const float* __restrict__ Kg,
    const float* __restrict__ Vg, const int* __restrict__ maskg,
    const float* __restrict__ nr, float* __restrict__ nump,
    float* __restrict__ denp, int idx) {
  int bh = idx >> 3, grp = idx & 7, b = bh >> 3;
  int tid = threadIdx.x;
  int half = tid >> 8, t = tid & 255;
  f16 (*Ks)[72] = (f16(*)[72])(smem + half * 18432);
  f16 (*Vs)[72] = (f16(*)[72])(smem + half * 18432 + 9216);
  float* kmul = (float*)(smem + 36864) + half * 64;
  int lane = tid & 63;
  int lm = lane & 15, hi = lane >> 4;
  int wv = t >> 6;
  int m0 = wv * 16;
  int gslot = grp * 2 + half;

  f16x8 nrf[2];
  {
    const float* p = nr + (long)bh*MM*DD + (long)(m0 + lm)*DD + hi*8;
    float4 q0 = *(const float4*)p;
    float4 q1 = *(const float4*)(p + 4);
    float4 q2 = *(const float4*)(p + 32);
    float4 q3 = *(const float4*)(p + 36);
    nrf[0][0]=(f16)q0.x; nrf[0][1]=(f16)q0.y; nrf[0][2]=(f16)q0.z; nrf[0][3]=(f16)q0.w;
    nrf[0][4]=(f16)q1.x; nrf[0][5]=(f16)q1.y; nrf[0][6]=(f16)q1.z; nrf[0][7]=(f16)q1.w;
    nrf[1][0]=(f16)q2.x; nrf[1][1]=(f16)q2.y; nrf[1][2]=(f16)q2.z; nrf[1][3]=(f16)q2.w;
    nrf[1][4]=(f16)q3.x; nrf[1][5]=(f16)q3.y; nrf[1][6]=(f16)q3.z; nrf[1][7]=(f16)q3.w;
  }

  f32x4 nacc[4];
  #pragma unroll
  for (int dt = 0; dt < 4; ++dt) nacc[dt] = (f32x4){0.f, 0.f, 0.f, 0.f};
  float dsum = 0.f;

  for (int sc = 0; sc < 4; ++sc) {
    int n0c = (gslot * 4 + sc) * 64;
    if (sc) __syncthreads();
    for (int s = t; s < 1024; s += 256) {
      int row = s >> 4, c4 = s & 15;
      float4 kv = *(const float4*)&Kg[((long)bh*NTOK + n0c + row)*DD + c4*4];
      float4 vv = *(const float4*)&Vg[((long)bh*NTOK + n0c + row)*DD + c4*4];
      f16x4 kk = {(f16)kv.x, (f16)kv.y, (f16)kv.z, (f16)kv.w};
      f16x4 vv4 = {(f16)vv.x, (f16)vv.y, (f16)vv.z, (f16)vv.w};
      *(f16x4*)&Ks[row][c4*4] = kk;
      *(f16x4*)&Vs[row][c4*4] = vv4;
    }
    if (t < 64) kmul[t] = maskg[b * NTOK + n0c + t] ? 1.f : 0.f;
    __syncthreads();

    f32x4 stv[4];
    #pragma unroll
    for (int g = 0; g < 4; ++g) {
      f16x8 a0 = *(const f16x8*)&Ks[g*16 + lm][hi*8];
      f16x8 a1 = *(const f16x8*)&Ks[g*16 + lm][32 + hi*8];
      stv[g] = mm2(a0, a1, nrf[0], nrf[1]);
    }
    f16x8 pa[2];
    #pragma unroll
    for (int g = 0; g < 4; ++g) {
      #pragma unroll
      for (int r = 0; r < 4; ++r) {
        float p = __expf(stv[g][r]) * kmul[g*16 + hi*4 + r];
        dsum += p;
        pa[g >> 1][(g & 1)*4 + r] = (f16)p;
      }
    }
    #pragma unroll
    for (int dt = 0; dt < 4; ++dt) {
      f16x8 vb0, vb1;
      #pragma unroll
      for (int j = 0; j < 8; ++j) {
        int nrow = hi*4 + (j & 3) + 16*(j >> 2);
        vb0[j] = Vs[nrow][dt*16 + lm];
        vb1[j] = Vs[32 + nrow][dt*16 + lm];
      }
      nacc[dt] = __builtin_amdgcn_mfma_f32_16x16x32_f16(pa[0], vb0, nacc[dt], 0, 0, 0);
      nacc[dt] = __builtin_amdgcn_mfma_f32_16x16x32_f16(pa[1], vb1, nacc[dt], 0, 0, 0);
    }
  }
  float* pnum = nump + ((long)bh * GPART + gslot) * (MM * DD);
  #pragma unroll
  for (int dt = 0; dt < 4; ++dt)
    #pragma unroll
    for (int r = 0; r < 4; ++r)
      pnum[(m0 + hi*4 + r)*DD + dt*16 + lm] = nacc[dt][r];
  float d2 = dsum + __shfl_xor(dsum, 16);
  d2 += __shfl_xor(d2, 32);
  if (lane < 16)
    denp[((long)bh * GPART + gslot) * MM + m0 + lane] = d2;
}

// merged launch: blocks [0,32) newton (independent of w3), blocks [32,288) w3
__global__ __launch_bounds__(512, 2) void k_mix(const float* __restrict__ u,
    const float* __restrict__ smax, float* __restrict__ vinv,
    const float* __restrict__ Kg, const float* __restrict__ Vg,
    const int* __restrict__ maskg, const float* __restrict__ nr,
    float* __restrict__ nump, float* __restrict__ denp) {
  __shared__ __align__(16) char smem[73728];
  if (blockIdx.x < 32)
    newton_dev(smem, u, smax, vinv, blockIdx.x);
  else
    w3_dev(smem, Kg, Vg, maskg, nr, nump, denp, blockIdx.x - 32);
}

// ---------------- Z = Vinv @ (sum_g num_g / sum_g den_g)
__global__ __launch_bounds__(256) void k_z(const float* __restrict__ vinv,
    const float* __restrict__ nump, const float* __restrict__ denp, float* __restrict__ Zg) {
  int bh = blockIdx.x, tid = threadIdx.x, ti = tid >> 4, tj = tid & 15;
  __shared__ float A[MM][PAD];
  __shared__ float W[MM][MM];
  __shared__ float dn[MM];
  if (tid < 64) {
    float s = 0.f;
    #pragma unroll
    for (int g = 0; g < GPART; ++g) s += denp[((long)bh * GPART + g) * MM + tid];
    dn[tid] = s;
  }
  for (int e = tid; e < 1024; e += 256) {
    int m = e >> 4, d4 = e & 15;
    *(float4*)&A[m][d4*4] = *(const float4*)&vinv[(long)bh*MM*MM + m*MM + d4*4];
  }
  __syncthreads();
  for (int e = tid; e < 1024; e += 256) {
    int m = e >> 4, d4 = e & 15;
    float4 s = {0.f, 0.f, 0.f, 0.f};
    #pragma unroll
    for (int g = 0; g < GPART; ++g) {
      float4 t = *(const float4*)&nump[((long)bh * GPART + g) * (MM*DD) + m*DD + d4*4];
      s.x += t.x; s.y += t.y; s.z += t.z; s.w += t.w;
    }
    float inv = 1.f / dn[m];
    s.x *= inv; s.y *= inv; s.z *= inv; s.w *= inv;
    *(float4*)&W[m][d4*4] = s;
  }
  __syncthreads();
  float acc[4][4] = {};
  mm_acc<PAD, MM>(acc, A, W, ti, tj);
  #pragma unroll
  for (int x = 0; x < 4; ++x) {
    float4 o; o.x = acc[x][0]; o.y = acc[x][1]; o.z = acc[x][2]; o.w = acc[x][3];
    *(float4*)&Zg[(long)bh*MM*DD + (ti*4+x)*DD + tj*4] = o;
  }
}

// ---------------- MFMA X = row-softmax(Qs @ nc^T) @ Z  (swapped S^T trick)
__global__ __launch_bounds__(256) void k_final(const float* __restrict__ Qg,
    const float* __restrict__ nc, const float* __restrict__ Zg, float* __restrict__ Xg) {
  int bh = blockIdx.x, chunk = blockIdx.y;
  int tid = threadIdx.x;
  int wave = tid >> 6, lane = tid & 63;
  int lm = lane & 15, hi = lane >> 4;
  int n0 = chunk * 64;
  __shared__ f16 Qs[64][72];
  __shared__ f16 Ncs[64][72];
  __shared__ f16 Zs[64][72];
  for (int s = tid; s < 1024; s += 256) {
    int row = s >> 4, c4 = s & 15;
    float4 q = *(const float4*)&Qg[((long)bh*NTOK + n0 + row)*DD + c4*4];
    f16x4 qq = {(f16)(q.x*0.125f), (f16)(q.y*0.125f), (f16)(q.z*0.125f), (f16)(q.w*0.125f)};
    *(f16x4*)&Qs[row][c4*4] = qq;
    float4 cv = *(const float4*)&nc[(long)bh*MM*DD + row*DD + c4*4];
    f16x4 cc = {(f16)cv.x, (f16)cv.y, (f16)cv.z, (f16)cv.w};
    *(f16x4*)&Ncs[row][c4*4] = cc;
    float4 zv = *(const float4*)&Zg[(long)bh*MM*DD + row*DD + c4*4];
    f16x4 zz = {(f16)zv.x, (f16)zv.y, (f16)zv.z, (f16)zv.w};
    *(f16x4*)&Zs[row][c4*4] = zz;
  }
  __syncthreads();

  f16x8 qb0 = *(const f16x8*)&Qs[wave*16 + lm][hi*8];
  f16x8 qb1 = *(const f16x8*)&Qs[wave*16 + lm][32 + hi*8];
  f32x4 stv[4];
  #pragma unroll
  for (int mt = 0; mt < 4; ++mt) {
    f16x8 a0 = *(const f16x8*)&Ncs[mt*16 + lm][hi*8];
    f16x8 a1 = *(const f16x8*)&Ncs[mt*16 + lm][32 + hi*8];
    stv[mt] = mm2(a0, a1, qb0, qb1);
  }
  f16x8 pa[2];
  float dsum = 0.f;
  #pragma unroll
  for (int mt = 0; mt < 4; ++mt) {
    #pragma unroll
    for (int r = 0; r < 4; ++r) {
      float p = __expf(stv[mt][r]);
      dsum += p;
      pa[mt >> 1][(mt & 1)*4 + r] = (f16)p;
    }
  }
  float dtot = dsum + __shfl_xor(dsum, 16);
  dtot += __shfl_xor(dtot, 32);
  f32x4 xacc[4];
  #pragma unroll
  for (int dt = 0; dt < 4; ++dt) {
    f16x8 zb0, zb1;
    #pragma unroll
    for (int j = 0; j < 8; ++j) {
      int mrow = hi*4 + (j & 3) + 16*(j >> 2);
      zb0[j] = Zs[mrow][dt*16 + lm];
      zb1[j] = Zs[32 + mrow][dt*16 + lm];
    }
    f32x4 c = {0.f, 0.f, 0.f, 0.f};
    c = __builtin_amdgcn_mfma_f32_16x16x32_f16(pa[0], zb0, c, 0, 0, 0);
    c = __builtin_amdgcn_mfma_f32_16x16x32_f16(pa[1], zb1, c, 0, 0, 0);
    xacc[dt] = c;
  }
  float rn[4];
  #pragma unroll
  for (int r = 0; r < 4; ++r) rn[r] = 1.f / __shfl(dtot, hi*4 + r);
  #pragma unroll
  for (int dt = 0; dt < 4; ++dt)
    #pragma unroll
    for (int r = 0; r < 4; ++r)
      Xg[((long)bh*NTOK + n0 + wave*16 + hi*4 + r)*DD + dt*16 + lm] = xacc[dt][r] * rn[r];
}

extern "C" void kernel_launch(void* const* d_in, const int* in_sizes, int n_in,
                              void* d_out, int out_size, void* d_ws, size_t ws_size,
                              hipStream_t stream) {
  (void)in_sizes; (void)n_in; (void)out_size; (void)ws_size;
  const float* Qp = (const float*)d_in[0];
  const float* Kp = (const float*)d_in[1];
  const float* Vp = (const float*)d_in[2];
  const int* maskp = (const int*)d_in[3];
  float* out = (float*)d_out;

  float* wsf = (float*)d_ws;
  float* NUMP = wsf;                                // 32*16*4096
  float* DENP = NUMP + (long)BHN * GPART * MM * DD; // 32*16*64
  float* SMAX = DENP + BHN * GPART * MM;            // 32
  float* NC = SMAX + 32;
  float* NR = NC + BHN * MM * DD;
  float* U  = NR + BHN * MM * DD;
  float* VI = U  + BHN * MM * MM;
  float* Zb = VI + BHN * MM * MM;
  float* SK = Zb + BHN * MM * DD;
  float* SQ = SK + BHN * NTOK;

  k_somme<<<16384, 256, 0, stream>>>(Kp, Qp, maskp, SK, SQ);
  k_select<<<dim3(32, 2), 256, 0, stream>>>(Kp, Qp, SK, SQ, NC, NR);
  k_u<<<32, 256, 0, stream>>>(NC, NR, U, SMAX);
  k_mix<<<32 + 256, 512, 0, stream>>>(U, SMAX, VI, Kp, Vp, maskp, NR, NUMP, DENP);
  k_z<<<32, 256, 0, stream>>>(VI, NUMP, DENP, Zb);
  k_final<<<dim3(32, 64), 256, 0, stream>>>(Qp, NC, Zb, out);
}

// Round 7
// 82.033 us; speedup vs baseline: 7.2771x; 1.0049x over previous
//
#include <hip/hip_runtime.h>
#include <float.h>

#define BB 4
#define HH 8
#define BHN 32
#define NTOK 4096
#define DD 64
#define MM 64
#define PAD 68
#define GPART 16

typedef _Float16 f16;
typedef __attribute__((ext_vector_type(4))) _Float16 f16x4;
typedef __attribute__((ext_vector_type(8))) _Float16 f16x8;
typedef __attribute__((ext_vector_type(4))) float f32x4;

union V8U { f16x8 v; f16x4 q[2]; };

__device__ __forceinline__ void fsplit(float v, f16* h, f16* l) {
  f16 hh = (f16)v;
  *h = hh;
  *l = (f16)(v - (float)hh);
}

// plain f16 (2-chain)
__device__ __forceinline__ f32x4 mm2(f16x8 a0, f16x8 a1, f16x8 b0, f16x8 b1) {
  f32x4 c = {0.f, 0.f, 0.f, 0.f};
  c = __builtin_amdgcn_mfma_f32_16x16x32_f16(a0, b0, c, 0, 0, 0);
  c = __builtin_amdgcn_mfma_f32_16x16x32_f16(a1, b1, c, 0, 0, 0);
  return c;
}

// 6-term fp32-faithful f16-split, as two independent 3-chains
__device__ __forceinline__ f32x4 mm6(f16x8 ah0, f16x8 ah1, f16x8 al0, f16x8 al1,
                                     f16x8 bh0, f16x8 bh1, f16x8 bl0, f16x8 bl1) {
  f32x4 a = {0.f, 0.f, 0.f, 0.f};
  f32x4 b = {0.f, 0.f, 0.f, 0.f};
  a = __builtin_amdgcn_mfma_f32_16x16x32_f16(ah0, bh0, a, 0, 0, 0);
  a = __builtin_amdgcn_mfma_f32_16x16x32_f16(ah0, bl0, a, 0, 0, 0);
  a = __builtin_amdgcn_mfma_f32_16x16x32_f16(al0, bh0, a, 0, 0, 0);
  b = __builtin_amdgcn_mfma_f32_16x16x32_f16(ah1, bh1, b, 0, 0, 0);
  b = __builtin_amdgcn_mfma_f32_16x16x32_f16(ah1, bl1, b, 0, 0, 0);
  b = __builtin_amdgcn_mfma_f32_16x16x32_f16(al1, bh1, b, 0, 0, 0);
  return a + b;
}

// ---------------- 4x4-tile 64x64x64 matmul helper (fp32 scalar, small kernels)
template<int LDA, int LDB>
__device__ __forceinline__ void mm_acc(float acc[4][4],
    const float (*A)[LDA], const float (*B)[LDB], int ti, int tj) {
  #pragma unroll
  for (int k4 = 0; k4 < 16; ++k4) {
    float a[4][4], b[4][4];
    #pragma unroll
    for (int x = 0; x < 4; ++x) {
      float4 t = *(const float4*)&A[ti*4+x][k4*4];
      a[x][0]=t.x; a[x][1]=t.y; a[x][2]=t.z; a[x][3]=t.w;
    }
    #pragma unroll
    for (int kk = 0; kk < 4; ++kk) {
      float4 t = *(const float4*)&B[k4*4+kk][tj*4];
      b[kk][0]=t.x; b[kk][1]=t.y; b[kk][2]=t.z; b[kk][3]=t.w;
    }
    #pragma unroll
    for (int kk = 0; kk < 4; ++kk)
      #pragma unroll
      for (int x = 0; x < 4; ++x)
        #pragma unroll
        for (int y = 0; y < 4; ++y)
          acc[x][y] = fmaf(a[x][kk], b[kk][y], acc[x][y]);
  }
}

// ---------------- row sums for selection (both K and Q), mask/token0 -> -FLT_MAX
__global__ __launch_bounds__(256) void k_somme(const float* __restrict__ Kg,
    const float* __restrict__ Qg, const int* __restrict__ mask,
    float* __restrict__ somK, float* __restrict__ somQ) {
  int tid = threadIdx.x;
  int lane = tid & 63;
  long grow = (long)blockIdx.x * 16 + (tid >> 6) * 4 + (lane >> 4);
  int which = grow >= (long)(BHN * NTOK);
  long row = which ? grow - (long)BHN * NTOK : grow;   // bh*N + n
  int n = (int)(row & (NTOK - 1));
  int bh = (int)(row >> 12);
  int b = bh >> 3;
  const float* src = which ? Qg : Kg;
  float4 v = *((const float4*)(src + row * DD) + (lane & 15));
  float s = v.x + v.y + v.z + v.w;
  s += __shfl_xor(s, 1); s += __shfl_xor(s, 2);
  s += __shfl_xor(s, 4); s += __shfl_xor(s, 8);
  if ((lane & 15) == 0) {
    float out = (n == 0 || mask[b * NTOK + n] != 0) ? -FLT_MAX : s;
    (which ? somQ : somK)[row] = out;
  }
}

// ---------------- per-(bh,which): radix top-63 select (wave-shfl scans) + gather
__global__ __launch_bounds__(256) void k_select(const float* __restrict__ Kg,
    const float* __restrict__ Qg, const float* __restrict__ somK,
    const float* __restrict__ somQ, float* __restrict__ nc, float* __restrict__ nr) {
  int bh = blockIdx.x;
  int which = blockIdx.y;           // 0: K -> nc, 1: Q (scaled) -> nr
  __shared__ unsigned int keys[NTOK];       // 16KB
  __shared__ unsigned int wb[4][256];       // per-wave histograms, 4KB
  __shared__ int wsum[4];
  __shared__ int wsumB[4];
  __shared__ int sh_bin, sh_need;
  __shared__ int sel[MM];
  int tid = threadIdx.x, wave = tid >> 6, lane = tid & 63;
  const float* som = (which ? somQ : somK) + (long)bh * NTOK;
  for (int i = tid; i < NTOK; i += 256) {
    float f = som[i];
    unsigned int u = __float_as_uint(f);
    u = (u & 0x80000000u) ? ~u : (u | 0x80000000u);   // monotone map, ascending
    keys[i] = (i == 0) ? 0u : u;                      // token 0 out of competition
  }
  unsigned int pref = 0; int need = MM - 1;           // 63
  for (int pass = 0; pass < 4; ++pass) {
    int shift = 24 - pass * 8;
    unsigned int pm = (pass == 0) ? 0u : (0xFFFFFFFFu << (32 - 8 * pass));
    unsigned int* wbf = (unsigned int*)wb;
    wbf[tid] = 0; wbf[tid + 256] = 0; wbf[tid + 512] = 0; wbf[tid + 768] = 0;
    __syncthreads();
    for (int i = tid; i < NTOK; i += 256) {
      unsigned int k = keys[i];
      if ((k & pm) == pref) atomicAdd(&wb[wave][(k >> shift) & 255], 1u);
    }
    __syncthreads();
    int binr = 255 - tid;                             // reversed position -> suffix sum
    int cnt = (int)(wb[0][binr] + wb[1][binr] + wb[2][binr] + wb[3][binr]);
    int v = cnt;
    #pragma unroll
    for (int d = 1; d < 64; d <<= 1) {
      int t = __shfl_up(v, d);
      if (lane >= d) v += t;
    }
    if (lane == 63) wsum[wave] = v;
    __syncthreads();
    int off = 0;
    #pragma unroll
    for (int w = 0; w < 4; ++w) off += (w < wave) ? wsum[w] : 0;
    v += off;
    int above = v - cnt;
    if (v >= need && above < need) { sh_bin = binr; sh_need = need - above; }
    __syncthreads();
    pref |= ((unsigned int)sh_bin) << shift;
    need = sh_need;
  }
  unsigned int thr = pref;

  int base = tid * 16;
  int ctie = 0;
  #pragma unroll
  for (int j = 0; j < 16; ++j) ctie += (keys[base + j] == thr);
  int v2 = ctie;
  #pragma unroll
  for (int d = 1; d < 64; d <<= 1) {
    int t = __shfl_up(v2, d);
    if (lane >= d) v2 += t;
  }
  if (lane == 63) wsum[wave] = v2;
  __syncthreads();
  int offt = 0;
  #pragma unroll
  for (int w = 0; w < 4; ++w) offt += (w < wave) ? wsum[w] : 0;
  int tie_excl = v2 + offt - ctie;

  int tieoff = tie_excl, cnt2 = 0;
  #pragma unroll
  for (int j = 0; j < 16; ++j) {
    unsigned int k = keys[base + j];
    int f = (k > thr) ? 1 : 0;
    if (k == thr) { f = (tieoff < need) ? 1 : 0; ++tieoff; }
    if (base + j == 0) f = 1;
    cnt2 += f;
  }
  int v3 = cnt2;
  #pragma unroll
  for (int d = 1; d < 64; d <<= 1) {
    int t = __shfl_up(v3, d);
    if (lane >= d) v3 += t;
  }
  if (lane == 63) wsumB[wave] = v3;
  __syncthreads();
  int offc = 0;
  #pragma unroll
  for (int w = 0; w < 4; ++w) offc += (w < wave) ? wsumB[w] : 0;
  int o = v3 + offc - cnt2;
  tieoff = tie_excl;
  #pragma unroll
  for (int j = 0; j < 16; ++j) {
    unsigned int k = keys[base + j];
    int f = (k > thr) ? 1 : 0;
    if (k == thr) { f = (tieoff < need) ? 1 : 0; ++tieoff; }
    if (base + j == 0) f = 1;
    if (f) sel[o++] = base + j;
  }
  __syncthreads();

  const float* src = which ? Qg : Kg;
  float* dst = (which ? nr : nc) + (long)bh * MM * DD;
  float scale = which ? 0.125f : 1.0f;
  for (int e = tid; e < MM * 16; e += 256) {
    int i = e >> 4, d4 = e & 15;
    float4 v = *(const float4*)&src[((long)bh * NTOK + sel[i]) * DD + d4 * 4];
    v.x *= scale; v.y *= scale; v.z *= scale; v.w *= scale;
    *(float4*)&dst[i * DD + d4 * 4] = v;
  }
}

// ---------------- u = row-softmax(nr @ nc^T); write u; per-bh colsum max
__global__ __launch_bounds__(256) void k_u(const float* __restrict__ nc,
    const float* __restrict__ nr, float* __restrict__ u, float* __restrict__ smax) {
  int bh = blockIdx.x, tid = threadIdx.x, ti = tid >> 4, tj = tid & 15;
  __shared__ float A[MM][PAD];
  __shared__ float BT[DD][MM];
  __shared__ float cs[4][MM];
  for (int e = tid; e < 1024; e += 256) {
    int m = e >> 4, d4 = e & 15;
    *(float4*)&A[m][d4*4] = *(const float4*)&nr[(long)bh*MM*DD + m*DD + d4*4];
    float4 c = *(const float4*)&nc[(long)bh*MM*DD + m*DD + d4*4];
    BT[d4*4+0][m] = c.x; BT[d4*4+1][m] = c.y; BT[d4*4+2][m] = c.z; BT[d4*4+3][m] = c.w;
  }
  __syncthreads();
  float acc[4][4] = {};
  mm_acc<PAD, MM>(acc, A, BT, ti, tj);
  float e_[4][4];
  #pragma unroll
  for (int x = 0; x < 4; ++x)
    #pragma unroll
    for (int y = 0; y < 4; ++y) e_[x][y] = expf(acc[x][y]);
  float rsx[4];
  #pragma unroll
  for (int x = 0; x < 4; ++x) {
    rsx[x] = e_[x][0] + e_[x][1] + e_[x][2] + e_[x][3];
    rsx[x] += __shfl_xor(rsx[x], 1); rsx[x] += __shfl_xor(rsx[x], 2);
    rsx[x] += __shfl_xor(rsx[x], 4); rsx[x] += __shfl_xor(rsx[x], 8);
  }
  float cp[4] = {0.f, 0.f, 0.f, 0.f};
  #pragma unroll
  for (int x = 0; x < 4; ++x) {
    float inv = 1.f / rsx[x];
    float v0 = e_[x][0]*inv, v1 = e_[x][1]*inv, v2 = e_[x][2]*inv, v3 = e_[x][3]*inv;
    cp[0] += v0; cp[1] += v1; cp[2] += v2; cp[3] += v3;
    float4 o; o.x = v0; o.y = v1; o.z = v2; o.w = v3;
    *(float4*)&u[(long)bh*MM*MM + (ti*4+x)*MM + tj*4] = o;
  }
  #pragma unroll
  for (int y = 0; y < 4; ++y) {
    cp[y] += __shfl_xor(cp[y], 16);
    cp[y] += __shfl_xor(cp[y], 32);
  }
  if (((tid >> 4) & 3) == 0) {
    #pragma unroll
    for (int y = 0; y < 4; ++y) cs[tid >> 6][tj*4 + y] = cp[y];
  }
  __syncthreads();
  if (tid < 64) {
    float tot = cs[0][tid] + cs[1][tid] + cs[2][tid] + cs[3][tid];
    for (int off = 32; off; off >>= 1) tot = fmaxf(tot, __shfl_xor(tot, off));
    if (tid == 0) smax[bh] = tot;
  }
}

// =============== Newton-Schulz, rolled loop (runtime-uniform PR), 8 waves ===============
__device__ void newton_dev(char* smem, const float* __restrict__ u,
    const float* __restrict__ smax, float* __restrict__ vinv, int bh) {
  f16 (*VT_h)[72] = (f16(*)[72])(smem);
  f16 (*VT_l)[72] = (f16(*)[72])(smem + 9216);
  f16 (*Vr_h)[72] = (f16(*)[72])(smem + 18432);
  f16 (*Vr_l)[72] = (f16(*)[72])(smem + 27648);
  f16 (*PT_h)[72] = (f16(*)[72])(smem + 36864);
  f16 (*PT_l)[72] = (f16(*)[72])(smem + 46080);
  f16 (*RT_h)[72] = (f16(*)[72])(smem + 55296);
  f16 (*RT_l)[72] = (f16(*)[72])(smem + 64512);
  int tid = threadIdx.x;
  int wave = tid >> 6, lane = tid & 63;
  int wr = wave >> 1, wc = wave & 1;
  int lm = lane & 15, hi = lane >> 4;

  float gmx = smax[0];
  #pragma unroll
  for (int i = 1; i < 32; ++i) gmx = fmaxf(gmx, smax[i]);
  float c0 = 1.0f / gmx;

  const float* pu = u + (long)bh * MM * MM;
  for (int e = tid; e < 4096; e += 512) {
    int i = e >> 6, j = e & 63;
    float sv = pu[e] * c0;
    f16 h, l;
    fsplit(sv, &h, &l);
    VT_h[i][j] = h; VT_l[i][j] = l;    // V0^T = c*K
    Vr_h[j][i] = h; Vr_l[j][i] = l;    // V0 = c*K^T
  }
  // K B-frag straight from global (u is L2-hot)
  f16x8 kb_h[2], kb_l[2];
  {
    const float* p = pu + (wr*16 + lm) * 64;
    float kv[16];
    *(float4*)&kv[0]  = *(const float4*)(p + hi*8);
    *(float4*)&kv[4]  = *(const float4*)(p + hi*8 + 4);
    *(float4*)&kv[8]  = *(const float4*)(p + 32 + hi*8);
    *(float4*)&kv[12] = *(const float4*)(p + 36 + hi*8);
    #pragma unroll
    for (int j = 0; j < 8; ++j) {
      f16 h, l;
      fsplit(kv[j], &h, &l);     kb_h[0][j] = h; kb_l[0][j] = l;
      fsplit(kv[8+j], &h, &l);   kb_h[1][j] = h; kb_l[1][j] = l;
    }
  }
  __syncthreads();

  for (int it = 0; it < 6; ++it) {
    const bool PR = (it >= 3);          // block-uniform
    const bool last = (it == 5);

    // ---- step 1: S^T slices (duplicated across wc) ----
    f32x4 st[4];
    #pragma unroll
    for (int g = 0; g < 4; ++g) {
      f16x8 ah0 = *(const f16x8*)&VT_h[g*16 + lm][hi*8];
      f16x8 ah1 = *(const f16x8*)&VT_h[g*16 + lm][32 + hi*8];
      if (PR) {
        f16x8 al0 = *(const f16x8*)&VT_l[g*16 + lm][hi*8];
        f16x8 al1 = *(const f16x8*)&VT_l[g*16 + lm][32 + hi*8];
        st[g] = mm6(ah0, ah1, al0, al1, kb_h[0], kb_h[1], kb_l[0], kb_l[1]);
      } else {
        st[g] = mm2(ah0, ah1, kb_h[0], kb_h[1]);
      }
    }
    f16x8 sa_h[2], sa_l[2];
    #pragma unroll
    for (int g = 0; g < 4; ++g)
      #pragma unroll
      for (int r = 0; r < 4; ++r) {
        if (PR) {
          f16 h, l; fsplit(st[g][r], &h, &l);
          sa_h[g >> 1][(g & 1)*4 + r] = h;
          sa_l[g >> 1][(g & 1)*4 + r] = l;
        } else {
          sa_h[g >> 1][(g & 1)*4 + r] = (f16)st[g][r];
        }
      }
    // write PT = 7I - S^T; wc=0 writes g 0,1; wc=1 writes g 2,3 (constant g indices)
    #pragma unroll
    for (int g = 0; g < 4; ++g) {
      if ((g >> 1) == wc) {
        #pragma unroll
        for (int r = 0; r < 4; ++r) {
          int i = g*16 + hi*4 + r, j = wr*16 + lm;
          float pv = (i == j ? 7.f : 0.f) - st[g][r];
          if (PR) {
            f16 h, l; fsplit(pv, &h, &l);
            PT_h[i][j] = h; PT_l[i][j] = l;
          } else {
            PT_h[i][j] = (f16)pv;
          }
        }
      }
    }
    __syncthreads();

    // ---- step 2: R = 15I - S@P -> RT ----
    #pragma unroll
    for (int cc2 = 0; cc2 < 2; ++cc2) {
      int cc = wc*2 + cc2;
      V8U bh0, bh1, bl0, bl1;
      bh0.q[0] = *(const f16x4*)&PT_h[cc*16 + lm][hi*4];
      bh0.q[1] = *(const f16x4*)&PT_h[cc*16 + lm][16 + hi*4];
      bh1.q[0] = *(const f16x4*)&PT_h[cc*16 + lm][32 + hi*4];
      bh1.q[1] = *(const f16x4*)&PT_h[cc*16 + lm][48 + hi*4];
      f32x4 a;
      if (PR) {
        bl0.q[0] = *(const f16x4*)&PT_l[cc*16 + lm][hi*4];
        bl0.q[1] = *(const f16x4*)&PT_l[cc*16 + lm][16 + hi*4];
        bl1.q[0] = *(const f16x4*)&PT_l[cc*16 + lm][32 + hi*4];
        bl1.q[1] = *(const f16x4*)&PT_l[cc*16 + lm][48 + hi*4];
        a = mm6(sa_h[0], sa_h[1], sa_l[0], sa_l[1], bh0.v, bh1.v, bl0.v, bl1.v);
      } else {
        a = mm2(sa_h[0], sa_h[1], bh0.v, bh1.v);
      }
      f16x4 wh, wl;
      #pragma unroll
      for (int r = 0; r < 4; ++r) {
        int row = wr*16 + hi*4 + r, col = cc*16 + lm;
        float rv = (row == col ? 15.f : 0.f) - a[r];
        if (PR) { f16 h, l; fsplit(rv, &h, &l); wh[r] = h; wl[r] = l; }
        else wh[r] = (f16)rv;
      }
      *(f16x4*)&RT_h[cc*16 + lm][wr*16 + hi*4] = wh;
      if (PR) *(f16x4*)&RT_l[cc*16 + lm][wr*16 + hi*4] = wl;
    }
    __syncthreads();

    // ---- step 3: W = 13I - S@R -> WT (into PT bufs) ----
    #pragma unroll
    for (int cc2 = 0; cc2 < 2; ++cc2) {
      int cc = wc*2 + cc2;
      V8U bh0, bh1, bl0, bl1;
      bh0.q[0] = *(const f16x4*)&RT_h[cc*16 + lm][hi*4];
      bh0.q[1] = *(const f16x4*)&RT_h[cc*16 + lm][16 + hi*4];
      bh1.q[0] = *(const f16x4*)&RT_h[cc*16 + lm][32 + hi*4];
      bh1.q[1] = *(const f16x4*)&RT_h[cc*16 + lm][48 + hi*4];
      f32x4 a;
      if (PR) {
        bl0.q[0] = *(const f16x4*)&RT_l[cc*16 + lm][hi*4];
        bl0.q[1] = *(const f16x4*)&RT_l[cc*16 + lm][16 + hi*4];
        bl1.q[0] = *(const f16x4*)&RT_l[cc*16 + lm][32 + hi*4];
        bl1.q[1] = *(const f16x4*)&RT_l[cc*16 + lm][48 + hi*4];
        a = mm6(sa_h[0], sa_h[1], sa_l[0], sa_l[1], bh0.v, bh1.v, bl0.v, bl1.v);
      } else {
        a = mm2(sa_h[0], sa_h[1], bh0.v, bh1.v);
      }
      f16x4 wh, wl;
      #pragma unroll
      for (int r = 0; r < 4; ++r) {
        int row = wr*16 + hi*4 + r, col = cc*16 + lm;
        float wv = (row == col ? 13.f : 0.f) - a[r];
        if (PR) { f16 h, l; fsplit(wv, &h, &l); wh[r] = h; wl[r] = l; }
        else wh[r] = (f16)wv;
      }
      *(f16x4*)&PT_h[cc*16 + lm][wr*16 + hi*4] = wh;
      if (PR) *(f16x4*)&PT_l[cc*16 + lm][wr*16 + hi*4] = wl;
    }
    __syncthreads();

    // ---- step 4: V' = 0.25 V@W ----
    f16x8 vh0 = *(const f16x8*)&Vr_h[wr*16 + lm][hi*8];
    f16x8 vh1 = *(const f16x8*)&Vr_h[wr*16 + lm][32 + hi*8];
    f16x8 vl0, vl1;
    if (PR) {
      vl0 = *(const f16x8*)&Vr_l[wr*16 + lm][hi*8];
      vl1 = *(const f16x8*)&Vr_l[wr*16 + lm][32 + hi*8];
    }
    #pragma unroll
    for (int cc2 = 0; cc2 < 2; ++cc2) {
      int cc = wc*2 + cc2;
      f16x8 wh0 = *(const f16x8*)&PT_h[cc*16 + lm][hi*8];
      f16x8 wh1 = *(const f16x8*)&PT_h[cc*16 + lm][32 + hi*8];
      f32x4 a;
      if (PR) {
        f16x8 wl0 = *(const f16x8*)&PT_l[cc*16 + lm][hi*8];
        f16x8 wl1 = *(const f16x8*)&PT_l[cc*16 + lm][32 + hi*8];
        a = mm6(vh0, vh1, vl0, vl1, wh0, wh1, wl0, wl1);
      } else {
        a = mm2(vh0, vh1, wh0, wh1);
      }
      if (last) {
        #pragma unroll
        for (int r = 0; r < 4; ++r)
          vinv[(long)bh*MM*MM + (wr*16 + hi*4 + r)*MM + cc*16 + lm] = 0.25f * a[r];
      } else {
        f16x4 th, tl;
        #pragma unroll
        for (int r = 0; r < 4; ++r) {
          float vv = 0.25f * a[r];
          f16 h, l; fsplit(vv, &h, &l);   // always h+l so first PR iter is clean
          Vr_h[wr*16 + hi*4 + r][cc*16 + lm] = h;
          Vr_l[wr*16 + hi*4 + r][cc*16 + lm] = l;
          th[r] = h; tl[r] = l;
        }
        *(f16x4*)&VT_h[cc*16 + lm][wr*16 + hi*4] = th;
        *(f16x4*)&VT_l[cc*16 + lm][wr*16 + hi*4] = tl;
      }
    }
    __syncthreads();
  }
}

// w3 as two independent 256-thread halves in a 512-thread block
__device__ void w3_dev(char* smem, const float* __restrict__ Kg,
    const float* __restrict__ Vg, const int* __restrict__ maskg,
    const float* __restrict__ nr, float* __restrict__ nump,
    float* __restrict__ denp, int idx) {
  int bh = idx >> 3, grp = idx & 7, b = bh >> 3;
  int tid = threadIdx.x;
  int half = tid >> 8, t = tid & 255;
  f16 (*Ks)[72] = (f16(*)[72])(smem + half * 18432);
  f16 (*Vs)[72] = (f16(*)[72])(smem + half * 18432 + 9216);
  float* kmul = (float*)(smem + 36864) + half * 64;
  int lane = tid & 63;
  int lm = lane & 15, hi = lane >> 4;
  int wv = t >> 6;
  int m0 = wv * 16;
  int gslot = grp * 2 + half;

  f16x8 nrf[2];
  {
    const float* p = nr + (long)bh*MM*DD + (long)(m0 + lm)*DD + hi*8;
    float4 q0 = *(const float4*)p;
    float4 q1 = *(const float4*)(p + 4);
    float4 q2 = *(const float4*)(p + 32);
    float4 q3 = *(const float4*)(p + 36);
    nrf[0][0]=(f16)q0.x; nrf[0][1]=(f16)q0.y; nrf[0][2]=(f16)q0.z; nrf[0][3]=(f16)q0.w;
    nrf[0][4]=(f16)q1.x; nrf[0][5]=(f16)q1.y; nrf[0][6]=(f16)q1.z; nrf[0][7]=(f16)q1.w;
    nrf[1][0]=(f16)q2.x; nrf[1][1]=(f16)q2.y; nrf[1][2]=(f16)q2.z; nrf[1][3]=(f16)q2.w;
    nrf[1][4]=(f16)q3.x; nrf[1][5]=(f16)q3.y; nrf[1][6]=(f16)q3.z; nrf[1][7]=(f16)q3.w;
  }

  f32x4 nacc[4];
  #pragma unroll
  for (int dt = 0; dt < 4; ++dt) nacc[dt] = (f32x4){0.f, 0.f, 0.f, 0.f};
  float dsum = 0.f;

  for (int sc = 0; sc < 4; ++sc) {
    int n0c = (gslot * 4 + sc) * 64;
    if (sc) __syncthreads();
    for (int s = t; s < 1024; s += 256) {
      int row = s >> 4, c4 = s & 15;
      float4 kv = *(const float4*)&Kg[((long)bh*NTOK + n0c + row)*DD + c4*4];
      float4 vv = *(const float4*)&Vg[((long)bh*NTOK + n0c + row)*DD + c4*4];
      f16x4 kk = {(f16)kv.x, (f16)kv.y, (f16)kv.z, (f16)kv.w};
      f16x4 vv4 = {(f16)vv.x, (f16)vv.y, (f16)vv.z, (f16)vv.w};
      *(f16x4*)&Ks[row][c4*4] = kk;
      *(f16x4*)&Vs[row][c4*4] = vv4;
    }
    if (t < 64) kmul[t] = maskg[b * NTOK + n0c + t] ? 1.f : 0.f;
    __syncthreads();

    f32x4 stv[4];
    #pragma unroll
    for (int g = 0; g < 4; ++g) {
      f16x8 a0 = *(const f16x8*)&Ks[g*16 + lm][hi*8];
      f16x8 a1 = *(const f16x8*)&Ks[g*16 + lm][32 + hi*8];
      stv[g] = mm2(a0, a1, nrf[0], nrf[1]);
    }
    f16x8 pa[2];
    #pragma unroll
    for (int g = 0; g < 4; ++g) {
      #pragma unroll
      for (int r = 0; r < 4; ++r) {
        float p = __expf(stv[g][r]) * kmul[g*16 + hi*4 + r];
        dsum += p;
        pa[g >> 1][(g & 1)*4 + r] = (f16)p;
      }
    }
    #pragma unroll
    for (int dt = 0; dt < 4; ++dt) {
      f16x8 vb0, vb1;
      #pragma unroll
      for (int j = 0; j < 8; ++j) {
        int nrow = hi*4 + (j & 3) + 16*(j >> 2);
        vb0[j] = Vs[nrow][dt*16 + lm];
        vb1[j] = Vs[32 + nrow][dt*16 + lm];
      }
      nacc[dt] = __builtin_amdgcn_mfma_f32_16x16x32_f16(pa[0], vb0, nacc[dt], 0, 0, 0);
      nacc[dt] = __builtin_amdgcn_mfma_f32_16x16x32_f16(pa[1], vb1, nacc[dt], 0, 0, 0);
    }
  }
  float* pnum = nump + ((long)bh * GPART + gslot) * (MM * DD);
  #pragma unroll
  for (int dt = 0; dt < 4; ++dt)
    #pragma unroll
    for (int r = 0; r < 4; ++r)
      pnum[(m0 + hi*4 + r)*DD + dt*16 + lm] = nacc[dt][r];
  float d2 = dsum + __shfl_xor(dsum, 16);
  d2 += __shfl_xor(d2, 32);
  if (lane < 16)
    denp[((long)bh * GPART + gslot) * MM + m0 + lane] = d2;
}

// merged launch: blocks [0,32) newton (independent of w3), blocks [32,288) w3
__global__ __launch_bounds__(512) void k_mix(const float* __restrict__ u,
    const float* __restrict__ smax, float* __restrict__ vinv,
    const float* __restrict__ Kg, const float* __restrict__ Vg,
    const int* __restrict__ maskg, const float* __restrict__ nr,
    float* __restrict__ nump, float* __restrict__ denp) {
  __shared__ __align__(16) char smem[73728];
  if (blockIdx.x < 32)
    newton_dev(smem, u, smax, vinv, blockIdx.x);
  else
    w3_dev(smem, Kg, Vg, maskg, nr, nump, denp, blockIdx.x - 32);
}

// ---------------- Z = Vinv @ (sum_g num_g / sum_g den_g)
__global__ __launch_bounds__(256) void k_z(const float* __restrict__ vinv,
    const float* __restrict__ nump, const float* __restrict__ denp, float* __restrict__ Zg) {
  int bh = blockIdx.x, tid = threadIdx.x, ti = tid >> 4, tj = tid & 15;
  __shared__ float A[MM][PAD];
  __shared__ float W[MM][MM];
  __shared__ float dn[MM];
  if (tid < 64) {
    float s = 0.f;
    #pragma unroll
    for (int g = 0; g < GPART; ++g) s += denp[((long)bh * GPART + g) * MM + tid];
    dn[tid] = s;
  }
  for (int e = tid; e < 1024; e += 256) {
    int m = e >> 4, d4 = e & 15;
    *(float4*)&A[m][d4*4] = *(const float4*)&vinv[(long)bh*MM*MM + m*MM + d4*4];
  }
  __syncthreads();
  for (int e = tid; e < 1024; e += 256) {
    int m = e >> 4, d4 = e & 15;
    float4 s = {0.f, 0.f, 0.f, 0.f};
    #pragma unroll
    for (int g = 0; g < GPART; ++g) {
      float4 t = *(const float4*)&nump[((long)bh * GPART + g) * (MM*DD) + m*DD + d4*4];
      s.x += t.x; s.y += t.y; s.z += t.z; s.w += t.w;
    }
    float inv = 1.f / dn[m];
    s.x *= inv; s.y *= inv; s.z *= inv; s.w *= inv;
    *(float4*)&W[m][d4*4] = s;
  }
  __syncthreads();
  float acc[4][4] = {};
  mm_acc<PAD, MM>(acc, A, W, ti, tj);
  #pragma unroll
  for (int x = 0; x < 4; ++x) {
    float4 o; o.x = acc[x][0]; o.y = acc[x][1]; o.z = acc[x][2]; o.w = acc[x][3];
    *(float4*)&Zg[(long)bh*MM*DD + (ti*4+x)*DD + tj*4] = o;
  }
}

// ---------------- MFMA X = row-softmax(Qs @ nc^T) @ Z  (swapped S^T trick)
__global__ __launch_bounds__(256) void k_final(const float* __restrict__ Qg,
    const float* __restrict__ nc, const float* __restrict__ Zg, float* __restrict__ Xg) {
  int bh = blockIdx.x, chunk = blockIdx.y;
  int tid = threadIdx.x;
  int wave = tid >> 6, lane = tid & 63;
  int lm = lane & 15, hi = lane >> 4;
  int n0 = chunk * 64;
  __shared__ f16 Qs[64][72];
  __shared__ f16 Ncs[64][72];
  __shared__ f16 Zs[64][72];
  for (int s = tid; s < 1024; s += 256) {
    int row = s >> 4, c4 = s & 15;
    float4 q = *(const float4*)&Qg[((long)bh*NTOK + n0 + row)*DD + c4*4];
    f16x4 qq = {(f16)(q.x*0.125f), (f16)(q.y*0.125f), (f16)(q.z*0.125f), (f16)(q.w*0.125f)};
    *(f16x4*)&Qs[row][c4*4] = qq;
    float4 cv = *(const float4*)&nc[(long)bh*MM*DD + row*DD + c4*4];
    f16x4 cc = {(f16)cv.x, (f16)cv.y, (f16)cv.z, (f16)cv.w};
    *(f16x4*)&Ncs[row][c4*4] = cc;
    float4 zv = *(const float4*)&Zg[(long)bh*MM*DD + row*DD + c4*4];
    f16x4 zz = {(f16)zv.x, (f16)zv.y, (f16)zv.z, (f16)zv.w};
    *(f16x4*)&Zs[row][c4*4] = zz;
  }
  __syncthreads();

  f16x8 qb0 = *(const f16x8*)&Qs[wave*16 + lm][hi*8];
  f16x8 qb1 = *(const f16x8*)&Qs[wave*16 + lm][32 + hi*8];
  f32x4 stv[4];
  #pragma unroll
  for (int mt = 0; mt < 4; ++mt) {
    f16x8 a0 = *(const f16x8*)&Ncs[mt*16 + lm][hi*8];
    f16x8 a1 = *(const f16x8*)&Ncs[mt*16 + lm][32 + hi*8];
    stv[mt] = mm2(a0, a1, qb0, qb1);
  }
  f16x8 pa[2];
  float dsum = 0.f;
  #pragma unroll
  for (int mt = 0; mt < 4; ++mt) {
    #pragma unroll
    for (int r = 0; r < 4; ++r) {
      float p = __expf(stv[mt][r]);
      dsum += p;
      pa[mt >> 1][(mt & 1)*4 + r] = (f16)p;
    }
  }
  float dtot = dsum + __shfl_xor(dsum, 16);
  dtot += __shfl_xor(dtot, 32);
  f32x4 xacc[4];
  #pragma unroll
  for (int dt = 0; dt < 4; ++dt) {
    f16x8 zb0, zb1;
    #pragma unroll
    for (int j = 0; j < 8; ++j) {
      int mrow = hi*4 + (j & 3) + 16*(j >> 2);
      zb0[j] = Zs[mrow][dt*16 + lm];
      zb1[j] = Zs[32 + mrow][dt*16 + lm];
    }
    f32x4 c = {0.f, 0.f, 0.f, 0.f};
    c = __builtin_amdgcn_mfma_f32_16x16x32_f16(pa[0], zb0, c, 0, 0, 0);
    c = __builtin_amdgcn_mfma_f32_16x16x32_f16(pa[1], zb1, c, 0, 0, 0);
    xacc[dt] = c;
  }
  float rn[4];
  #pragma unroll
  for (int r = 0; r < 4; ++r) rn[r] = 1.f / __shfl(dtot, hi*4 + r);
  #pragma unroll
  for (int dt = 0; dt < 4; ++dt)
    #pragma unroll
    for (int r = 0; r < 4; ++r)
      Xg[((long)bh*NTOK + n0 + wave*16 + hi*4 + r)*DD + dt*16 + lm] = xacc[dt][r] * rn[r];
}

extern "C" void kernel_launch(void* const* d_in, const int* in_sizes, int n_in,
                              void* d_out, int out_size, void* d_ws, size_t ws_size,
                              hipStream_t stream) {
  (void)in_sizes; (void)n_in; (void)out_size; (void)ws_size;
  const float* Qp = (const float*)d_in[0];
  const float* Kp = (const float*)d_in[1];
  const float* Vp = (const float*)d_in[2];
  const int* maskp = (const int*)d_in[3];
  float* out = (float*)d_out;

  float* wsf = (float*)d_ws;
  float* NUMP = wsf;                                // 32*16*4096
  float* DENP = NUMP + (long)BHN * GPART * MM * DD; // 32*16*64
  float* SMAX = DENP + BHN * GPART * MM;            // 32
  float* NC = SMAX + 32;
  float* NR = NC + BHN * MM * DD;
  float* U  = NR + BHN * MM * DD;
  float* VI = U  + BHN * MM * MM;
  float* Zb = VI + BHN * MM * MM;
  float* SK = Zb + BHN * MM * DD;
  float* SQ = SK + BHN * NTOK;

  k_somme<<<16384, 256, 0, stream>>>(Kp, Qp, maskp, SK, SQ);
  k_select<<<dim3(32, 2), 256, 0, stream>>>(Kp, Qp, SK, SQ, NC, NR);
  k_u<<<32, 256, 0, stream>>>(NC, NR, U, SMAX);
  k_mix<<<32 + 256, 512, 0, stream>>>(U, SMAX, VI, Kp, Vp, maskp, NR, NUMP, DENP);
  k_z<<<32, 256, 0, stream>>>(VI, NUMP, DENP, Zb);
  k_final<<<dim3(32, 64), 256, 0, stream>>>(Qp, NC, Zb, out);
}